// Round 10
// baseline (498.140 us; speedup 1.0000x reference)
//
#include <hip/hip_runtime.h>

typedef unsigned short u16;
typedef u16  u16x4 __attribute__((ext_vector_type(4)));
typedef u16  u16x8 __attribute__((ext_vector_type(8)));
typedef float f32x4 __attribute__((ext_vector_type(4)));
typedef int   i32x4 __attribute__((ext_vector_type(4)));
typedef __bf16 bf16x8 __attribute__((ext_vector_type(8)));

#define LSEQ 2048
#define NB 8
#define EDIM 1024
#define HNUM 16
#define DDIM 64
#define KPDIM 256
#define NE (NB*EDIM)       /* 8192 */
#define MROWS (LSEQ*NB)    /* 16384 */
#define AWSZ ((size_t)NB*LSEQ*KPDIM)  /* 4194304 */

__device__ __forceinline__ u16 f2b(float f) {
  unsigned u = __builtin_bit_cast(unsigned, f);
  u += 0x7fffu + ((u >> 16) & 1u);
  return (u16)(u >> 16);
}

__device__ __forceinline__ void gl_lds16(const void* g, void* l) {
  __builtin_amdgcn_global_load_lds(
      (const __attribute__((address_space(1))) void*)g,
      (__attribute__((address_space(3))) void*)l, 16, 0, 0);
}

__device__ __forceinline__ f32x4 mfma16(bf16x8 a, bf16x8 b, f32x4 c) {
  return __builtin_amdgcn_mfma_f32_16x16x32_bf16(a, b, c, 0, 0, 0);
}

#define BAR()   __builtin_amdgcn_s_barrier()
#define SB0()   __builtin_amdgcn_sched_barrier(0)
#define LGKM0() asm volatile("s_waitcnt lgkmcnt(0)" ::: "memory")
#define WVM16() asm volatile("s_waitcnt vmcnt(16)" ::: "memory")
#define WVM6()  asm volatile("s_waitcnt vmcnt(6)" ::: "memory")
#define WVM0()  asm volatile("s_waitcnt vmcnt(0)" ::: "memory")

// ---------------------------------------------------------------------------
// Weight prep kernels
// ---------------------------------------------------------------------------
__global__ void wconv(const float* __restrict__ src, u16* __restrict__ dst,
                      int n4, int scale_n4, float sc) {
  int i = blockIdx.x * blockDim.x + threadIdx.x;
  if (i >= n4) return;
  f32x4 v = ((const f32x4*)src)[i];
  float s = (i < scale_n4) ? sc : 1.0f;
  u16x4 o;
  o[0] = f2b(v[0] * s); o[1] = f2b(v[1] * s);
  o[2] = f2b(v[2] * s); o[3] = f2b(v[3] * s);
  ((u16x4*)dst)[i] = o;
}

// (O, I, 8) f32  ->  (O, t*E + i) bf16   (per-wave LDS transpose)
__global__ void wtrans(const float* __restrict__ ew, const float* __restrict__ fw,
                       u16* __restrict__ eT, u16* __restrict__ fT) {
  const float* src = blockIdx.y ? fw : ew;
  u16* dst = blockIdx.y ? fT : eT;
  int eo = blockIdx.x >> 4;
  int ei0 = (blockIdx.x & 15) * 64;
  int l = threadIdx.x;
  __shared__ u16 lds[8][64];
  const float* s = src + (size_t)eo * 8192 + (size_t)ei0 * 8 + l * 8;
  f32x4 a = *(const f32x4*)s;
  f32x4 b = *(const f32x4*)(s + 4);
  float v[8] = {a[0], a[1], a[2], a[3], b[0], b[1], b[2], b[3]};
#pragma unroll
  for (int t = 0; t < 8; ++t) lds[t][l] = f2b(v[t]);
  __syncthreads();
  int t = l >> 3, c = l & 7;
  i32x4 out = *(const i32x4*)&lds[t][c * 8];
  *(i32x4*)(dst + (size_t)eo * 8192 + t * 1024 + ei0 + c * 8) = out;
}

__global__ void bscale(const float* __restrict__ b, float* __restrict__ out) {
  int i = blockIdx.x * blockDim.x + threadIdx.x;
  if (i < EDIM) out[i] = b[i] * 0.125f;
}

// q/k/v f32 -> bf16, contiguous [3][MROWS][E]
__global__ void castqkv(const float* __restrict__ q, const float* __restrict__ k,
                        const float* __restrict__ v, u16* __restrict__ out) {
  const float* src = blockIdx.y == 0 ? q : (blockIdx.y == 1 ? k : v);
  size_t base = (size_t)blockIdx.y * ((size_t)MROWS * EDIM);
  size_t i = ((size_t)blockIdx.x * 256 + threadIdx.x) * 8;
  f32x4 v0 = *(const f32x4*)(src + i);
  f32x4 v1 = *(const f32x4*)(src + i + 4);
  u16x8 o;
  o[0] = f2b(v0[0]); o[1] = f2b(v0[1]); o[2] = f2b(v0[2]); o[3] = f2b(v0[3]);
  o[4] = f2b(v1[0]); o[5] = f2b(v1[1]); o[6] = f2b(v1[2]); o[7] = f2b(v1[3]);
  *(u16x8*)(out + base + i) = o;
}

// sum 4 split-K partials + bias -> bf16.
// K -> head-major (N,H,Kp,D). V -> transposed (N,H,D,Kp) chunk-swizzled.
__global__ void redc(const float* __restrict__ part, const float* __restrict__ eb,
                     const float* __restrict__ fb, u16* __restrict__ kc,
                     u16* __restrict__ vcT) {
  int zc = blockIdx.y;
  const float* p = part + (size_t)zc * 4 * 2048 * 1024;
  const float* bias = zc ? fb : eb;
  size_t i = ((size_t)blockIdx.x * 256 + threadIdx.x) * 4;
  f32x4 s = *(const f32x4*)(p + i);
  s += *(const f32x4*)(p + 2097152 + i);
  s += *(const f32x4*)(p + 2 * 2097152 + i);
  s += *(const f32x4*)(p + 3 * 2097152 + i);
  int e = (int)(i & 1023);
  int row = (int)(i >> 10);           // n*256 + p
  int n = row >> 8, pp = row & 255;
  int h = e >> 6, d = e & 63;
  f32x4 b = *(const f32x4*)(bias + e);
  if (zc == 0) {
    u16x4 o;
    o[0] = f2b(s[0] + b[0]); o[1] = f2b(s[1] + b[1]);
    o[2] = f2b(s[2] + b[2]); o[3] = f2b(s[3] + b[3]);
    *(u16x4*)(kc + (((size_t)(n * HNUM + h) * KPDIM + pp) * DDIM + d)) = o;
  } else {
    size_t base = (size_t)(n * HNUM + h) * (DDIM * KPDIM);
#pragma unroll
    for (int q = 0; q < 4; ++q) {
      int dq = d + q;
      vcT[base + dq * 256 + (((pp >> 3) ^ (dq & 7)) * 8) + (pp & 7)] =
          f2b(s[q] + b[q]);
    }
  }
}

// sum the 4 head-group AW partials
__global__ void awred(const float* __restrict__ awp, float* __restrict__ aw) {
  size_t i = ((size_t)blockIdx.x * 256 + threadIdx.x) * 4;
  f32x4 s = *(const f32x4*)(awp + i);
  s += *(const f32x4*)(awp + AWSZ + i);
  s += *(const f32x4*)(awp + 2 * AWSZ + i);
  s += *(const f32x4*)(awp + 3 * AWSZ + i);
  *(f32x4*)(aw + i) = s;
}

// ---------------------------------------------------------------------------
// 256x256 GEMM — 8-phase ring schedule (r8, verified) + coalesced bf16
// epilogue (r9). Reader/stage ring and vmcnt ledger: see r8 comments.
//   AMODE 0: A bf16 rows contiguous (ld=K); AMODE 1: conv-gather
//   OUTMODE 0: bf16 C+bias (LDS-bounced); 1: f32 C+bias; 2: f32 split-K partial
// grid = (M/256, N/256, nz*kspl); block = 512 (8 waves, 2M x 4N); nt even
// ---------------------------------------------------------------------------
template<int AMODE, int OUTMODE>
__global__ __launch_bounds__(512, 2)
void gemm256(const void* A0p, const void* A1p, const void* A2p,
             const u16* B0p, const u16* B1p, const u16* B2p,
             const float* b0p, const float* b1p, const float* b2p,
             void* C0p, void* C1p, void* C2p,
             int M, int K, int kspl) {
  const int zc = blockIdx.z / kspl, sp = blockIdx.z % kspl;
  const void* Ap = zc == 0 ? A0p : (zc == 1 ? A1p : A2p);
  const u16* Bp = zc == 0 ? B0p : (zc == 1 ? B1p : B2p);
  const float* biasp = zc == 0 ? b0p : (zc == 1 ? b1p : b2p);
  void* Cp = zc == 0 ? C0p : (zc == 1 ? C1p : C2p);

  __shared__ u16 lds[2][2][2][128 * 64];  // [buf][A=0/B=1][half][r*64+swzchunk*8]

  const int tid = threadIdx.x;
  const int w = tid >> 6, lane = tid & 63;
  const int lr = lane & 15, lg = lane >> 4;
  const int wr = w >> 2, wc = w & 3;            // 2M x 4N waves
  const int m0 = blockIdx.x * 256, n0 = blockIdx.y * 256;
  const int kper = K / kspl, kbase = sp * kper, nt = kper >> 6;

  f32x4 acc[8][4];
#pragma unroll
  for (int mi = 0; mi < 8; ++mi)
#pragma unroll
    for (int ni = 0; ni < 4; ++ni) {
      f32x4 zv = {0.f, 0.f, 0.f, 0.f};
      acc[mi][ni] = zv;
    }

  // stage one 16KB half: op (0=A,1=B), half (0/1 = rows 0-127/128-255), tile kt
  auto stage_half = [&](int buf, int op, int half, int kt) {
    const int k0 = kbase + (kt << 6);
#pragma unroll
    for (int i = 0; i < 2; ++i) {
      int c = i * 512 + tid;               // 0..1023
      int r = c >> 3, j = c & 7, js = j ^ (r & 7);
      int row = half * 128 + r;
      u16* dst = &lds[buf][op][half][c * 8];
      if (op == 1) {
        gl_lds16(Bp + (size_t)(n0 + row) * K + k0 + js * 8, dst);
      } else if (AMODE == 0) {
        gl_lds16((const u16*)Ap + (size_t)(m0 + row) * K + k0 + js * 8, dst);
      } else {  // conv gather: m=(nn,p), k=(t,ei); k0 mult of 64, no 1024-cross
        int m = m0 + row;
        int nn = m >> 8, p = m & 255;
        int k = k0 + js * 8;
        gl_lds16((const u16*)Ap + (size_t)(p * 8 + (k >> 10)) * NE +
                 nn * EDIM + (k & 1023), dst);
      }
    }
  };

  auto LDA = [&](int buf, int row, int ks) -> bf16x8 {
    return *(const bf16x8*)&lds[buf][0][row >> 7]
        [(row & 127) * 64 + (((ks * 4 + lg) ^ (row & 7)) << 3)];
  };
  auto LDB = [&](int buf, int row, int ks) -> bf16x8 {
    return *(const bf16x8*)&lds[buf][1][row >> 7]
        [(row & 127) * 64 + (((ks * 4 + lg) ^ (row & 7)) << 3)];
  };

  // ---- prologue: T0 all 4 halves -> buf0; T1 B0,B1,A0 -> buf1 ----
  stage_half(0, 0, 0, 0); stage_half(0, 1, 0, 0);
  stage_half(0, 1, 1, 0); stage_half(0, 0, 1, 0);
  if (nt > 1) {
    stage_half(1, 1, 0, 1); stage_half(1, 1, 1, 1); stage_half(1, 0, 0, 1);
    WVM6();
  } else {
    WVM0();
  }
  BAR();

  for (int t = 0; t < nt; t += 2) {
    bf16x8 a0[4][2], a1[4][2], b0f[2][2], b1f[2][2];
    // ================= tile t (buf0) =================
    // ---- ph1: reads a0, b0 ----
#pragma unroll
    for (int mi = 0; mi < 4; ++mi)
#pragma unroll
      for (int ks = 0; ks < 2; ++ks)
        a0[mi][ks] = LDA(0, wr * 128 + mi * 16 + lr, ks);
#pragma unroll
    for (int ni = 0; ni < 2; ++ni)
#pragma unroll
      for (int ks = 0; ks < 2; ++ks)
        b0f[ni][ks] = LDB(0, wc * 64 + ni * 16 + lr, ks);
    stage_half(1, 0, 1, t + 1);            // (t+1).A1 (free since prev ph7)
    BAR(); LGKM0();
    __builtin_amdgcn_s_setprio(1);
#pragma unroll
    for (int mi = 0; mi < 4; ++mi)
#pragma unroll
      for (int ni = 0; ni < 2; ++ni)
#pragma unroll
        for (int ks = 0; ks < 2; ++ks)
          acc[mi][ni] = mfma16(a0[mi][ks], b0f[ni][ks], acc[mi][ni]);
    __builtin_amdgcn_s_setprio(0);
    BAR();
    // ---- ph2: reads b1; no stage ----
#pragma unroll
    for (int ni = 0; ni < 2; ++ni)
#pragma unroll
      for (int ks = 0; ks < 2; ++ks)
        b1f[ni][ks] = LDB(0, wc * 64 + (ni + 2) * 16 + lr, ks);
    BAR(); LGKM0();
    __builtin_amdgcn_s_setprio(1);
#pragma unroll
    for (int mi = 0; mi < 4; ++mi)
#pragma unroll
      for (int ni = 0; ni < 2; ++ni)
#pragma unroll
        for (int ks = 0; ks < 2; ++ks)
          acc[mi][ni + 2] = mfma16(a0[mi][ks], b1f[ni][ks], acc[mi][ni + 2]);
    __builtin_amdgcn_s_setprio(0);
    BAR();
    // ---- ph3: reads a1 ----
#pragma unroll
    for (int mi = 0; mi < 4; ++mi)
#pragma unroll
      for (int ks = 0; ks < 2; ++ks)
        a1[mi][ks] = LDA(0, wr * 128 + 64 + mi * 16 + lr, ks);
    if (t + 2 < nt) stage_half(0, 1, 0, t + 2);   // (t+2).B0 (free after ph2)
    BAR(); LGKM0();
    __builtin_amdgcn_s_setprio(1);
#pragma unroll
    for (int mi = 0; mi < 4; ++mi)
#pragma unroll
      for (int ni = 0; ni < 2; ++ni)
#pragma unroll
        for (int ks = 0; ks < 2; ++ks)
          acc[mi + 4][ni + 2] = mfma16(a1[mi][ks], b1f[ni][ks], acc[mi + 4][ni + 2]);
    __builtin_amdgcn_s_setprio(0);
    BAR();
    // ---- ph4: regs only; stage B1+A0 ----
    if (t + 2 < nt) { stage_half(0, 1, 1, t + 2); stage_half(0, 0, 0, t + 2); }
    BAR();
    __builtin_amdgcn_s_setprio(1);
#pragma unroll
    for (int mi = 0; mi < 4; ++mi)
#pragma unroll
      for (int ni = 0; ni < 2; ++ni)
#pragma unroll
        for (int ks = 0; ks < 2; ++ks)
          acc[mi + 4][ni] = mfma16(a1[mi][ks], b0f[ni][ks], acc[mi + 4][ni]);
    __builtin_amdgcn_s_setprio(0);
    if (t + 2 < nt) { WVM6(); } else { WVM0(); }
    BAR();
    // ================= tile t+1 (buf1) =================
    // ---- ph5 ----
#pragma unroll
    for (int mi = 0; mi < 4; ++mi)
#pragma unroll
      for (int ks = 0; ks < 2; ++ks)
        a0[mi][ks] = LDA(1, wr * 128 + mi * 16 + lr, ks);
#pragma unroll
    for (int ni = 0; ni < 2; ++ni)
#pragma unroll
      for (int ks = 0; ks < 2; ++ks)
        b0f[ni][ks] = LDB(1, wc * 64 + ni * 16 + lr, ks);
    if (t + 2 < nt) stage_half(0, 0, 1, t + 2);   // (t+2).A1 (free after ph3)
    BAR(); LGKM0();
    __builtin_amdgcn_s_setprio(1);
#pragma unroll
    for (int mi = 0; mi < 4; ++mi)
#pragma unroll
      for (int ni = 0; ni < 2; ++ni)
#pragma unroll
        for (int ks = 0; ks < 2; ++ks)
          acc[mi][ni] = mfma16(a0[mi][ks], b0f[ni][ks], acc[mi][ni]);
    __builtin_amdgcn_s_setprio(0);
    BAR();
    // ---- ph6: no stage ----
#pragma unroll
    for (int ni = 0; ni < 2; ++ni)
#pragma unroll
      for (int ks = 0; ks < 2; ++ks)
        b1f[ni][ks] = LDB(1, wc * 64 + (ni + 2) * 16 + lr, ks);
    BAR(); LGKM0();
    __builtin_amdgcn_s_setprio(1);
#pragma unroll
    for (int mi = 0; mi < 4; ++mi)
#pragma unroll
      for (int ni = 0; ni < 2; ++ni)
#pragma unroll
        for (int ks = 0; ks < 2; ++ks)
          acc[mi][ni + 2] = mfma16(a0[mi][ks], b1f[ni][ks], acc[mi][ni + 2]);
    __builtin_amdgcn_s_setprio(0);
    BAR();
    // ---- ph7 ----
#pragma unroll
    for (int mi = 0; mi < 4; ++mi)
#pragma unroll
      for (int ks = 0; ks < 2; ++ks)
        a1[mi][ks] = LDA(1, wr * 128 + 64 + mi * 16 + lr, ks);
    if (t + 3 < nt) stage_half(1, 1, 0, t + 3);   // (t+3).B0 (free after ph6)
    BAR(); LGKM0();
    __builtin_amdgcn_s_setprio(1);
#pragma unroll
    for (int mi = 0; mi < 4; ++mi)
#pragma unroll
      for (int ni = 0; ni < 2; ++ni)
#pragma unroll
        for (int ks = 0; ks < 2; ++ks)
          acc[mi + 4][ni + 2] = mfma16(a1[mi][ks], b1f[ni][ks], acc[mi + 4][ni + 2]);
    __builtin_amdgcn_s_setprio(0);
    BAR();
    // ---- ph8: regs only; stage B1'+A0' ----
    if (t + 3 < nt) { stage_half(1, 1, 1, t + 3); stage_half(1, 0, 0, t + 3); }
    BAR();
    __builtin_amdgcn_s_setprio(1);
#pragma unroll
    for (int mi = 0; mi < 4; ++mi)
#pragma unroll
      for (int ni = 0; ni < 2; ++ni)
#pragma unroll
        for (int ks = 0; ks < 2; ++ks)
          acc[mi + 4][ni] = mfma16(a1[mi][ks], b0f[ni][ks], acc[mi + 4][ni]);
    __builtin_amdgcn_s_setprio(0);
    if (t + 3 < nt) { WVM6(); } else { WVM0(); }
    BAR();
  }

  // ---- epilogue ----
  if (OUTMODE == 0) {
    // LDS-bounce: tile -> LDS (128 KB), then fully-coalesced 16B/lane stores.
    __syncthreads();
    u16* cw = (u16*)&lds[0][0][0][0];       // [256][256] u16
#pragma unroll
    for (int ni = 0; ni < 4; ++ni) {
      const int col = wc * 64 + ni * 16 + lr;
      const float bv = biasp[n0 + col];
#pragma unroll
      for (int mi = 0; mi < 8; ++mi)
#pragma unroll
        for (int j = 0; j < 4; ++j) {
          const int row = wr * 128 + mi * 16 + lg * 4 + j;
          cw[row * 256 + col] = f2b(acc[mi][ni][j] + bv);
        }
    }
    __syncthreads();
#pragma unroll
    for (int it = 0; it < 16; ++it) {
      int c = it * 512 + tid;
      int row = c >> 5, ch = c & 31;
      i32x4 v = *(const i32x4*)&cw[row * 256 + ch * 8];
      *(i32x4*)((u16*)Cp + (size_t)(m0 + row) * 1024 + n0 + ch * 8) = v;
    }
  } else {
#pragma unroll
    for (int ni = 0; ni < 4; ++ni) {
      const int col = n0 + wc * 64 + ni * 16 + lr;
      const float bv = (OUTMODE == 2) ? 0.f : biasp[col];
#pragma unroll
      for (int mi = 0; mi < 8; ++mi)
#pragma unroll
        for (int j = 0; j < 4; ++j) {
          const int row = m0 + wr * 128 + mi * 16 + lg * 4 + j;
          const float v = acc[mi][ni][j] + bv;
          if (OUTMODE == 2)
            ((float*)Cp)[(size_t)sp * M * 1024 + (size_t)row * 1024 + col] = v;
          else
            ((float*)Cp)[(size_t)row * 1024 + col] = v;
        }
    }
  }
}

// ---------------------------------------------------------------------------
// Legacy 128x128 GEMM — fallback paths only (small workspace)
//   OUTMODE 3: bf16+bias -> head-major (N,H,Kp,D)
//   OUTMODE 4: bf16+bias -> transposed swizzled (N,H,D,Kp)
// ---------------------------------------------------------------------------
template<int AMODE, int OUTMODE>
__global__ __launch_bounds__(256)
void gemm_bt(const void* A0p, const void* A1p, const void* A2p,
             const u16* B0p, const u16* B1p, const u16* B2p,
             const float* b0p, const float* b1p, const float* b2p,
             void* C0p, void* C1p, void* C2p,
             int M, int K, int kspl) {
  const int zc = blockIdx.z / kspl;
  const int sp = blockIdx.z % kspl;
  const void* Ap = zc == 0 ? A0p : (zc == 1 ? A1p : A2p);
  const u16* Bp = zc == 0 ? B0p : (zc == 1 ? B1p : B2p);
  const float* biasp = zc == 0 ? b0p : (zc == 1 ? b1p : b2p);
  void* Cp = zc == 0 ? C0p : (zc == 1 ? C1p : C2p);

  __shared__ u16 Alds[128 * 64];
  __shared__ u16 Blds[128 * 64];

  const int tid = threadIdx.x;
  const int w = tid >> 6, lane = tid & 63;
  const int lr = lane & 15, lg = lane >> 4;
  const int m0 = blockIdx.x * 128, n0 = blockIdx.y * 128;
  const int wr = (w >> 1) * 64, wc = (w & 1) * 64;
  const int brow = lane >> 3;
  const int bcol = (lane & 7) * 8;

  f32x4 acc[4][4];
#pragma unroll
  for (int mi = 0; mi < 4; ++mi)
#pragma unroll
    for (int ni = 0; ni < 4; ++ni) {
      f32x4 zv = {0.f, 0.f, 0.f, 0.f};
      acc[mi][ni] = zv;
    }

  const int kper = K / kspl;
  const int ktn = kper >> 6;
  const int kb = sp * kper;
  for (int kt = 0; kt < ktn; ++kt) {
    const int k0 = kb + (kt << 6);
    __syncthreads();
#pragma unroll
    for (int i = 0; i < 4; ++i) {
      const int c = w * 4 + i;
      const int row = c * 8 + brow;
      gl_lds16(Bp + (size_t)(n0 + row) * K + k0 + bcol, &Blds[c * 512]);
    }
    if (AMODE == 2) {
      const float* Af = (const float*)Ap;
#pragma unroll
      for (int i = 0; i < 4; ++i) {
        const int c = i * 256 + tid;
        const int row = c >> 3, k8 = (c & 7) * 8;
        const float* s = Af + (size_t)(m0 + row) * K + k0 + k8;
        f32x4 v0 = *(const f32x4*)s;
        f32x4 v1 = *(const f32x4*)(s + 4);
        u16x8 pk;
        pk[0] = f2b(v0[0]); pk[1] = f2b(v0[1]); pk[2] = f2b(v0[2]); pk[3] = f2b(v0[3]);
        pk[4] = f2b(v1[0]); pk[5] = f2b(v1[1]); pk[6] = f2b(v1[2]); pk[7] = f2b(v1[3]);
        *(u16x8*)&Alds[row * 64 + k8] = pk;
      }
    } else if (AMODE == 0) {
      const u16* Ab = (const u16*)Ap;
#pragma unroll
      for (int i = 0; i < 4; ++i) {
        const int c = w * 4 + i;
        const int row = c * 8 + brow;
        gl_lds16(Ab + (size_t)(m0 + row) * K + k0 + bcol, &Alds[c * 512]);
      }
    } else {
      const u16* Ab = (const u16*)Ap;
#pragma unroll
      for (int i = 0; i < 4; ++i) {
        const int c = w * 4 + i;
        const int m = m0 + c * 8 + brow;
        const int nn = m >> 8, p = m & 255;
        const int k = k0 + bcol;
        gl_lds16(Ab + (size_t)(p * 8 + (k >> 10)) * NE + nn * EDIM + (k & 1023),
                 &Alds[c * 512]);
      }
    }
    __syncthreads();
#pragma unroll
    for (int ks = 0; ks < 2; ++ks) {
      bf16x8 af[4], bf[4];
#pragma unroll
      for (int mi = 0; mi < 4; ++mi)
        af[mi] = *(const bf16x8*)&Alds[(wr + mi * 16 + lr) * 64 + ks * 32 + lg * 8];
#pragma unroll
      for (int ni = 0; ni < 4; ++ni)
        bf[ni] = *(const bf16x8*)&Blds[(wc + ni * 16 + lr) * 64 + ks * 32 + lg * 8];
#pragma unroll
      for (int mi = 0; mi < 4; ++mi)
#pragma unroll
        for (int ni = 0; ni < 4; ++ni)
          acc[mi][ni] = mfma16(af[mi], bf[ni], acc[mi][ni]);
    }
  }
#pragma unroll
  for (int ni = 0; ni < 4; ++ni) {
    const int col = n0 + wc + ni * 16 + lr;
    const float bv = (OUTMODE == 2) ? 0.f : biasp[col];
#pragma unroll
    for (int mi = 0; mi < 4; ++mi)
#pragma unroll
      for (int j = 0; j < 4; ++j) {
        const int row = m0 + wr + mi * 16 + lg * 4 + j;
        const float v = acc[mi][ni][j] + bv;
        if (OUTMODE == 4) {
          const int nn = row >> 8, pp = row & 255, h = col >> 6, d = col & 63;
          ((u16*)Cp)[(size_t)(nn * HNUM + h) * (DDIM * KPDIM) + d * 256 +
                     (((pp >> 3) ^ (d & 7)) * 8) + (pp & 7)] = f2b(v);
        } else if (OUTMODE == 3) {
          const int nn = row >> 8, pp = row & 255, h = col >> 6, d = col & 63;
          ((u16*)Cp)[((size_t)(nn * HNUM + h) * KPDIM + pp) * DDIM + d] = f2b(v);
        } else if (OUTMODE == 2)
          ((float*)Cp)[(size_t)sp * M * 1024 + (size_t)row * 1024 + col] = v;
        else if (OUTMODE == 1)
          ((float*)Cp)[(size_t)row * 1024 + col] = v;
        else
          ((u16*)Cp)[(size_t)row * 1024 + col] = f2b(v);
      }
  }
}

// ---------------------------------------------------------------------------
// Fused attention v4: cross-head K/V double-buffer (T3/T14 for attn).
// block = (64 q-rows, n, head-group of 4). LDS 128 KB: Kbuf[2] (P overlays
// Kbuf[b] post-QK), Vbuf[2]. 1 block/CU.
// Schedule per head hh (b=hh&1):  QK(K[b]) -> softmax -> BAR ->
//   P-store(K[b]) -> PV(V[b]) -> O-store -> [WVM16; BAR; stage KV(hh+2)->b]
// vmcnt ledger (per lane): prologue issues aq(8)+KV0(16)+KV1(16); WVM16
// drains aq+KV0, keeps KV1. At head hh boundary: outstanding =
// KV(hh+1)(16) + Ost(hh)(16 newest); WVM16 keeps the 16 newest (own stores),
// drains KV(hh+1) and all older (incl. prior Ost). Stage KV(hh+2) after the
// barrier (P_hh and V_hh dead block-wide: each wave's PV ds_reads complete
// before its MFMA-dependent O f2b, hence before its WVM+BAR). Q preloaded in
// prologue (32 VGPR) so no mid-loop compiler vmcnt waits drain the prefetch.
// sched_barrier(0) after each BAR pins LDS ops / gl_lds below the barrier.
// P stored as RAW exp (<=1.0); inv folded into O-scale and macc FMA.
// ---------------------------------------------------------------------------
__global__ __launch_bounds__(256)
void attn_fused4(const u16* __restrict__ Q, const u16* __restrict__ Kc,
                 const u16* __restrict__ VcT, u16* __restrict__ Aout,
                 float* __restrict__ AWp) {
  __shared__ u16 Kbuf[2][256 * 64];   // [b][p][d] chunk-swz; P overlays post-QK
  __shared__ u16 Vbuf[2][64 * 256];   // [b][d][p] chunk-swz
  const int tid = threadIdx.x;
  const int w = tid >> 6, lane = tid & 63;
  const int lr = lane & 15, lg = lane >> 4;
  const int n = blockIdx.y;
  const int l0 = blockIdx.x * 64;
  const int lrow = l0 + w * 16 + lr;
  const int h0 = blockIdx.z * 4;

  auto stageKV = [&](int b, int hh) {
    const int h = h0 + hh;
    const u16* kh = Kc + (size_t)(n * HNUM + h) * (KPDIM * DDIM);
    const u16* vh = VcT + (size_t)(n * HNUM + h) * (DDIM * KPDIM);
    char* kb = (char*)Kbuf[b];
    char* vb = (char*)Vbuf[b];
#pragma unroll
    for (int it = 0; it < 8; ++it) {
      int c = it * 256 + tid, p = c >> 3, j = c & 7;
      gl_lds16(kh + p * 64 + ((j ^ (p & 7)) << 3), kb + c * 16);
    }
#pragma unroll
    for (int it = 0; it < 8; ++it) {
      int c = it * 256 + tid;
      gl_lds16(vh + c * 8, vb + c * 16);
    }
  };

  // ---- prologue: preload Q (all 4 heads), stage KV(0), KV(1) ----
  bf16x8 aq[4][2];
#pragma unroll
  for (int hh = 0; hh < 4; ++hh) {
    const u16* qp = Q + (size_t)lrow * NE + n * EDIM + (h0 + hh) * DDIM + lg * 8;
    aq[hh][0] = *(const bf16x8*)qp;
    aq[hh][1] = *(const bf16x8*)(qp + 32);
  }
  stageKV(0, 0);
  stageKV(1, 1);
  WVM16();
  BAR(); SB0();

  f32x4 macc[16];
#pragma unroll
  for (int ni = 0; ni < 16; ++ni) { f32x4 zv = {0.f,0.f,0.f,0.f}; macc[ni] = zv; }

#pragma unroll
  for (int hh = 0; hh < 4; ++hh) {
    const int b = hh & 1;
    const int h = h0 + hh;
    char* kbase = (char*)Kbuf[b];
    char* vbase = (char*)Vbuf[b];
    char* pbase = (char*)Kbuf[b] + w * 8192;  // 16 rows x 256 x 2B per wave
    // ---- S = q @ k^T : 16 rows x 256 cols per wave ----
    f32x4 s[16];
#pragma unroll
    for (int ni = 0; ni < 16; ++ni) { f32x4 zv = {0.f,0.f,0.f,0.f}; s[ni] = zv; }
#pragma unroll
    for (int ni = 0; ni < 16; ++ni) {
      int row = ni * 16 + lr;
      const char* kr = kbase + row * 128;
      bf16x8 b0 = *(const bf16x8*)(kr + ((lg ^ (row & 7)) << 4));
      bf16x8 b1 = *(const bf16x8*)(kr + (((4 + lg) ^ (row & 7)) << 4));
      s[ni] = mfma16(aq[hh][0], b0, s[ni]);
      s[ni] = mfma16(aq[hh][1], b1, s[ni]);
    }
    // ---- softmax (row r = lg*4+j lives in 16-lane group lg) ----
    float mx[4], sm[4], inv[4], invs[4];
#pragma unroll
    for (int j = 0; j < 4; ++j) mx[j] = -1e30f;
#pragma unroll
    for (int ni = 0; ni < 16; ++ni)
#pragma unroll
      for (int j = 0; j < 4; ++j) mx[j] = fmaxf(mx[j], s[ni][j]);
#pragma unroll
    for (int msk = 1; msk <= 8; msk <<= 1)
#pragma unroll
      for (int j = 0; j < 4; ++j) mx[j] = fmaxf(mx[j], __shfl_xor(mx[j], msk, 64));
#pragma unroll
    for (int j = 0; j < 4; ++j) sm[j] = 0.f;
#pragma unroll
    for (int ni = 0; ni < 16; ++ni)
#pragma unroll
      for (int j = 0; j < 4; ++j) {
        float e = __expf(s[ni][j] - mx[j]);
        s[ni][j] = e; sm[j] += e;
      }
#pragma unroll
    for (int msk = 1; msk <= 8; msk <<= 1)
#pragma unroll
      for (int j = 0; j < 4; ++j) sm[j] += __shfl_xor(sm[j], msk, 64);
#pragma unroll
    for (int j = 0; j < 4; ++j) { inv[j] = 1.0f / sm[j]; invs[j] = inv[j] * 0.0625f; }
    BAR(); SB0();   // all waves done reading K[b]; P may overwrite it
    // ---- head-mean FMA + store RAW P (bf16, per-wave quarter of Kbuf[b]) ----
#pragma unroll
    for (int ni = 0; ni < 16; ++ni)
#pragma unroll
      for (int j = 0; j < 4; ++j) {
        macc[ni][j] += s[ni][j] * invs[j];
        int r = lg * 4 + j;
        *(u16*)(pbase + r * 512 + ((ni * 32 + lr * 2) ^ ((r & 7) << 4))) =
            f2b(s[ni][j]);
      }
    // ---- O = Praw @ V, then scale by inv (P wave-private; no barrier) ----
    f32x4 o[4];
#pragma unroll
    for (int ni2 = 0; ni2 < 4; ++ni2) { f32x4 zv = {0.f,0.f,0.f,0.f}; o[ni2] = zv; }
#pragma unroll
    for (int ks = 0; ks < 8; ++ks) {
      bf16x8 a = *(const bf16x8*)(pbase + lr * 512 + ((ks * 64 + 16 * lg) ^ ((lr & 7) << 4)));
#pragma unroll
      for (int ni2 = 0; ni2 < 4; ++ni2) {
        int d = ni2 * 16 + lr;
        bf16x8 bv = *(const bf16x8*)(vbase + d * 512 + (((ks * 4 + lg) ^ (d & 7)) << 4));
        o[ni2] = mfma16(a, bv, o[ni2]);
      }
    }
    // ---- write O tile ----
#pragma unroll
    for (int ni2 = 0; ni2 < 4; ++ni2)
#pragma unroll
      for (int j = 0; j < 4; ++j) {
        int gl = l0 + w * 16 + lg * 4 + j;
        Aout[(size_t)gl * NE + n * EDIM + h * DDIM + ni2 * 16 + lr] =
            f2b(o[ni2][j] * inv[j]);
      }
    // ---- boundary: drain KV(hh+1) (keep own 16 O-stores in flight);
    //      after barrier stage KV(hh+2) into freed buf b ----
    if (hh < 3) {
      WVM16();
      BAR(); SB0();
      if (hh < 2) stageKV(b, hh + 2);
    }
  }
  // ---- write head-mean attention weight partial ----
  float* awo = AWp + (size_t)blockIdx.z * AWSZ + (size_t)n * (LSEQ * KPDIM);
#pragma unroll
  for (int ni = 0; ni < 16; ++ni)
#pragma unroll
    for (int j = 0; j < 4; ++j) {
      int r = lg * 4 + j;
      awo[(size_t)(l0 + w * 16 + r) * KPDIM + ni * 16 + lr] = macc[ni][j];
    }
}

// ---------------------------------------------------------------------------
// Fused attention v3 (r9, stable) — fallback path only (small workspace).
// ---------------------------------------------------------------------------
__global__ __launch_bounds__(256)
void attn_fused(const u16* __restrict__ Q, const u16* __restrict__ Kc,
                const u16* __restrict__ VcT, u16* __restrict__ Aout,
                float* __restrict__ AWp, int hpg) {
  __shared__ u16 Ares[256 * 64];
  __shared__ u16 Bres[64 * 256];
  const int tid = threadIdx.x;
  const int w = tid >> 6, lane = tid & 63;
  const int lr = lane & 15, lg = lane >> 4;
  const int n = blockIdx.y;
  const int l0 = blockIdx.x * 64;
  const int lrow = l0 + w * 16 + lr;
  char* kbase = (char*)Ares;
  char* vbase = (char*)Bres;
  char* pbase = (char*)Ares + w * 8192;

  f32x4 macc[16];
#pragma unroll
  for (int ni = 0; ni < 16; ++ni) { f32x4 zv = {0.f,0.f,0.f,0.f}; macc[ni] = zv; }

  for (int hh = 0; hh < hpg; ++hh) {
    const int h = blockIdx.z * hpg + hh;
    const u16* kh = Kc + (size_t)(n * HNUM + h) * (KPDIM * DDIM);
    const u16* vh = VcT + (size_t)(n * HNUM + h) * (DDIM * KPDIM);
    __syncthreads();
#pragma unroll
    for (int it = 0; it < 8; ++it) {
      int c = it * 256 + tid;
      int p = c >> 3, j = c & 7;
      gl_lds16(kh + p * 64 + ((j ^ (p & 7)) << 3), kbase + c * 16);
    }
#pragma unroll
    for (int it = 0; it < 8; ++it) {
      int c = it * 256 + tid;
      gl_lds16(vh + c * 8, vbase + c * 16);
    }
    const u16* qp = Q + (size_t)lrow * NE + n * EDIM + h * DDIM + lg * 8;
    bf16x8 aq0 = *(const bf16x8*)qp;
    bf16x8 aq1 = *(const bf16x8*)(qp + 32);
    __syncthreads();
    f32x4 s[16];
#pragma unroll
    for (int ni = 0; ni < 16; ++ni) { f32x4 zv = {0.f,0.f,0.f,0.f}; s[ni] = zv; }
#pragma unroll
    for (int ni = 0; ni < 16; ++ni) {
      int row = ni * 16 + lr;
      const char* kr = kbase + row * 128;
      bf16x8 b0 = *(const bf16x8*)(kr + ((lg ^ (row & 7)) << 4));
      bf16x8 b1 = *(const bf16x8*)(kr + (((4 + lg) ^ (row & 7)) << 4));
      s[ni] = mfma16(aq0, b0, s[ni]);
      s[ni] = mfma16(aq1, b1, s[ni]);
    }
    float mx[4], sm[4], inv[4];
#pragma unroll
    for (int j = 0; j < 4; ++j) mx[j] = -1e30f;
#pragma unroll
    for (int ni = 0; ni < 16; ++ni)
#pragma unroll
      for (int j = 0; j < 4; ++j) mx[j] = fmaxf(mx[j], s[ni][j]);
#pragma unroll
    for (int msk = 1; msk <= 8; msk <<= 1)
#pragma unroll
      for (int j = 0; j < 4; ++j) mx[j] = fmaxf(mx[j], __shfl_xor(mx[j], msk, 64));
#pragma unroll
    for (int j = 0; j < 4; ++j) sm[j] = 0.f;
#pragma unroll
    for (int ni = 0; ni < 16; ++ni)
#pragma unroll
      for (int j = 0; j < 4; ++j) {
        float e = __expf(s[ni][j] - mx[j]);
        s[ni][j] = e; sm[j] += e;
      }
#pragma unroll
    for (int msk = 1; msk <= 8; msk <<= 1)
#pragma unroll
      for (int j = 0; j < 4; ++j) sm[j] += __shfl_xor(sm[j], msk, 64);
#pragma unroll
    for (int j = 0; j < 4; ++j) inv[j] = 1.0f / sm[j];
    __syncthreads();
#pragma unroll
    for (int ni = 0; ni < 16; ++ni)
#pragma unroll
      for (int j = 0; j < 4; ++j) {
        float pv = s[ni][j] * inv[j];
        macc[ni][j] += pv * 0.0625f;
        int r = lg * 4 + j;
        *(u16*)(pbase + r * 512 + ((ni * 32 + lr * 2) ^ ((r & 7) << 4))) = f2b(pv);
      }
    f32x4 o[4];
#pragma unroll
    for (int ni2 = 0; ni2 < 4; ++ni2) { f32x4 zv = {0.f,0.f,0.f,0.f}; o[ni2] = zv; }
#pragma unroll
    for (int ks = 0; ks < 8; ++ks) {
      bf16x8 a = *(const bf16x8*)(pbase + lr * 512 + ((ks * 64 + 16 * lg) ^ ((lr & 7) << 4)));
#pragma unroll
      for (int ni2 = 0; ni2 < 4; ++ni2) {
        int d = ni2 * 16 + lr;
        bf16x8 b = *(const bf16x8*)(vbase + d * 512 + (((ks * 4 + lg) ^ (d & 7)) << 4));
        o[ni2] = mfma16(a, b, o[ni2]);
      }
    }
#pragma unroll
    for (int ni2 = 0; ni2 < 4; ++ni2)
#pragma unroll
      for (int j = 0; j < 4; ++j) {
        int gl = l0 + w * 16 + lg * 4 + j;
        Aout[(size_t)gl * NE + n * EDIM + h * DDIM + ni2 * 16 + lr] = f2b(o[ni2][j]);
      }
  }
  float* awo = AWp + (size_t)blockIdx.z * AWSZ + (size_t)n * (LSEQ * KPDIM);
#pragma unroll
  for (int ni = 0; ni < 16; ++ni)
#pragma unroll
    for (int j = 0; j < 4; ++j) {
      int r = lg * 4 + j;
      awo[(size_t)(l0 + w * 16 + r) * KPDIM + ni * 16 + lr] = macc[ni][j];
    }
}

// ---------------------------------------------------------------------------
extern "C" void kernel_launch(void* const* d_in, const int* in_sizes, int n_in,
                              void* d_out, int out_size, void* d_ws, size_t ws_size,
                              hipStream_t stream) {
  const float* query = (const float*)d_in[0];
  const float* key   = (const float*)d_in[1];
  const float* value = (const float*)d_in[2];
  const float* ipw   = (const float*)d_in[3];
  const float* ipb   = (const float*)d_in[4];
  const float* ew    = (const float*)d_in[5];
  const float* eb    = (const float*)d_in[6];
  const float* fw    = (const float*)d_in[7];
  const float* fb    = (const float*)d_in[8];
  const float* ow    = (const float*)d_in[9];
  const float* ob    = (const float*)d_in[10];

  char* ws = (char*)d_ws;
  size_t off = 0;
  auto alloc = [&](size_t bytes) {
    void* p = ws + off;
    off += (bytes + 255) & ~(size_t)255;
    return p;
  };
  u16* qp    = (u16*)alloc((size_t)MROWS * EDIM * 2);
  u16* kp    = (u16*)alloc((size_t)MROWS * EDIM * 2);
  u16* vp    = (u16*)alloc((size_t)MROWS * EDIM * 2);
  u16* ao    = (u16*)alloc((size_t)MROWS * EDIM * 2);
  u16* kc    = (u16*)alloc((size_t)NB * KPDIM * EDIM * 2);   // (N,H,Kp,D)
  u16* vcT   = (u16*)alloc((size_t)NB * KPDIM * EDIM * 2);   // (N,H,D,Kp) swz
  u16* w_in  = (u16*)alloc((size_t)3 * EDIM * EDIM * 2);
  u16* w_eT  = (u16*)alloc((size_t)EDIM * 8 * EDIM * 2);
  u16* w_fT  = (u16*)alloc((size_t)EDIM * 8 * EDIM * 2);
  u16* w_out = (u16*)alloc((size_t)EDIM * EDIM * 2);
  float* bq  = (float*)alloc(EDIM * 4);
  size_t base_needed = off;

  size_t qkv16_b = (size_t)3 * MROWS * EDIM * 2;
  size_t part_b  = (size_t)2 * 4 * 2048 * 1024 * 4;
  bool bigX  = ws_size >= base_needed + qkv16_b;
  bool midX  = ws_size >= base_needed + part_b;
  char* X = (char*)alloc(bigX ? qkv16_b : (midX ? part_b : 0));
  u16* qkv16 = (u16*)X;
  float* part = (float*)X;
  float* awp  = (float*)X;

  float* out_f = (float*)d_out;                        // (L, N, E)
  float* aw_f  = (float*)d_out + (size_t)MROWS * EDIM; // (N, L, Kp)

  // weight prep
  wconv<<<dim3(3072), 256, 0, stream>>>(ipw, w_in, 786432, 262144, 0.125f);
  wconv<<<dim3(1024), 256, 0, stream>>>(ow, w_out, 262144, 0, 1.0f);
  wtrans<<<dim3(16384, 2), 64, 0, stream>>>(ew, fw, w_eT, w_fT);
  bscale<<<dim3(4), 256, 0, stream>>>(ipb, bq);

  // q/k/v projections
  if (bigX) {
    castqkv<<<dim3(8192, 3), 256, 0, stream>>>(query, key, value, qkv16);
    gemm256<0, 0><<<dim3(64, 4, 3), 512, 0, stream>>>(
        qkv16, qkv16 + (size_t)MROWS * EDIM, qkv16 + (size_t)2 * MROWS * EDIM,
        w_in, w_in + 1048576, w_in + 2097152,
        bq, ipb + 1024, ipb + 2048,
        qp, kp, vp, MROWS, 1024, 1);
  } else {
    gemm_bt<2, 0><<<dim3(128, 8, 3), 256, 0, stream>>>(
        query, key, value,
        w_in, w_in + 1048576, w_in + 2097152,
        bq, ipb + 1024, ipb + 2048,
        qp, kp, vp, MROWS, 1024, 1);
  }

  // conv compression of k and v -> kc (head-major) / vcT (transposed swz)
  if (bigX || midX) {
    gemm256<1, 2><<<dim3(8, 4, 8), 512, 0, stream>>>(
        kp, vp, vp,
        w_eT, w_fT, w_fT,
        eb, fb, fb,
        part, part + (size_t)4 * 2048 * 1024, part,
        NB * KPDIM, 8192, 4);
    redc<<<dim3(2048, 2), 256, 0, stream>>>(part, eb, fb, kc, vcT);
  } else {
    gemm_bt<1, 3><<<dim3(16, 8, 1), 256, 0, stream>>>(
        kp, kp, kp, w_eT, w_eT, w_eT, eb, eb, eb,
        kc, kc, kc, NB * KPDIM, 8192, 1);
    gemm_bt<1, 4><<<dim3(16, 8, 1), 256, 0, stream>>>(
        vp, vp, vp, w_fT, w_fT, w_fT, fb, fb, fb,
        vcT, vcT, vcT, NB * KPDIM, 8192, 1);
  }

  // fused attention + head-mean weights
  if (bigX) {
    attn_fused4<<<dim3(32, 8, 4), 256, 0, stream>>>(qp, kc, vcT, ao, awp);
    awred<<<dim3(4096), 256, 0, stream>>>(awp, aw_f);
  } else {
    attn_fused<<<dim3(32, 8, 1), 256, 0, stream>>>(qp, kc, vcT, ao, aw_f, 16);
  }

  // output projection -> f32 d_out
  gemm256<0, 1><<<dim3(64, 4, 1), 512, 0, stream>>>(
      ao, ao, ao,
      w_out, w_out, w_out,
      ob, ob, ob,
      out_f, out_f, out_f, MROWS, 1024, 1);
}

// Round 11
// 439.793 us; speedup vs baseline: 1.1327x; 1.1327x over previous
//
#include <hip/hip_runtime.h>

typedef unsigned short u16;
typedef u16  u16x4 __attribute__((ext_vector_type(4)));
typedef u16  u16x8 __attribute__((ext_vector_type(8)));
typedef float f32x4 __attribute__((ext_vector_type(4)));
typedef int   i32x4 __attribute__((ext_vector_type(4)));
typedef __bf16 bf16x8 __attribute__((ext_vector_type(8)));

#define LSEQ 2048
#define NB 8
#define EDIM 1024
#define HNUM 16
#define DDIM 64
#define KPDIM 256
#define NE (NB*EDIM)       /* 8192 */
#define MROWS (LSEQ*NB)    /* 16384 */
#define AWSZ ((size_t)NB*LSEQ*KPDIM)  /* 4194304 */

__device__ __forceinline__ u16 f2b(float f) {
  unsigned u = __builtin_bit_cast(unsigned, f);
  u += 0x7fffu + ((u >> 16) & 1u);
  return (u16)(u >> 16);
}

__device__ __forceinline__ void gl_lds16(const void* g, void* l) {
  __builtin_amdgcn_global_load_lds(
      (const __attribute__((address_space(1))) void*)g,
      (__attribute__((address_space(3))) void*)l, 16, 0, 0);
}

__device__ __forceinline__ f32x4 mfma16(bf16x8 a, bf16x8 b, f32x4 c) {
  return __builtin_amdgcn_mfma_f32_16x16x32_bf16(a, b, c, 0, 0, 0);
}

#define BAR()   __builtin_amdgcn_s_barrier()
#define LGKM0() asm volatile("s_waitcnt lgkmcnt(0)" ::: "memory")
#define WVM6()  asm volatile("s_waitcnt vmcnt(6)" ::: "memory")
#define WVM0()  asm volatile("s_waitcnt vmcnt(0)" ::: "memory")

// ---------------------------------------------------------------------------
// Weight prep: in_proj cast (+q scale), out_w cast, q-bias scale — one launch
// ---------------------------------------------------------------------------
__global__ void prep1(const float* __restrict__ ipw, const float* __restrict__ ow,
                      const float* __restrict__ ipb, u16* __restrict__ w_in,
                      u16* __restrict__ w_out, float* __restrict__ bq) {
  int i = blockIdx.x * blockDim.x + threadIdx.x;
  if (i < 786432) {
    f32x4 v = ((const f32x4*)ipw)[i];
    float s = (i < 262144) ? 0.125f : 1.0f;
    u16x4 o;
    o[0] = f2b(v[0] * s); o[1] = f2b(v[1] * s);
    o[2] = f2b(v[2] * s); o[3] = f2b(v[3] * s);
    ((u16x4*)w_in)[i] = o;
  }
  if (i < 262144) {
    f32x4 v = ((const f32x4*)ow)[i];
    u16x4 o;
    o[0] = f2b(v[0]); o[1] = f2b(v[1]); o[2] = f2b(v[2]); o[3] = f2b(v[3]);
    ((u16x4*)w_out)[i] = o;
  }
  if (i < 256) {
    f32x4 b = ((const f32x4*)ipb)[i];
    ((f32x4*)bq)[i] = b * 0.125f;
  }
}

// (O, I, 8) f32  ->  (O, t*E + i) bf16   (per-wave LDS transpose)
__global__ void wtrans(const float* __restrict__ ew, const float* __restrict__ fw,
                       u16* __restrict__ eT, u16* __restrict__ fT) {
  const float* src = blockIdx.y ? fw : ew;
  u16* dst = blockIdx.y ? fT : eT;
  int eo = blockIdx.x >> 4;
  int ei0 = (blockIdx.x & 15) * 64;
  int l = threadIdx.x;
  __shared__ u16 lds[8][64];
  const float* s = src + (size_t)eo * 8192 + (size_t)ei0 * 8 + l * 8;
  f32x4 a = *(const f32x4*)s;
  f32x4 b = *(const f32x4*)(s + 4);
  float v[8] = {a[0], a[1], a[2], a[3], b[0], b[1], b[2], b[3]};
#pragma unroll
  for (int t = 0; t < 8; ++t) lds[t][l] = f2b(v[t]);
  __syncthreads();
  int t = l >> 3, c = l & 7;
  i32x4 out = *(const i32x4*)&lds[t][c * 8];
  *(i32x4*)(dst + (size_t)eo * 8192 + t * 1024 + ei0 + c * 8) = out;
}

// q/k/v f32 -> bf16, contiguous [3][MROWS][E]
__global__ void castqkv(const float* __restrict__ q, const float* __restrict__ k,
                        const float* __restrict__ v, u16* __restrict__ out) {
  const float* src = blockIdx.y == 0 ? q : (blockIdx.y == 1 ? k : v);
  size_t base = (size_t)blockIdx.y * ((size_t)MROWS * EDIM);
  size_t i = ((size_t)blockIdx.x * 256 + threadIdx.x) * 8;
  f32x4 v0 = *(const f32x4*)(src + i);
  f32x4 v1 = *(const f32x4*)(src + i + 4);
  u16x8 o;
  o[0] = f2b(v0[0]); o[1] = f2b(v0[1]); o[2] = f2b(v0[2]); o[3] = f2b(v0[3]);
  o[4] = f2b(v1[0]); o[5] = f2b(v1[1]); o[6] = f2b(v1[2]); o[7] = f2b(v1[3]);
  *(u16x8*)(out + base + i) = o;
}

// sum 4 split-K partials + bias -> bf16.
// K -> head-major (N,H,Kp,D). V -> transposed (N,H,D,Kp) chunk-swizzled.
__global__ void redc(const float* __restrict__ part, const float* __restrict__ eb,
                     const float* __restrict__ fb, u16* __restrict__ kc,
                     u16* __restrict__ vcT) {
  int zc = blockIdx.y;
  const float* p = part + (size_t)zc * 4 * 2048 * 1024;
  const float* bias = zc ? fb : eb;
  size_t i = ((size_t)blockIdx.x * 256 + threadIdx.x) * 4;
  f32x4 s = *(const f32x4*)(p + i);
  s += *(const f32x4*)(p + 2097152 + i);
  s += *(const f32x4*)(p + 2 * 2097152 + i);
  s += *(const f32x4*)(p + 3 * 2097152 + i);
  int e = (int)(i & 1023);
  int row = (int)(i >> 10);           // n*256 + p
  int n = row >> 8, pp = row & 255;
  int h = e >> 6, d = e & 63;
  f32x4 b = *(const f32x4*)(bias + e);
  if (zc == 0) {
    u16x4 o;
    o[0] = f2b(s[0] + b[0]); o[1] = f2b(s[1] + b[1]);
    o[2] = f2b(s[2] + b[2]); o[3] = f2b(s[3] + b[3]);
    *(u16x4*)(kc + (((size_t)(n * HNUM + h) * KPDIM + pp) * DDIM + d)) = o;
  } else {
    size_t base = (size_t)(n * HNUM + h) * (DDIM * KPDIM);
#pragma unroll
    for (int q = 0; q < 4; ++q) {
      int dq = d + q;
      vcT[base + dq * 256 + (((pp >> 3) ^ (dq & 7)) * 8) + (pp & 7)] =
          f2b(s[q] + b[q]);
    }
  }
}

// sum the 4 head-group AW partials
__global__ void awred(const float* __restrict__ awp, float* __restrict__ aw) {
  size_t i = ((size_t)blockIdx.x * 256 + threadIdx.x) * 4;
  f32x4 s = *(const f32x4*)(awp + i);
  s += *(const f32x4*)(awp + AWSZ + i);
  s += *(const f32x4*)(awp + 2 * AWSZ + i);
  s += *(const f32x4*)(awp + 3 * AWSZ + i);
  *(f32x4*)(aw + i) = s;
}

// ---------------------------------------------------------------------------
// 256x256 GEMM — 8-phase ring schedule (r8, verified) + coalesced bf16
// epilogue (r9). Reader/stage ring and vmcnt ledger: see r8 comments.
//   AMODE 0: A bf16 rows contiguous (ld=K); AMODE 1: conv-gather
//   OUTMODE 0: bf16 C+bias (LDS-bounced); 1: f32 C+bias; 2: f32 split-K partial
// grid = (M/256, N/256, nz*kspl); block = 512 (8 waves, 2M x 4N); nt even
// ---------------------------------------------------------------------------
template<int AMODE, int OUTMODE>
__global__ __launch_bounds__(512, 2)
void gemm256(const void* A0p, const void* A1p, const void* A2p,
             const u16* B0p, const u16* B1p, const u16* B2p,
             const float* b0p, const float* b1p, const float* b2p,
             void* C0p, void* C1p, void* C2p,
             int M, int K, int kspl) {
  const int zc = blockIdx.z / kspl, sp = blockIdx.z % kspl;
  const void* Ap = zc == 0 ? A0p : (zc == 1 ? A1p : A2p);
  const u16* Bp = zc == 0 ? B0p : (zc == 1 ? B1p : B2p);
  const float* biasp = zc == 0 ? b0p : (zc == 1 ? b1p : b2p);
  void* Cp = zc == 0 ? C0p : (zc == 1 ? C1p : C2p);

  __shared__ u16 lds[2][2][2][128 * 64];  // [buf][A=0/B=1][half][r*64+swzchunk*8]

  const int tid = threadIdx.x;
  const int w = tid >> 6, lane = tid & 63;
  const int lr = lane & 15, lg = lane >> 4;
  const int wr = w >> 2, wc = w & 3;            // 2M x 4N waves
  const int m0 = blockIdx.x * 256, n0 = blockIdx.y * 256;
  const int kper = K / kspl, kbase = sp * kper, nt = kper >> 6;

  f32x4 acc[8][4];
#pragma unroll
  for (int mi = 0; mi < 8; ++mi)
#pragma unroll
    for (int ni = 0; ni < 4; ++ni) {
      f32x4 zv = {0.f, 0.f, 0.f, 0.f};
      acc[mi][ni] = zv;
    }

  // stage one 16KB half: op (0=A,1=B), half (0/1 = rows 0-127/128-255), tile kt
  auto stage_half = [&](int buf, int op, int half, int kt) {
    const int k0 = kbase + (kt << 6);
#pragma unroll
    for (int i = 0; i < 2; ++i) {
      int c = i * 512 + tid;               // 0..1023
      int r = c >> 3, j = c & 7, js = j ^ (r & 7);
      int row = half * 128 + r;
      u16* dst = &lds[buf][op][half][c * 8];
      if (op == 1) {
        gl_lds16(Bp + (size_t)(n0 + row) * K + k0 + js * 8, dst);
      } else if (AMODE == 0) {
        gl_lds16((const u16*)Ap + (size_t)(m0 + row) * K + k0 + js * 8, dst);
      } else {  // conv gather: m=(nn,p), k=(t,ei); k0 mult of 64, no 1024-cross
        int m = m0 + row;
        int nn = m >> 8, p = m & 255;
        int k = k0 + js * 8;
        gl_lds16((const u16*)Ap + (size_t)(p * 8 + (k >> 10)) * NE +
                 nn * EDIM + (k & 1023), dst);
      }
    }
  };

  auto LDA = [&](int buf, int row, int ks) -> bf16x8 {
    return *(const bf16x8*)&lds[buf][0][row >> 7]
        [(row & 127) * 64 + (((ks * 4 + lg) ^ (row & 7)) << 3)];
  };
  auto LDB = [&](int buf, int row, int ks) -> bf16x8 {
    return *(const bf16x8*)&lds[buf][1][row >> 7]
        [(row & 127) * 64 + (((ks * 4 + lg) ^ (row & 7)) << 3)];
  };

  // ---- prologue: T0 all 4 halves -> buf0; T1 B0,B1,A0 -> buf1 ----
  stage_half(0, 0, 0, 0); stage_half(0, 1, 0, 0);
  stage_half(0, 1, 1, 0); stage_half(0, 0, 1, 0);
  if (nt > 1) {
    stage_half(1, 1, 0, 1); stage_half(1, 1, 1, 1); stage_half(1, 0, 0, 1);
    WVM6();
  } else {
    WVM0();
  }
  BAR();

  for (int t = 0; t < nt; t += 2) {
    bf16x8 a0[4][2], a1[4][2], b0f[2][2], b1f[2][2];
    // ================= tile t (buf0) =================
    // ---- ph1: reads a0, b0 ----
#pragma unroll
    for (int mi = 0; mi < 4; ++mi)
#pragma unroll
      for (int ks = 0; ks < 2; ++ks)
        a0[mi][ks] = LDA(0, wr * 128 + mi * 16 + lr, ks);
#pragma unroll
    for (int ni = 0; ni < 2; ++ni)
#pragma unroll
      for (int ks = 0; ks < 2; ++ks)
        b0f[ni][ks] = LDB(0, wc * 64 + ni * 16 + lr, ks);
    stage_half(1, 0, 1, t + 1);            // (t+1).A1 (free since prev ph7)
    BAR(); LGKM0();
    __builtin_amdgcn_s_setprio(1);
#pragma unroll
    for (int mi = 0; mi < 4; ++mi)
#pragma unroll
      for (int ni = 0; ni < 2; ++ni)
#pragma unroll
        for (int ks = 0; ks < 2; ++ks)
          acc[mi][ni] = mfma16(a0[mi][ks], b0f[ni][ks], acc[mi][ni]);
    __builtin_amdgcn_s_setprio(0);
    BAR();
    // ---- ph2: reads b1; no stage ----
#pragma unroll
    for (int ni = 0; ni < 2; ++ni)
#pragma unroll
      for (int ks = 0; ks < 2; ++ks)
        b1f[ni][ks] = LDB(0, wc * 64 + (ni + 2) * 16 + lr, ks);
    BAR(); LGKM0();
    __builtin_amdgcn_s_setprio(1);
#pragma unroll
    for (int mi = 0; mi < 4; ++mi)
#pragma unroll
      for (int ni = 0; ni < 2; ++ni)
#pragma unroll
        for (int ks = 0; ks < 2; ++ks)
          acc[mi][ni + 2] = mfma16(a0[mi][ks], b1f[ni][ks], acc[mi][ni + 2]);
    __builtin_amdgcn_s_setprio(0);
    BAR();
    // ---- ph3: reads a1 ----
#pragma unroll
    for (int mi = 0; mi < 4; ++mi)
#pragma unroll
      for (int ks = 0; ks < 2; ++ks)
        a1[mi][ks] = LDA(0, wr * 128 + 64 + mi * 16 + lr, ks);
    if (t + 2 < nt) stage_half(0, 1, 0, t + 2);   // (t+2).B0 (free after ph2)
    BAR(); LGKM0();
    __builtin_amdgcn_s_setprio(1);
#pragma unroll
    for (int mi = 0; mi < 4; ++mi)
#pragma unroll
      for (int ni = 0; ni < 2; ++ni)
#pragma unroll
        for (int ks = 0; ks < 2; ++ks)
          acc[mi + 4][ni + 2] = mfma16(a1[mi][ks], b1f[ni][ks], acc[mi + 4][ni + 2]);
    __builtin_amdgcn_s_setprio(0);
    BAR();
    // ---- ph4: regs only; stage B1+A0 ----
    if (t + 2 < nt) { stage_half(0, 1, 1, t + 2); stage_half(0, 0, 0, t + 2); }
    BAR();
    __builtin_amdgcn_s_setprio(1);
#pragma unroll
    for (int mi = 0; mi < 4; ++mi)
#pragma unroll
      for (int ni = 0; ni < 2; ++ni)
#pragma unroll
        for (int ks = 0; ks < 2; ++ks)
          acc[mi + 4][ni] = mfma16(a1[mi][ks], b0f[ni][ks], acc[mi + 4][ni]);
    __builtin_amdgcn_s_setprio(0);
    if (t + 2 < nt) { WVM6(); } else { WVM0(); }
    BAR();
    // ================= tile t+1 (buf1) =================
    // ---- ph5 ----
#pragma unroll
    for (int mi = 0; mi < 4; ++mi)
#pragma unroll
      for (int ks = 0; ks < 2; ++ks)
        a0[mi][ks] = LDA(1, wr * 128 + mi * 16 + lr, ks);
#pragma unroll
    for (int ni = 0; ni < 2; ++ni)
#pragma unroll
      for (int ks = 0; ks < 2; ++ks)
        b0f[ni][ks] = LDB(1, wc * 64 + ni * 16 + lr, ks);
    if (t + 2 < nt) stage_half(0, 0, 1, t + 2);   // (t+2).A1 (free after ph3)
    BAR(); LGKM0();
    __builtin_amdgcn_s_setprio(1);
#pragma unroll
    for (int mi = 0; mi < 4; ++mi)
#pragma unroll
      for (int ni = 0; ni < 2; ++ni)
#pragma unroll
        for (int ks = 0; ks < 2; ++ks)
          acc[mi][ni] = mfma16(a0[mi][ks], b0f[ni][ks], acc[mi][ni]);
    __builtin_amdgcn_s_setprio(0);
    BAR();
    // ---- ph6: no stage ----
#pragma unroll
    for (int ni = 0; ni < 2; ++ni)
#pragma unroll
      for (int ks = 0; ks < 2; ++ks)
        b1f[ni][ks] = LDB(1, wc * 64 + (ni + 2) * 16 + lr, ks);
    BAR(); LGKM0();
    __builtin_amdgcn_s_setprio(1);
#pragma unroll
    for (int mi = 0; mi < 4; ++mi)
#pragma unroll
      for (int ni = 0; ni < 2; ++ni)
#pragma unroll
        for (int ks = 0; ks < 2; ++ks)
          acc[mi][ni + 2] = mfma16(a0[mi][ks], b1f[ni][ks], acc[mi][ni + 2]);
    __builtin_amdgcn_s_setprio(0);
    BAR();
    // ---- ph7 ----
#pragma unroll
    for (int mi = 0; mi < 4; ++mi)
#pragma unroll
      for (int ks = 0; ks < 2; ++ks)
        a1[mi][ks] = LDA(1, wr * 128 + 64 + mi * 16 + lr, ks);
    if (t + 3 < nt) stage_half(1, 1, 0, t + 3);   // (t+3).B0 (free after ph6)
    BAR(); LGKM0();
    __builtin_amdgcn_s_setprio(1);
#pragma unroll
    for (int mi = 0; mi < 4; ++mi)
#pragma unroll
      for (int ni = 0; ni < 2; ++ni)
#pragma unroll
        for (int ks = 0; ks < 2; ++ks)
          acc[mi + 4][ni + 2] = mfma16(a1[mi][ks], b1f[ni][ks], acc[mi + 4][ni + 2]);
    __builtin_amdgcn_s_setprio(0);
    BAR();
    // ---- ph8: regs only; stage B1'+A0' ----
    if (t + 3 < nt) { stage_half(1, 1, 1, t + 3); stage_half(1, 0, 0, t + 3); }
    BAR();
    __builtin_amdgcn_s_setprio(1);
#pragma unroll
    for (int mi = 0; mi < 4; ++mi)
#pragma unroll
      for (int ni = 0; ni < 2; ++ni)
#pragma unroll
        for (int ks = 0; ks < 2; ++ks)
          acc[mi + 4][ni] = mfma16(a1[mi][ks], b0f[ni][ks], acc[mi + 4][ni]);
    __builtin_amdgcn_s_setprio(0);
    if (t + 3 < nt) { WVM6(); } else { WVM0(); }
    BAR();
  }

  // ---- epilogue ----
  if (OUTMODE == 0) {
    // LDS-bounce: tile -> LDS (128 KB), then fully-coalesced 16B/lane stores.
    __syncthreads();
    u16* cw = (u16*)&lds[0][0][0][0];       // [256][256] u16
#pragma unroll
    for (int ni = 0; ni < 4; ++ni) {
      const int col = wc * 64 + ni * 16 + lr;
      const float bv = biasp[n0 + col];
#pragma unroll
      for (int mi = 0; mi < 8; ++mi)
#pragma unroll
        for (int j = 0; j < 4; ++j) {
          const int row = wr * 128 + mi * 16 + lg * 4 + j;
          cw[row * 256 + col] = f2b(acc[mi][ni][j] + bv);
        }
    }
    __syncthreads();
#pragma unroll
    for (int it = 0; it < 16; ++it) {
      int c = it * 512 + tid;
      int row = c >> 5, ch = c & 31;
      i32x4 v = *(const i32x4*)&cw[row * 256 + ch * 8];
      *(i32x4*)((u16*)Cp + (size_t)(m0 + row) * 1024 + n0 + ch * 8) = v;
    }
  } else {
#pragma unroll
    for (int ni = 0; ni < 4; ++ni) {
      const int col = n0 + wc * 64 + ni * 16 + lr;
      const float bv = (OUTMODE == 2) ? 0.f : biasp[col];
#pragma unroll
      for (int mi = 0; mi < 8; ++mi)
#pragma unroll
        for (int j = 0; j < 4; ++j) {
          const int row = m0 + wr * 128 + mi * 16 + lg * 4 + j;
          const float v = acc[mi][ni][j] + bv;
          if (OUTMODE == 2)
            ((float*)Cp)[(size_t)sp * M * 1024 + (size_t)row * 1024 + col] = v;
          else
            ((float*)Cp)[(size_t)row * 1024 + col] = v;
        }
    }
  }
}

// ---------------------------------------------------------------------------
// Legacy 128x128 GEMM — fallback paths only (small workspace)
//   OUTMODE 3: bf16+bias -> head-major (N,H,Kp,D)
//   OUTMODE 4: bf16+bias -> transposed swizzled (N,H,D,Kp)
// ---------------------------------------------------------------------------
template<int AMODE, int OUTMODE>
__global__ __launch_bounds__(256)
void gemm_bt(const void* A0p, const void* A1p, const void* A2p,
             const u16* B0p, const u16* B1p, const u16* B2p,
             const float* b0p, const float* b1p, const float* b2p,
             void* C0p, void* C1p, void* C2p,
             int M, int K, int kspl) {
  const int zc = blockIdx.z / kspl;
  const int sp = blockIdx.z % kspl;
  const void* Ap = zc == 0 ? A0p : (zc == 1 ? A1p : A2p);
  const u16* Bp = zc == 0 ? B0p : (zc == 1 ? B1p : B2p);
  const float* biasp = zc == 0 ? b0p : (zc == 1 ? b1p : b2p);
  void* Cp = zc == 0 ? C0p : (zc == 1 ? C1p : C2p);

  __shared__ u16 Alds[128 * 64];
  __shared__ u16 Blds[128 * 64];

  const int tid = threadIdx.x;
  const int w = tid >> 6, lane = tid & 63;
  const int lr = lane & 15, lg = lane >> 4;
  const int m0 = blockIdx.x * 128, n0 = blockIdx.y * 128;
  const int wr = (w >> 1) * 64, wc = (w & 1) * 64;
  const int brow = lane >> 3;
  const int bcol = (lane & 7) * 8;

  f32x4 acc[4][4];
#pragma unroll
  for (int mi = 0; mi < 4; ++mi)
#pragma unroll
    for (int ni = 0; ni < 4; ++ni) {
      f32x4 zv = {0.f, 0.f, 0.f, 0.f};
      acc[mi][ni] = zv;
    }

  const int kper = K / kspl;
  const int ktn = kper >> 6;
  const int kb = sp * kper;
  for (int kt = 0; kt < ktn; ++kt) {
    const int k0 = kb + (kt << 6);
    __syncthreads();
#pragma unroll
    for (int i = 0; i < 4; ++i) {
      const int c = w * 4 + i;
      const int row = c * 8 + brow;
      gl_lds16(Bp + (size_t)(n0 + row) * K + k0 + bcol, &Blds[c * 512]);
    }
    if (AMODE == 2) {
      const float* Af = (const float*)Ap;
#pragma unroll
      for (int i = 0; i < 4; ++i) {
        const int c = i * 256 + tid;
        const int row = c >> 3, k8 = (c & 7) * 8;
        const float* s = Af + (size_t)(m0 + row) * K + k0 + k8;
        f32x4 v0 = *(const f32x4*)s;
        f32x4 v1 = *(const f32x4*)(s + 4);
        u16x8 pk;
        pk[0] = f2b(v0[0]); pk[1] = f2b(v0[1]); pk[2] = f2b(v0[2]); pk[3] = f2b(v0[3]);
        pk[4] = f2b(v1[0]); pk[5] = f2b(v1[1]); pk[6] = f2b(v1[2]); pk[7] = f2b(v1[3]);
        *(u16x8*)&Alds[row * 64 + k8] = pk;
      }
    } else if (AMODE == 0) {
      const u16* Ab = (const u16*)Ap;
#pragma unroll
      for (int i = 0; i < 4; ++i) {
        const int c = w * 4 + i;
        const int row = c * 8 + brow;
        gl_lds16(Ab + (size_t)(m0 + row) * K + k0 + bcol, &Alds[c * 512]);
      }
    } else {
      const u16* Ab = (const u16*)Ap;
#pragma unroll
      for (int i = 0; i < 4; ++i) {
        const int c = w * 4 + i;
        const int m = m0 + c * 8 + brow;
        const int nn = m >> 8, p = m & 255;
        const int k = k0 + bcol;
        gl_lds16(Ab + (size_t)(p * 8 + (k >> 10)) * NE + nn * EDIM + (k & 1023),
                 &Alds[c * 512]);
      }
    }
    __syncthreads();
#pragma unroll
    for (int ks = 0; ks < 2; ++ks) {
      bf16x8 af[4], bf[4];
#pragma unroll
      for (int mi = 0; mi < 4; ++mi)
        af[mi] = *(const bf16x8*)&Alds[(wr + mi * 16 + lr) * 64 + ks * 32 + lg * 8];
#pragma unroll
      for (int ni = 0; ni < 4; ++ni)
        bf[ni] = *(const bf16x8*)&Blds[(wc + ni * 16 + lr) * 64 + ks * 32 + lg * 8];
#pragma unroll
      for (int mi = 0; mi < 4; ++mi)
#pragma unroll
        for (int ni = 0; ni < 4; ++ni)
          acc[mi][ni] = mfma16(af[mi], bf[ni], acc[mi][ni]);
    }
  }
#pragma unroll
  for (int ni = 0; ni < 4; ++ni) {
    const int col = n0 + wc + ni * 16 + lr;
    const float bv = (OUTMODE == 2) ? 0.f : biasp[col];
#pragma unroll
    for (int mi = 0; mi < 4; ++mi)
#pragma unroll
      for (int j = 0; j < 4; ++j) {
        const int row = m0 + wr + mi * 16 + lg * 4 + j;
        const float v = acc[mi][ni][j] + bv;
        if (OUTMODE == 4) {
          const int nn = row >> 8, pp = row & 255, h = col >> 6, d = col & 63;
          ((u16*)Cp)[(size_t)(nn * HNUM + h) * (DDIM * KPDIM) + d * 256 +
                     (((pp >> 3) ^ (d & 7)) * 8) + (pp & 7)] = f2b(v);
        } else if (OUTMODE == 3) {
          const int nn = row >> 8, pp = row & 255, h = col >> 6, d = col & 63;
          ((u16*)Cp)[((size_t)(nn * HNUM + h) * KPDIM + pp) * DDIM + d] = f2b(v);
        } else if (OUTMODE == 2)
          ((float*)Cp)[(size_t)sp * M * 1024 + (size_t)row * 1024 + col] = v;
        else if (OUTMODE == 1)
          ((float*)Cp)[(size_t)row * 1024 + col] = v;
        else
          ((u16*)Cp)[(size_t)row * 1024 + col] = f2b(v);
      }
  }
}

// ---------------------------------------------------------------------------
// Fused attention v3 (r9-verified structure; raw-P micro-opt from r10):
// block = (64 q-rows, n, head-group), hpg heads. Kc (N,H,Kp,D);
// VcT (N,H,D,Kp) pre-transposed + chunk-swizzled in global. LDS 64 KB
// (K/P overlay 32K + V^T 32K) -> 2 blocks/CU, 2 waves/SIMD (the TLP that
// r10's 128KB prefetch variant destroyed — 74 vs 158 µs).
// P stored as RAW exp (<=1); 1/sum folded into O-write and head-mean FMA.
// ---------------------------------------------------------------------------
__global__ __launch_bounds__(256)
void attn_fused(const u16* __restrict__ Q, const u16* __restrict__ Kc,
                const u16* __restrict__ VcT, u16* __restrict__ Aout,
                float* __restrict__ AWp, int hpg) {
  __shared__ u16 Ares[256 * 64];   // K [p][d] chunk-swizzled -> P quarters
  __shared__ u16 Bres[64 * 256];   // V^T [d][p] chunk-swizzled
  const int tid = threadIdx.x;
  const int w = tid >> 6, lane = tid & 63;
  const int lr = lane & 15, lg = lane >> 4;
  const int n = blockIdx.y;
  const int l0 = blockIdx.x * 64;
  const int lrow = l0 + w * 16 + lr;
  char* kbase = (char*)Ares;
  char* vbase = (char*)Bres;
  char* pbase = (char*)Ares + w * 8192;

  f32x4 macc[16];
#pragma unroll
  for (int ni = 0; ni < 16; ++ni) { f32x4 zv = {0.f,0.f,0.f,0.f}; macc[ni] = zv; }

  for (int hh = 0; hh < hpg; ++hh) {
    const int h = blockIdx.z * hpg + hh;
    const u16* kh = Kc + (size_t)(n * HNUM + h) * (KPDIM * DDIM);
    const u16* vh = VcT + (size_t)(n * HNUM + h) * (DDIM * KPDIM);
    __syncthreads();
#pragma unroll
    for (int it = 0; it < 8; ++it) {
      int c = it * 256 + tid;
      int p = c >> 3, j = c & 7;
      gl_lds16(kh + p * 64 + ((j ^ (p & 7)) << 3), kbase + c * 16);
    }
#pragma unroll
    for (int it = 0; it < 8; ++it) {
      int c = it * 256 + tid;
      gl_lds16(vh + c * 8, vbase + c * 16);
    }
    const u16* qp = Q + (size_t)lrow * NE + n * EDIM + h * DDIM + lg * 8;
    bf16x8 aq0 = *(const bf16x8*)qp;
    bf16x8 aq1 = *(const bf16x8*)(qp + 32);
    __syncthreads();
    f32x4 s[16];
#pragma unroll
    for (int ni = 0; ni < 16; ++ni) { f32x4 zv = {0.f,0.f,0.f,0.f}; s[ni] = zv; }
#pragma unroll
    for (int ni = 0; ni < 16; ++ni) {
      int row = ni * 16 + lr;
      const char* kr = kbase + row * 128;
      bf16x8 b0 = *(const bf16x8*)(kr + ((lg ^ (row & 7)) << 4));
      bf16x8 b1 = *(const bf16x8*)(kr + (((4 + lg) ^ (row & 7)) << 4));
      s[ni] = mfma16(aq0, b0, s[ni]);
      s[ni] = mfma16(aq1, b1, s[ni]);
    }
    float mx[4], sm[4], inv[4], invs[4];
#pragma unroll
    for (int j = 0; j < 4; ++j) mx[j] = -1e30f;
#pragma unroll
    for (int ni = 0; ni < 16; ++ni)
#pragma unroll
      for (int j = 0; j < 4; ++j) mx[j] = fmaxf(mx[j], s[ni][j]);
#pragma unroll
    for (int msk = 1; msk <= 8; msk <<= 1)
#pragma unroll
      for (int j = 0; j < 4; ++j) mx[j] = fmaxf(mx[j], __shfl_xor(mx[j], msk, 64));
#pragma unroll
    for (int j = 0; j < 4; ++j) sm[j] = 0.f;
#pragma unroll
    for (int ni = 0; ni < 16; ++ni)
#pragma unroll
      for (int j = 0; j < 4; ++j) {
        float e = __expf(s[ni][j] - mx[j]);
        s[ni][j] = e; sm[j] += e;
      }
#pragma unroll
    for (int msk = 1; msk <= 8; msk <<= 1)
#pragma unroll
      for (int j = 0; j < 4; ++j) sm[j] += __shfl_xor(sm[j], msk, 64);
#pragma unroll
    for (int j = 0; j < 4; ++j) { inv[j] = 1.0f / sm[j]; invs[j] = inv[j] * 0.0625f; }
    __syncthreads();   // all waves done reading K; P may overwrite it
    // ---- head-mean FMA + store RAW P (bf16, per-wave quarter of Ares) ----
#pragma unroll
    for (int ni = 0; ni < 16; ++ni)
#pragma unroll
      for (int j = 0; j < 4; ++j) {
        macc[ni][j] += s[ni][j] * invs[j];
        int r = lg * 4 + j;
        *(u16*)(pbase + r * 512 + ((ni * 32 + lr * 2) ^ ((r & 7) << 4))) =
            f2b(s[ni][j]);
      }
    // ---- O = Praw @ V, scaled by inv (P wave-private; no barrier) ----
    f32x4 o[4];
#pragma unroll
    for (int ni2 = 0; ni2 < 4; ++ni2) { f32x4 zv = {0.f,0.f,0.f,0.f}; o[ni2] = zv; }
#pragma unroll
    for (int ks = 0; ks < 8; ++ks) {
      bf16x8 a = *(const bf16x8*)(pbase + lr * 512 + ((ks * 64 + 16 * lg) ^ ((lr & 7) << 4)));
#pragma unroll
      for (int ni2 = 0; ni2 < 4; ++ni2) {
        int d = ni2 * 16 + lr;
        bf16x8 b = *(const bf16x8*)(vbase + d * 512 + (((ks * 4 + lg) ^ (d & 7)) << 4));
        o[ni2] = mfma16(a, b, o[ni2]);
      }
    }
#pragma unroll
    for (int ni2 = 0; ni2 < 4; ++ni2)
#pragma unroll
      for (int j = 0; j < 4; ++j) {
        int gl = l0 + w * 16 + lg * 4 + j;
        Aout[(size_t)gl * NE + n * EDIM + h * DDIM + ni2 * 16 + lr] =
            f2b(o[ni2][j] * inv[j]);
      }
  }
  float* awo = AWp + (size_t)blockIdx.z * AWSZ + (size_t)n * (LSEQ * KPDIM);
#pragma unroll
  for (int ni = 0; ni < 16; ++ni)
#pragma unroll
    for (int j = 0; j < 4; ++j) {
      int r = lg * 4 + j;
      awo[(size_t)(l0 + w * 16 + r) * KPDIM + ni * 16 + lr] = macc[ni][j];
    }
}

// ---------------------------------------------------------------------------
extern "C" void kernel_launch(void* const* d_in, const int* in_sizes, int n_in,
                              void* d_out, int out_size, void* d_ws, size_t ws_size,
                              hipStream_t stream) {
  const float* query = (const float*)d_in[0];
  const float* key   = (const float*)d_in[1];
  const float* value = (const float*)d_in[2];
  const float* ipw   = (const float*)d_in[3];
  const float* ipb   = (const float*)d_in[4];
  const float* ew    = (const float*)d_in[5];
  const float* eb    = (const float*)d_in[6];
  const float* fw    = (const float*)d_in[7];
  const float* fb    = (const float*)d_in[8];
  const float* ow    = (const float*)d_in[9];
  const float* ob    = (const float*)d_in[10];

  char* ws = (char*)d_ws;
  size_t off = 0;
  auto alloc = [&](size_t bytes) {
    void* p = ws + off;
    off += (bytes + 255) & ~(size_t)255;
    return p;
  };
  u16* qp    = (u16*)alloc((size_t)MROWS * EDIM * 2);
  u16* kp    = (u16*)alloc((size_t)MROWS * EDIM * 2);
  u16* vp    = (u16*)alloc((size_t)MROWS * EDIM * 2);
  u16* ao    = (u16*)alloc((size_t)MROWS * EDIM * 2);
  u16* kc    = (u16*)alloc((size_t)NB * KPDIM * EDIM * 2);   // (N,H,Kp,D)
  u16* vcT   = (u16*)alloc((size_t)NB * KPDIM * EDIM * 2);   // (N,H,D,Kp) swz
  u16* w_in  = (u16*)alloc((size_t)3 * EDIM * EDIM * 2);
  u16* w_eT  = (u16*)alloc((size_t)EDIM * 8 * EDIM * 2);
  u16* w_fT  = (u16*)alloc((size_t)EDIM * 8 * EDIM * 2);
  u16* w_out = (u16*)alloc((size_t)EDIM * EDIM * 2);
  float* bq  = (float*)alloc(EDIM * 4);
  size_t base_needed = off;

  size_t qkv16_b = (size_t)3 * MROWS * EDIM * 2;
  size_t part_b  = (size_t)2 * 4 * 2048 * 1024 * 4;
  bool bigX  = ws_size >= base_needed + qkv16_b;
  bool midX  = ws_size >= base_needed + part_b;
  char* X = (char*)alloc(bigX ? qkv16_b : (midX ? part_b : 0));
  u16* qkv16 = (u16*)X;
  float* part = (float*)X;
  float* awp  = (float*)X;

  float* out_f = (float*)d_out;                        // (L, N, E)
  float* aw_f  = (float*)d_out + (size_t)MROWS * EDIM; // (N, L, Kp)

  // weight prep (merged) + conv-weight transpose
  prep1<<<dim3(3072), 256, 0, stream>>>(ipw, ow, ipb, w_in, w_out, bq);
  wtrans<<<dim3(16384, 2), 64, 0, stream>>>(ew, fw, w_eT, w_fT);

  // q/k/v projections
  if (bigX) {
    castqkv<<<dim3(8192, 3), 256, 0, stream>>>(query, key, value, qkv16);
    gemm256<0, 0><<<dim3(64, 4, 3), 512, 0, stream>>>(
        qkv16, qkv16 + (size_t)MROWS * EDIM, qkv16 + (size_t)2 * MROWS * EDIM,
        w_in, w_in + 1048576, w_in + 2097152,
        bq, ipb + 1024, ipb + 2048,
        qp, kp, vp, MROWS, 1024, 1);
  } else {
    gemm_bt<2, 0><<<dim3(128, 8, 3), 256, 0, stream>>>(
        query, key, value,
        w_in, w_in + 1048576, w_in + 2097152,
        bq, ipb + 1024, ipb + 2048,
        qp, kp, vp, MROWS, 1024, 1);
  }

  // conv compression of k and v -> kc (head-major) / vcT (transposed swz)
  if (bigX || midX) {
    gemm256<1, 2><<<dim3(8, 4, 8), 512, 0, stream>>>(
        kp, vp, vp,
        w_eT, w_fT, w_fT,
        eb, fb, fb,
        part, part + (size_t)4 * 2048 * 1024, part,
        NB * KPDIM, 8192, 4);
    redc<<<dim3(2048, 2), 256, 0, stream>>>(part, eb, fb, kc, vcT);
  } else {
    gemm_bt<1, 3><<<dim3(16, 8, 1), 256, 0, stream>>>(
        kp, kp, kp, w_eT, w_eT, w_eT, eb, eb, eb,
        kc, kc, kc, NB * KPDIM, 8192, 1);
    gemm_bt<1, 4><<<dim3(16, 8, 1), 256, 0, stream>>>(
        vp, vp, vp, w_fT, w_fT, w_fT, fb, fb, fb,
        vcT, vcT, vcT, NB * KPDIM, 8192, 1);
  }

  // fused attention + head-mean weights
  if (bigX) {
    attn_fused<<<dim3(32, 8, 4), 256, 0, stream>>>(qp, kc, vcT, ao, awp, 4);
    awred<<<dim3(4096), 256, 0, stream>>>(awp, aw_f);
  } else {
    attn_fused<<<dim3(32, 8, 1), 256, 0, stream>>>(qp, kc, vcT, ao, aw_f, 16);
  }

  // output projection -> f32 d_out
  gemm256<0, 1><<<dim3(64, 4, 1), 512, 0, stream>>>(
      ao, ao, ao,
      w_out, w_out, w_out,
      ob, ob, ob,
      out_f, out_f, out_f, MROWS, 1024, 1);
}

// Round 12
// 428.186 us; speedup vs baseline: 1.1634x; 1.0271x over previous
//
#include <hip/hip_runtime.h>

typedef unsigned short u16;
typedef u16  u16x4 __attribute__((ext_vector_type(4)));
typedef u16  u16x8 __attribute__((ext_vector_type(8)));
typedef float f32x4 __attribute__((ext_vector_type(4)));
typedef int   i32x4 __attribute__((ext_vector_type(4)));
typedef __bf16 bf16x8 __attribute__((ext_vector_type(8)));

#define LSEQ 2048
#define NB 8
#define EDIM 1024
#define HNUM 16
#define DDIM 64
#define KPDIM 256
#define NE (NB*EDIM)       /* 8192 */
#define MROWS (LSEQ*NB)    /* 16384 */
#define AWSZ ((size_t)NB*LSEQ*KPDIM)  /* 4194304 */

__device__ __forceinline__ u16 f2b(float f) {
  unsigned u = __builtin_bit_cast(unsigned, f);
  u += 0x7fffu + ((u >> 16) & 1u);
  return (u16)(u >> 16);
}

__device__ __forceinline__ unsigned pk2(float a, float b) {
  return (unsigned)f2b(a) | ((unsigned)f2b(b) << 16);
}

__device__ __forceinline__ void gl_lds16(const void* g, void* l) {
  __builtin_amdgcn_global_load_lds(
      (const __attribute__((address_space(1))) void*)g,
      (__attribute__((address_space(3))) void*)l, 16, 0, 0);
}

__device__ __forceinline__ f32x4 mfma16(bf16x8 a, bf16x8 b, f32x4 c) {
  return __builtin_amdgcn_mfma_f32_16x16x32_bf16(a, b, c, 0, 0, 0);
}

#define BAR()   __builtin_amdgcn_s_barrier()
#define LGKM0() asm volatile("s_waitcnt lgkmcnt(0)" ::: "memory")
#define WVM6()  asm volatile("s_waitcnt vmcnt(6)" ::: "memory")
#define WVM0()  asm volatile("s_waitcnt vmcnt(0)" ::: "memory")

// ---------------------------------------------------------------------------
// Weight prep: in_proj cast (+q scale), out_w cast, q-bias scale — one launch
// ---------------------------------------------------------------------------
__global__ void prep1(const float* __restrict__ ipw, const float* __restrict__ ow,
                      const float* __restrict__ ipb, u16* __restrict__ w_in,
                      u16* __restrict__ w_out, float* __restrict__ bq) {
  int i = blockIdx.x * blockDim.x + threadIdx.x;
  if (i < 786432) {
    f32x4 v = ((const f32x4*)ipw)[i];
    float s = (i < 262144) ? 0.125f : 1.0f;
    u16x4 o;
    o[0] = f2b(v[0] * s); o[1] = f2b(v[1] * s);
    o[2] = f2b(v[2] * s); o[3] = f2b(v[3] * s);
    ((u16x4*)w_in)[i] = o;
  }
  if (i < 262144) {
    f32x4 v = ((const f32x4*)ow)[i];
    u16x4 o;
    o[0] = f2b(v[0]); o[1] = f2b(v[1]); o[2] = f2b(v[2]); o[3] = f2b(v[3]);
    ((u16x4*)w_out)[i] = o;
  }
  if (i < 256) {
    f32x4 b = ((const f32x4*)ipb)[i];
    ((f32x4*)bq)[i] = b * 0.125f;
  }
}

// (O, I, 8) f32  ->  (O, t*E + i) bf16   (per-wave LDS transpose)
__global__ void wtrans(const float* __restrict__ ew, const float* __restrict__ fw,
                       u16* __restrict__ eT, u16* __restrict__ fT) {
  const float* src = blockIdx.y ? fw : ew;
  u16* dst = blockIdx.y ? fT : eT;
  int eo = blockIdx.x >> 4;
  int ei0 = (blockIdx.x & 15) * 64;
  int l = threadIdx.x;
  __shared__ u16 lds[8][64];
  const float* s = src + (size_t)eo * 8192 + (size_t)ei0 * 8 + l * 8;
  f32x4 a = *(const f32x4*)s;
  f32x4 b = *(const f32x4*)(s + 4);
  float v[8] = {a[0], a[1], a[2], a[3], b[0], b[1], b[2], b[3]};
#pragma unroll
  for (int t = 0; t < 8; ++t) lds[t][l] = f2b(v[t]);
  __syncthreads();
  int t = l >> 3, c = l & 7;
  i32x4 out = *(const i32x4*)&lds[t][c * 8];
  *(i32x4*)(dst + (size_t)eo * 8192 + t * 1024 + ei0 + c * 8) = out;
}

// q/k/v f32 -> bf16, contiguous [3][MROWS][E]
__global__ void castqkv(const float* __restrict__ q, const float* __restrict__ k,
                        const float* __restrict__ v, u16* __restrict__ out) {
  const float* src = blockIdx.y == 0 ? q : (blockIdx.y == 1 ? k : v);
  size_t base = (size_t)blockIdx.y * ((size_t)MROWS * EDIM);
  size_t i = ((size_t)blockIdx.x * 256 + threadIdx.x) * 8;
  f32x4 v0 = *(const f32x4*)(src + i);
  f32x4 v1 = *(const f32x4*)(src + i + 4);
  u16x8 o;
  o[0] = f2b(v0[0]); o[1] = f2b(v0[1]); o[2] = f2b(v0[2]); o[3] = f2b(v0[3]);
  o[4] = f2b(v1[0]); o[5] = f2b(v1[1]); o[6] = f2b(v1[2]); o[7] = f2b(v1[3]);
  *(u16x8*)(out + base + i) = o;
}

// sum 4 split-K partials + bias -> bf16.
// K -> head-major (N,H,Kp,D). V -> transposed (N,H,D,Kp) chunk-swizzled.
__global__ void redc(const float* __restrict__ part, const float* __restrict__ eb,
                     const float* __restrict__ fb, u16* __restrict__ kc,
                     u16* __restrict__ vcT) {
  int zc = blockIdx.y;
  const float* p = part + (size_t)zc * 4 * 2048 * 1024;
  const float* bias = zc ? fb : eb;
  size_t i = ((size_t)blockIdx.x * 256 + threadIdx.x) * 4;
  f32x4 s = *(const f32x4*)(p + i);
  s += *(const f32x4*)(p + 2097152 + i);
  s += *(const f32x4*)(p + 2 * 2097152 + i);
  s += *(const f32x4*)(p + 3 * 2097152 + i);
  int e = (int)(i & 1023);
  int row = (int)(i >> 10);           // n*256 + p
  int n = row >> 8, pp = row & 255;
  int h = e >> 6, d = e & 63;
  f32x4 b = *(const f32x4*)(bias + e);
  if (zc == 0) {
    u16x4 o;
    o[0] = f2b(s[0] + b[0]); o[1] = f2b(s[1] + b[1]);
    o[2] = f2b(s[2] + b[2]); o[3] = f2b(s[3] + b[3]);
    *(u16x4*)(kc + (((size_t)(n * HNUM + h) * KPDIM + pp) * DDIM + d)) = o;
  } else {
    size_t base = (size_t)(n * HNUM + h) * (DDIM * KPDIM);
#pragma unroll
    for (int q = 0; q < 4; ++q) {
      int dq = d + q;
      vcT[base + dq * 256 + (((pp >> 3) ^ (dq & 7)) * 8) + (pp & 7)] =
          f2b(s[q] + b[q]);
    }
  }
}

// sum the 4 head-group AW partials
__global__ void awred(const float* __restrict__ awp, float* __restrict__ aw) {
  size_t i = ((size_t)blockIdx.x * 256 + threadIdx.x) * 4;
  f32x4 s = *(const f32x4*)(awp + i);
  s += *(const f32x4*)(awp + AWSZ + i);
  s += *(const f32x4*)(awp + 2 * AWSZ + i);
  s += *(const f32x4*)(awp + 3 * AWSZ + i);
  *(f32x4*)(aw + i) = s;
}

// ---------------------------------------------------------------------------
// 256x256 GEMM — 8-phase ring schedule (r8, verified) + coalesced bf16
// epilogue (r9). Reader/stage ring and vmcnt ledger: see r8 comments.
//   AMODE 0: A bf16 rows contiguous (ld=K); AMODE 1: conv-gather
//   OUTMODE 0: bf16 C+bias (LDS-bounced); 1: f32 C+bias; 2: f32 split-K partial
// grid = (M/256, N/256, nz*kspl); block = 512 (8 waves, 2M x 4N); nt even
// ---------------------------------------------------------------------------
template<int AMODE, int OUTMODE>
__global__ __launch_bounds__(512, 2)
void gemm256(const void* A0p, const void* A1p, const void* A2p,
             const u16* B0p, const u16* B1p, const u16* B2p,
             const float* b0p, const float* b1p, const float* b2p,
             void* C0p, void* C1p, void* C2p,
             int M, int K, int kspl) {
  const int zc = blockIdx.z / kspl, sp = blockIdx.z % kspl;
  const void* Ap = zc == 0 ? A0p : (zc == 1 ? A1p : A2p);
  const u16* Bp = zc == 0 ? B0p : (zc == 1 ? B1p : B2p);
  const float* biasp = zc == 0 ? b0p : (zc == 1 ? b1p : b2p);
  void* Cp = zc == 0 ? C0p : (zc == 1 ? C1p : C2p);

  __shared__ u16 lds[2][2][2][128 * 64];  // [buf][A=0/B=1][half][r*64+swzchunk*8]

  const int tid = threadIdx.x;
  const int w = tid >> 6, lane = tid & 63;
  const int lr = lane & 15, lg = lane >> 4;
  const int wr = w >> 2, wc = w & 3;            // 2M x 4N waves
  const int m0 = blockIdx.x * 256, n0 = blockIdx.y * 256;
  const int kper = K / kspl, kbase = sp * kper, nt = kper >> 6;

  f32x4 acc[8][4];
#pragma unroll
  for (int mi = 0; mi < 8; ++mi)
#pragma unroll
    for (int ni = 0; ni < 4; ++ni) {
      f32x4 zv = {0.f, 0.f, 0.f, 0.f};
      acc[mi][ni] = zv;
    }

  // stage one 16KB half: op (0=A,1=B), half (0/1 = rows 0-127/128-255), tile kt
  auto stage_half = [&](int buf, int op, int half, int kt) {
    const int k0 = kbase + (kt << 6);
#pragma unroll
    for (int i = 0; i < 2; ++i) {
      int c = i * 512 + tid;               // 0..1023
      int r = c >> 3, j = c & 7, js = j ^ (r & 7);
      int row = half * 128 + r;
      u16* dst = &lds[buf][op][half][c * 8];
      if (op == 1) {
        gl_lds16(Bp + (size_t)(n0 + row) * K + k0 + js * 8, dst);
      } else if (AMODE == 0) {
        gl_lds16((const u16*)Ap + (size_t)(m0 + row) * K + k0 + js * 8, dst);
      } else {  // conv gather: m=(nn,p), k=(t,ei); k0 mult of 64, no 1024-cross
        int m = m0 + row;
        int nn = m >> 8, p = m & 255;
        int k = k0 + js * 8;
        gl_lds16((const u16*)Ap + (size_t)(p * 8 + (k >> 10)) * NE +
                 nn * EDIM + (k & 1023), dst);
      }
    }
  };

  auto LDA = [&](int buf, int row, int ks) -> bf16x8 {
    return *(const bf16x8*)&lds[buf][0][row >> 7]
        [(row & 127) * 64 + (((ks * 4 + lg) ^ (row & 7)) << 3)];
  };
  auto LDB = [&](int buf, int row, int ks) -> bf16x8 {
    return *(const bf16x8*)&lds[buf][1][row >> 7]
        [(row & 127) * 64 + (((ks * 4 + lg) ^ (row & 7)) << 3)];
  };

  // ---- prologue: T0 all 4 halves -> buf0; T1 B0,B1,A0 -> buf1 ----
  stage_half(0, 0, 0, 0); stage_half(0, 1, 0, 0);
  stage_half(0, 1, 1, 0); stage_half(0, 0, 1, 0);
  if (nt > 1) {
    stage_half(1, 1, 0, 1); stage_half(1, 1, 1, 1); stage_half(1, 0, 0, 1);
    WVM6();
  } else {
    WVM0();
  }
  BAR();

  for (int t = 0; t < nt; t += 2) {
    bf16x8 a0[4][2], a1[4][2], b0f[2][2], b1f[2][2];
    // ================= tile t (buf0) =================
    // ---- ph1: reads a0, b0 ----
#pragma unroll
    for (int mi = 0; mi < 4; ++mi)
#pragma unroll
      for (int ks = 0; ks < 2; ++ks)
        a0[mi][ks] = LDA(0, wr * 128 + mi * 16 + lr, ks);
#pragma unroll
    for (int ni = 0; ni < 2; ++ni)
#pragma unroll
      for (int ks = 0; ks < 2; ++ks)
        b0f[ni][ks] = LDB(0, wc * 64 + ni * 16 + lr, ks);
    stage_half(1, 0, 1, t + 1);            // (t+1).A1 (free since prev ph7)
    BAR(); LGKM0();
    __builtin_amdgcn_s_setprio(1);
#pragma unroll
    for (int mi = 0; mi < 4; ++mi)
#pragma unroll
      for (int ni = 0; ni < 2; ++ni)
#pragma unroll
        for (int ks = 0; ks < 2; ++ks)
          acc[mi][ni] = mfma16(a0[mi][ks], b0f[ni][ks], acc[mi][ni]);
    __builtin_amdgcn_s_setprio(0);
    BAR();
    // ---- ph2: reads b1; no stage ----
#pragma unroll
    for (int ni = 0; ni < 2; ++ni)
#pragma unroll
      for (int ks = 0; ks < 2; ++ks)
        b1f[ni][ks] = LDB(0, wc * 64 + (ni + 2) * 16 + lr, ks);
    BAR(); LGKM0();
    __builtin_amdgcn_s_setprio(1);
#pragma unroll
    for (int mi = 0; mi < 4; ++mi)
#pragma unroll
      for (int ni = 0; ni < 2; ++ni)
#pragma unroll
        for (int ks = 0; ks < 2; ++ks)
          acc[mi][ni + 2] = mfma16(a0[mi][ks], b1f[ni][ks], acc[mi][ni + 2]);
    __builtin_amdgcn_s_setprio(0);
    BAR();
    // ---- ph3: reads a1 ----
#pragma unroll
    for (int mi = 0; mi < 4; ++mi)
#pragma unroll
      for (int ks = 0; ks < 2; ++ks)
        a1[mi][ks] = LDA(0, wr * 128 + 64 + mi * 16 + lr, ks);
    if (t + 2 < nt) stage_half(0, 1, 0, t + 2);   // (t+2).B0 (free after ph2)
    BAR(); LGKM0();
    __builtin_amdgcn_s_setprio(1);
#pragma unroll
    for (int mi = 0; mi < 4; ++mi)
#pragma unroll
      for (int ni = 0; ni < 2; ++ni)
#pragma unroll
        for (int ks = 0; ks < 2; ++ks)
          acc[mi + 4][ni + 2] = mfma16(a1[mi][ks], b1f[ni][ks], acc[mi + 4][ni + 2]);
    __builtin_amdgcn_s_setprio(0);
    BAR();
    // ---- ph4: regs only; stage B1+A0 ----
    if (t + 2 < nt) { stage_half(0, 1, 1, t + 2); stage_half(0, 0, 0, t + 2); }
    BAR();
    __builtin_amdgcn_s_setprio(1);
#pragma unroll
    for (int mi = 0; mi < 4; ++mi)
#pragma unroll
      for (int ni = 0; ni < 2; ++ni)
#pragma unroll
        for (int ks = 0; ks < 2; ++ks)
          acc[mi + 4][ni] = mfma16(a1[mi][ks], b0f[ni][ks], acc[mi + 4][ni]);
    __builtin_amdgcn_s_setprio(0);
    if (t + 2 < nt) { WVM6(); } else { WVM0(); }
    BAR();
    // ================= tile t+1 (buf1) =================
    // ---- ph5 ----
#pragma unroll
    for (int mi = 0; mi < 4; ++mi)
#pragma unroll
      for (int ks = 0; ks < 2; ++ks)
        a0[mi][ks] = LDA(1, wr * 128 + mi * 16 + lr, ks);
#pragma unroll
    for (int ni = 0; ni < 2; ++ni)
#pragma unroll
      for (int ks = 0; ks < 2; ++ks)
        b0f[ni][ks] = LDB(1, wc * 64 + ni * 16 + lr, ks);
    if (t + 2 < nt) stage_half(0, 0, 1, t + 2);   // (t+2).A1 (free after ph3)
    BAR(); LGKM0();
    __builtin_amdgcn_s_setprio(1);
#pragma unroll
    for (int mi = 0; mi < 4; ++mi)
#pragma unroll
      for (int ni = 0; ni < 2; ++ni)
#pragma unroll
        for (int ks = 0; ks < 2; ++ks)
          acc[mi][ni] = mfma16(a0[mi][ks], b0f[ni][ks], acc[mi][ni]);
    __builtin_amdgcn_s_setprio(0);
    BAR();
    // ---- ph6: no stage ----
#pragma unroll
    for (int ni = 0; ni < 2; ++ni)
#pragma unroll
      for (int ks = 0; ks < 2; ++ks)
        b1f[ni][ks] = LDB(1, wc * 64 + (ni + 2) * 16 + lr, ks);
    BAR(); LGKM0();
    __builtin_amdgcn_s_setprio(1);
#pragma unroll
    for (int mi = 0; mi < 4; ++mi)
#pragma unroll
      for (int ni = 0; ni < 2; ++ni)
#pragma unroll
        for (int ks = 0; ks < 2; ++ks)
          acc[mi][ni + 2] = mfma16(a0[mi][ks], b1f[ni][ks], acc[mi][ni + 2]);
    __builtin_amdgcn_s_setprio(0);
    BAR();
    // ---- ph7 ----
#pragma unroll
    for (int mi = 0; mi < 4; ++mi)
#pragma unroll
      for (int ks = 0; ks < 2; ++ks)
        a1[mi][ks] = LDA(1, wr * 128 + 64 + mi * 16 + lr, ks);
    if (t + 3 < nt) stage_half(1, 1, 0, t + 3);   // (t+3).B0 (free after ph6)
    BAR(); LGKM0();
    __builtin_amdgcn_s_setprio(1);
#pragma unroll
    for (int mi = 0; mi < 4; ++mi)
#pragma unroll
      for (int ni = 0; ni < 2; ++ni)
#pragma unroll
        for (int ks = 0; ks < 2; ++ks)
          acc[mi + 4][ni + 2] = mfma16(a1[mi][ks], b1f[ni][ks], acc[mi + 4][ni + 2]);
    __builtin_amdgcn_s_setprio(0);
    BAR();
    // ---- ph8: regs only; stage B1'+A0' ----
    if (t + 3 < nt) { stage_half(1, 1, 1, t + 3); stage_half(1, 0, 0, t + 3); }
    BAR();
    __builtin_amdgcn_s_setprio(1);
#pragma unroll
    for (int mi = 0; mi < 4; ++mi)
#pragma unroll
      for (int ni = 0; ni < 2; ++ni)
#pragma unroll
        for (int ks = 0; ks < 2; ++ks)
          acc[mi + 4][ni] = mfma16(a1[mi][ks], b0f[ni][ks], acc[mi + 4][ni]);
    __builtin_amdgcn_s_setprio(0);
    if (t + 3 < nt) { WVM6(); } else { WVM0(); }
    BAR();
  }

  // ---- epilogue ----
  if (OUTMODE == 0) {
    // LDS-bounce: tile -> LDS (128 KB), then fully-coalesced 16B/lane stores.
    __syncthreads();
    u16* cw = (u16*)&lds[0][0][0][0];       // [256][256] u16
#pragma unroll
    for (int ni = 0; ni < 4; ++ni) {
      const int col = wc * 64 + ni * 16 + lr;
      const float bv = biasp[n0 + col];
#pragma unroll
      for (int mi = 0; mi < 8; ++mi)
#pragma unroll
        for (int j = 0; j < 4; ++j) {
          const int row = wr * 128 + mi * 16 + lg * 4 + j;
          cw[row * 256 + col] = f2b(acc[mi][ni][j] + bv);
        }
    }
    __syncthreads();
#pragma unroll
    for (int it = 0; it < 16; ++it) {
      int c = it * 512 + tid;
      int row = c >> 5, ch = c & 31;
      i32x4 v = *(const i32x4*)&cw[row * 256 + ch * 8];
      *(i32x4*)((u16*)Cp + (size_t)(m0 + row) * 1024 + n0 + ch * 8) = v;
    }
  } else {
#pragma unroll
    for (int ni = 0; ni < 4; ++ni) {
      const int col = n0 + wc * 64 + ni * 16 + lr;
      const float bv = (OUTMODE == 2) ? 0.f : biasp[col];
#pragma unroll
      for (int mi = 0; mi < 8; ++mi)
#pragma unroll
        for (int j = 0; j < 4; ++j) {
          const int row = m0 + wr * 128 + mi * 16 + lg * 4 + j;
          const float v = acc[mi][ni][j] + bv;
          if (OUTMODE == 2)
            ((float*)Cp)[(size_t)sp * M * 1024 + (size_t)row * 1024 + col] = v;
          else
            ((float*)Cp)[(size_t)row * 1024 + col] = v;
        }
    }
  }
}

// ---------------------------------------------------------------------------
// Legacy 128x128 GEMM — fallback paths only (small workspace)
// ---------------------------------------------------------------------------
template<int AMODE, int OUTMODE>
__global__ __launch_bounds__(256)
void gemm_bt(const void* A0p, const void* A1p, const void* A2p,
             const u16* B0p, const u16* B1p, const u16* B2p,
             const float* b0p, const float* b1p, const float* b2p,
             void* C0p, void* C1p, void* C2p,
             int M, int K, int kspl) {
  const int zc = blockIdx.z / kspl;
  const int sp = blockIdx.z % kspl;
  const void* Ap = zc == 0 ? A0p : (zc == 1 ? A1p : A2p);
  const u16* Bp = zc == 0 ? B0p : (zc == 1 ? B1p : B2p);
  const float* biasp = zc == 0 ? b0p : (zc == 1 ? b1p : b2p);
  void* Cp = zc == 0 ? C0p : (zc == 1 ? C1p : C2p);

  __shared__ u16 Alds[128 * 64];
  __shared__ u16 Blds[128 * 64];

  const int tid = threadIdx.x;
  const int w = tid >> 6, lane = tid & 63;
  const int lr = lane & 15, lg = lane >> 4;
  const int m0 = blockIdx.x * 128, n0 = blockIdx.y * 128;
  const int wr = (w >> 1) * 64, wc = (w & 1) * 64;
  const int brow = lane >> 3;
  const int bcol = (lane & 7) * 8;

  f32x4 acc[4][4];
#pragma unroll
  for (int mi = 0; mi < 4; ++mi)
#pragma unroll
    for (int ni = 0; ni < 4; ++ni) {
      f32x4 zv = {0.f, 0.f, 0.f, 0.f};
      acc[mi][ni] = zv;
    }

  const int kper = K / kspl;
  const int ktn = kper >> 6;
  const int kb = sp * kper;
  for (int kt = 0; kt < ktn; ++kt) {
    const int k0 = kb + (kt << 6);
    __syncthreads();
#pragma unroll
    for (int i = 0; i < 4; ++i) {
      const int c = w * 4 + i;
      const int row = c * 8 + brow;
      gl_lds16(Bp + (size_t)(n0 + row) * K + k0 + bcol, &Blds[c * 512]);
    }
    if (AMODE == 2) {
      const float* Af = (const float*)Ap;
#pragma unroll
      for (int i = 0; i < 4; ++i) {
        const int c = i * 256 + tid;
        const int row = c >> 3, k8 = (c & 7) * 8;
        const float* s = Af + (size_t)(m0 + row) * K + k0 + k8;
        f32x4 v0 = *(const f32x4*)s;
        f32x4 v1 = *(const f32x4*)(s + 4);
        u16x8 pk;
        pk[0] = f2b(v0[0]); pk[1] = f2b(v0[1]); pk[2] = f2b(v0[2]); pk[3] = f2b(v0[3]);
        pk[4] = f2b(v1[0]); pk[5] = f2b(v1[1]); pk[6] = f2b(v1[2]); pk[7] = f2b(v1[3]);
        *(u16x8*)&Alds[row * 64 + k8] = pk;
      }
    } else if (AMODE == 0) {
      const u16* Ab = (const u16*)Ap;
#pragma unroll
      for (int i = 0; i < 4; ++i) {
        const int c = w * 4 + i;
        const int row = c * 8 + brow;
        gl_lds16(Ab + (size_t)(m0 + row) * K + k0 + bcol, &Alds[c * 512]);
      }
    } else {
      const u16* Ab = (const u16*)Ap;
#pragma unroll
      for (int i = 0; i < 4; ++i) {
        const int c = w * 4 + i;
        const int m = m0 + c * 8 + brow;
        const int nn = m >> 8, p = m & 255;
        const int k = k0 + bcol;
        gl_lds16(Ab + (size_t)(p * 8 + (k >> 10)) * NE + nn * EDIM + (k & 1023),
                 &Alds[c * 512]);
      }
    }
    __syncthreads();
#pragma unroll
    for (int ks = 0; ks < 2; ++ks) {
      bf16x8 af[4], bf[4];
#pragma unroll
      for (int mi = 0; mi < 4; ++mi)
        af[mi] = *(const bf16x8*)&Alds[(wr + mi * 16 + lr) * 64 + ks * 32 + lg * 8];
#pragma unroll
      for (int ni = 0; ni < 4; ++ni)
        bf[ni] = *(const bf16x8*)&Blds[(wc + ni * 16 + lr) * 64 + ks * 32 + lg * 8];
#pragma unroll
      for (int mi = 0; mi < 4; ++mi)
#pragma unroll
        for (int ni = 0; ni < 4; ++ni)
          acc[mi][ni] = mfma16(af[mi], bf[ni], acc[mi][ni]);
    }
  }
#pragma unroll
  for (int ni = 0; ni < 4; ++ni) {
    const int col = n0 + wc + ni * 16 + lr;
    const float bv = (OUTMODE == 2) ? 0.f : biasp[col];
#pragma unroll
    for (int mi = 0; mi < 4; ++mi)
#pragma unroll
      for (int j = 0; j < 4; ++j) {
        const int row = m0 + wr + mi * 16 + lg * 4 + j;
        const float v = acc[mi][ni][j] + bv;
        if (OUTMODE == 4) {
          const int nn = row >> 8, pp = row & 255, h = col >> 6, d = col & 63;
          ((u16*)Cp)[(size_t)(nn * HNUM + h) * (DDIM * KPDIM) + d * 256 +
                     (((pp >> 3) ^ (d & 7)) * 8) + (pp & 7)] = f2b(v);
        } else if (OUTMODE == 3) {
          const int nn = row >> 8, pp = row & 255, h = col >> 6, d = col & 63;
          ((u16*)Cp)[((size_t)(nn * HNUM + h) * KPDIM + pp) * DDIM + d] = f2b(v);
        } else if (OUTMODE == 2)
          ((float*)Cp)[(size_t)sp * M * 1024 + (size_t)row * 1024 + col] = v;
        else if (OUTMODE == 1)
          ((float*)Cp)[(size_t)row * 1024 + col] = v;
        else
          ((u16*)Cp)[(size_t)row * 1024 + col] = f2b(v);
      }
  }
}

// ---------------------------------------------------------------------------
// Fused attention v5: swapped-operand QK^T -> S^T in registers, P never in LDS.
// block = (64 q-rows, n, head-group of hpg). LDS 64 KB (K 32K + V 32K),
// 2 blocks/CU (the TLP r10 proved essential).
// Layouts (16x16x32, verified A/B mirror: both keyed by lane&15, k=lg*8+e):
//   QK swapped: s[ni] = mfma(Kfrag, Qfrag):  S^T C-layout:
//     lane lr = q ; reg (ni,j): p = ni*16 + lg*4 + j
//   => softmax normalizer is a per-lane scalar (reduce own 64 + shfl 16,32).
//   PV A-frag (P): lane (lr=q, lg) needs p = 32ks + lg*8 + e. Own quads are
//     p in {4lg..4lg+3} (s[2ks]) and {16+4lg..} (s[2ks+1]); the missing quads
//     live in lanes srcA = lr + 32*(lg&1), srcB = srcA+16; part = lg>>1
//     selects their low (p<16) or high quads. 8 shfl + 4 sel per ks.
//   PV B-frag (V) and O-store identical to v3 (layouts unchanged).
// K region dead after QK reads => stage K(h+1) overlaps softmax+pack+PV.
// V region dead after PV reads => stage V(h+1) at end (exposed ~1 load lat).
// P pre-normalized (s *= inv) so O needs no per-row scale (O rows q=lg*4+j
// differ from lane's lr-q — inv would be cross-lane otherwise).
// ---------------------------------------------------------------------------
__global__ __launch_bounds__(256)
void attn_fused5(const u16* __restrict__ Q, const u16* __restrict__ Kc,
                 const u16* __restrict__ VcT, u16* __restrict__ Aout,
                 float* __restrict__ AWp, int hpg) {
  __shared__ u16 Kl[256 * 64];   // K [p][d] chunk-swizzled
  __shared__ u16 Vl[64 * 256];   // V^T [d][p] chunk-swizzled
  const int tid = threadIdx.x;
  const int w = tid >> 6, lane = tid & 63;
  const int lr = lane & 15, lg = lane >> 4;
  const int n = blockIdx.y;
  const int l0 = blockIdx.x * 64;
  const int lrow = l0 + w * 16 + lr;     // this lane's q-row (for S^T / AW)
  char* kbase = (char*)Kl;
  char* vbase = (char*)Vl;
  const int sA = lr + ((lg & 1) << 5);   // lr + 32*(lg&1)
  const int sB = sA + 16;
  const int part = lg >> 1;

  auto stageK = [&](int h) {
    const u16* kh = Kc + (size_t)(n * HNUM + h) * (KPDIM * DDIM);
#pragma unroll
    for (int it = 0; it < 8; ++it) {
      int c = it * 256 + tid, p = c >> 3, j = c & 7;
      gl_lds16(kh + p * 64 + ((j ^ (p & 7)) << 3), kbase + c * 16);
    }
  };
  auto stageV = [&](int h) {
    const u16* vh = VcT + (size_t)(n * HNUM + h) * (DDIM * KPDIM);
#pragma unroll
    for (int it = 0; it < 8; ++it) {
      int c = it * 256 + tid;
      gl_lds16(vh + c * 8, vbase + c * 16);
    }
  };

  f32x4 macc[16];
#pragma unroll
  for (int ni = 0; ni < 16; ++ni) { f32x4 zv = {0.f,0.f,0.f,0.f}; macc[ni] = zv; }

  const int hbase = blockIdx.z * hpg;
  stageK(hbase); stageV(hbase);

  for (int hh = 0; hh < hpg; ++hh) {
    const int h = hbase + hh;
    __syncthreads();   // staged K,V landed (drains vmcnt + rendezvous)
    // ---- Q fragment (B-operand; same regs as old A-operand layout) ----
    const u16* qp = Q + (size_t)lrow * NE + n * EDIM + h * DDIM + lg * 8;
    bf16x8 aq0 = *(const bf16x8*)qp;
    bf16x8 aq1 = *(const bf16x8*)(qp + 32);
    // ---- S^T = K @ Q^T : swapped operands ----
    f32x4 s[16];
#pragma unroll
    for (int ni = 0; ni < 16; ++ni) { f32x4 zv = {0.f,0.f,0.f,0.f}; s[ni] = zv; }
#pragma unroll
    for (int ni = 0; ni < 16; ++ni) {
      int row = ni * 16 + lr;             // K row p (A-operand, lane lr)
      const char* kr = kbase + row * 128;
      bf16x8 k0 = *(const bf16x8*)(kr + ((lg ^ (row & 7)) << 4));
      bf16x8 k1 = *(const bf16x8*)(kr + (((4 + lg) ^ (row & 7)) << 4));
      s[ni] = mfma16(k0, aq0, s[ni]);
      s[ni] = mfma16(k1, aq1, s[ni]);
    }
    LGKM0();
    BAR();            // all waves' K reads done -> K region free
    if (hh + 1 < hpg) stageK(h + 1);      // overlaps softmax+pack+PV
    // ---- softmax: per-lane scalar (q = lr) ----
    float mx = -1e30f;
#pragma unroll
    for (int ni = 0; ni < 16; ++ni)
#pragma unroll
      for (int j = 0; j < 4; ++j) mx = fmaxf(mx, s[ni][j]);
    mx = fmaxf(mx, __shfl_xor(mx, 16, 64));
    mx = fmaxf(mx, __shfl_xor(mx, 32, 64));
    float sm = 0.f;
#pragma unroll
    for (int ni = 0; ni < 16; ++ni)
#pragma unroll
      for (int j = 0; j < 4; ++j) {
        float e = __expf(s[ni][j] - mx);
        s[ni][j] = e; sm += e;
      }
    sm += __shfl_xor(sm, 16, 64);
    sm += __shfl_xor(sm, 32, 64);
    const float inv = 1.0f / sm;
#pragma unroll
    for (int ni = 0; ni < 16; ++ni) {
#pragma unroll
      for (int j = 0; j < 4; ++j) s[ni][j] *= inv;   // normalized P
      macc[ni] += s[ni] * 0.0625f;                   // head-mean accum
    }
    // ---- pack P into A-frags (cross-lane quad exchange) + PV ----
    f32x4 o[4];
#pragma unroll
    for (int ni2 = 0; ni2 < 4; ++ni2) { f32x4 zv = {0.f,0.f,0.f,0.f}; o[ni2] = zv; }
#pragma unroll
    for (int ks = 0; ks < 8; ++ks) {
      unsigned lo0 = pk2(s[2 * ks][0], s[2 * ks][1]);
      unsigned lo1 = pk2(s[2 * ks][2], s[2 * ks][3]);
      unsigned hi0 = pk2(s[2 * ks + 1][0], s[2 * ks + 1][1]);
      unsigned hi1 = pk2(s[2 * ks + 1][2], s[2 * ks + 1][3]);
      unsigned aL0 = (unsigned)__shfl((int)lo0, sA, 64);
      unsigned aL1 = (unsigned)__shfl((int)lo1, sA, 64);
      unsigned aH0 = (unsigned)__shfl((int)hi0, sA, 64);
      unsigned aH1 = (unsigned)__shfl((int)hi1, sA, 64);
      unsigned bL0 = (unsigned)__shfl((int)lo0, sB, 64);
      unsigned bL1 = (unsigned)__shfl((int)lo1, sB, 64);
      unsigned bH0 = (unsigned)__shfl((int)hi0, sB, 64);
      unsigned bH1 = (unsigned)__shfl((int)hi1, sB, 64);
      i32x4 pu;
      pu[0] = (int)(part ? aH0 : aL0);
      pu[1] = (int)(part ? aH1 : aL1);
      pu[2] = (int)(part ? bH0 : bL0);
      pu[3] = (int)(part ? bH1 : bL1);
      bf16x8 pa = __builtin_bit_cast(bf16x8, pu);
#pragma unroll
      for (int ni2 = 0; ni2 < 4; ++ni2) {
        int d = ni2 * 16 + lr;
        bf16x8 vf = *(const bf16x8*)(vbase + d * 512 + (((ks * 4 + lg) ^ (d & 7)) << 4));
        o[ni2] = mfma16(pa, vf, o[ni2]);
      }
    }
    // ---- write O tile (rows q = lg*4+j; already normalized) ----
#pragma unroll
    for (int ni2 = 0; ni2 < 4; ++ni2)
#pragma unroll
      for (int j = 0; j < 4; ++j) {
        int gl = l0 + w * 16 + lg * 4 + j;
        Aout[(size_t)gl * NE + n * EDIM + h * DDIM + ni2 * 16 + lr] = f2b(o[ni2][j]);
      }
    LGKM0();
    BAR();            // all waves' V reads done -> V region free
    if (hh + 1 < hpg) stageV(h + 1);
  }
  // ---- write head-mean attention weight partial: lane owns q-row lrow ----
  float* awo = AWp + (size_t)blockIdx.z * AWSZ + (size_t)n * (LSEQ * KPDIM)
             + (size_t)lrow * KPDIM;
#pragma unroll
  for (int ni = 0; ni < 16; ++ni)
    *(f32x4*)(awo + ni * 16 + lg * 4) = macc[ni];
}

// ---------------------------------------------------------------------------
// Fused attention v3 (r9/r11, stable) — fallback path only (small workspace).
// ---------------------------------------------------------------------------
__global__ __launch_bounds__(256)
void attn_fused(const u16* __restrict__ Q, const u16* __restrict__ Kc,
                const u16* __restrict__ VcT, u16* __restrict__ Aout,
                float* __restrict__ AWp, int hpg) {
  __shared__ u16 Ares[256 * 64];
  __shared__ u16 Bres[64 * 256];
  const int tid = threadIdx.x;
  const int w = tid >> 6, lane = tid & 63;
  const int lr = lane & 15, lg = lane >> 4;
  const int n = blockIdx.y;
  const int l0 = blockIdx.x * 64;
  const int lrow = l0 + w * 16 + lr;
  char* kbase = (char*)Ares;
  char* vbase = (char*)Bres;
  char* pbase = (char*)Ares + w * 8192;

  f32x4 macc[16];
#pragma unroll
  for (int ni = 0; ni < 16; ++ni) { f32x4 zv = {0.f,0.f,0.f,0.f}; macc[ni] = zv; }

  for (int hh = 0; hh < hpg; ++hh) {
    const int h = blockIdx.z * hpg + hh;
    const u16* kh = Kc + (size_t)(n * HNUM + h) * (KPDIM * DDIM);
    const u16* vh = VcT + (size_t)(n * HNUM + h) * (DDIM * KPDIM);
    __syncthreads();
#pragma unroll
    for (int it = 0; it < 8; ++it) {
      int c = it * 256 + tid;
      int p = c >> 3, j = c & 7;
      gl_lds16(kh + p * 64 + ((j ^ (p & 7)) << 3), kbase + c * 16);
    }
#pragma unroll
    for (int it = 0; it < 8; ++it) {
      int c = it * 256 + tid;
      gl_lds16(vh + c * 8, vbase + c * 16);
    }
    const u16* qp = Q + (size_t)lrow * NE + n * EDIM + h * DDIM + lg * 8;
    bf16x8 aq0 = *(const bf16x8*)qp;
    bf16x8 aq1 = *(const bf16x8*)(qp + 32);
    __syncthreads();
    f32x4 s[16];
#pragma unroll
    for (int ni = 0; ni < 16; ++ni) { f32x4 zv = {0.f,0.f,0.f,0.f}; s[ni] = zv; }
#pragma unroll
    for (int ni = 0; ni < 16; ++ni) {
      int row = ni * 16 + lr;
      const char* kr = kbase + row * 128;
      bf16x8 b0 = *(const bf16x8*)(kr + ((lg ^ (row & 7)) << 4));
      bf16x8 b1 = *(const bf16x8*)(kr + (((4 + lg) ^ (row & 7)) << 4));
      s[ni] = mfma16(aq0, b0, s[ni]);
      s[ni] = mfma16(aq1, b1, s[ni]);
    }
    float mx[4], sm[4], inv[4], invs[4];
#pragma unroll
    for (int j = 0; j < 4; ++j) mx[j] = -1e30f;
#pragma unroll
    for (int ni = 0; ni < 16; ++ni)
#pragma unroll
      for (int j = 0; j < 4; ++j) mx[j] = fmaxf(mx[j], s[ni][j]);
#pragma unroll
    for (int msk = 1; msk <= 8; msk <<= 1)
#pragma unroll
      for (int j = 0; j < 4; ++j) mx[j] = fmaxf(mx[j], __shfl_xor(mx[j], msk, 64));
#pragma unroll
    for (int j = 0; j < 4; ++j) sm[j] = 0.f;
#pragma unroll
    for (int ni = 0; ni < 16; ++ni)
#pragma unroll
      for (int j = 0; j < 4; ++j) {
        float e = __expf(s[ni][j] - mx[j]);
        s[ni][j] = e; sm[j] += e;
      }
#pragma unroll
    for (int msk = 1; msk <= 8; msk <<= 1)
#pragma unroll
      for (int j = 0; j < 4; ++j) sm[j] += __shfl_xor(sm[j], msk, 64);
#pragma unroll
    for (int j = 0; j < 4; ++j) { inv[j] = 1.0f / sm[j]; invs[j] = inv[j] * 0.0625f; }
    __syncthreads();
#pragma unroll
    for (int ni = 0; ni < 16; ++ni)
#pragma unroll
      for (int j = 0; j < 4; ++j) {
        macc[ni][j] += s[ni][j] * invs[j];
        int r = lg * 4 + j;
        *(u16*)(pbase + r * 512 + ((ni * 32 + lr * 2) ^ ((r & 7) << 4))) =
            f2b(s[ni][j]);
      }
    f32x4 o[4];
#pragma unroll
    for (int ni2 = 0; ni2 < 4; ++ni2) { f32x4 zv = {0.f,0.f,0.f,0.f}; o[ni2] = zv; }
#pragma unroll
    for (int ks = 0; ks < 8; ++ks) {
      bf16x8 a = *(const bf16x8*)(pbase + lr * 512 + ((ks * 64 + 16 * lg) ^ ((lr & 7) << 4)));
#pragma unroll
      for (int ni2 = 0; ni2 < 4; ++ni2) {
        int d = ni2 * 16 + lr;
        bf16x8 b = *(const bf16x8*)(vbase + d * 512 + (((ks * 4 + lg) ^ (d & 7)) << 4));
        o[ni2] = mfma16(a, b, o[ni2]);
      }
    }
#pragma unroll
    for (int ni2 = 0; ni2 < 4; ++ni2)
#pragma unroll
      for (int j = 0; j < 4; ++j) {
        int gl = l0 + w * 16 + lg * 4 + j;
        Aout[(size_t)gl * NE + n * EDIM + h * DDIM + ni2 * 16 + lr] =
            f2b(o[ni2][j] * inv[j]);
      }
  }
  float* awo = AWp + (size_t)blockIdx.z * AWSZ + (size_t)n * (LSEQ * KPDIM);
#pragma unroll
  for (int ni = 0; ni < 16; ++ni)
#pragma unroll
    for (int j = 0; j < 4; ++j) {
      int r = lg * 4 + j;
      awo[(size_t)(l0 + w * 16 + r) * KPDIM + ni * 16 + lr] = macc[ni][j];
    }
}

// ---------------------------------------------------------------------------
extern "C" void kernel_launch(void* const* d_in, const int* in_sizes, int n_in,
                              void* d_out, int out_size, void* d_ws, size_t ws_size,
                              hipStream_t stream) {
  const float* query = (const float*)d_in[0];
  const float* key   = (const float*)d_in[1];
  const float* value = (const float*)d_in[2];
  const float* ipw   = (const float*)d_in[3];
  const float* ipb   = (const float*)d_in[4];
  const float* ew    = (const float*)d_in[5];
  const float* eb    = (const float*)d_in[6];
  const float* fw    = (const float*)d_in[7];
  const float* fb    = (const float*)d_in[8];
  const float* ow    = (const float*)d_in[9];
  const float* ob    = (const float*)d_in[10];

  char* ws = (char*)d_ws;
  size_t off = 0;
  auto alloc = [&](size_t bytes) {
    void* p = ws + off;
    off += (bytes + 255) & ~(size_t)255;
    return p;
  };
  u16* qp    = (u16*)alloc((size_t)MROWS * EDIM * 2);
  u16* kp    = (u16*)alloc((size_t)MROWS * EDIM * 2);
  u16* vp    = (u16*)alloc((size_t)MROWS * EDIM * 2);
  u16* ao    = (u16*)alloc((size_t)MROWS * EDIM * 2);
  u16* kc    = (u16*)alloc((size_t)NB * KPDIM * EDIM * 2);   // (N,H,Kp,D)
  u16* vcT   = (u16*)alloc((size_t)NB * KPDIM * EDIM * 2);   // (N,H,D,Kp) swz
  u16* w_in  = (u16*)alloc((size_t)3 * EDIM * EDIM * 2);
  u16* w_eT  = (u16*)alloc((size_t)EDIM * 8 * EDIM * 2);
  u16* w_fT  = (u16*)alloc((size_t)EDIM * 8 * EDIM * 2);
  u16* w_out = (u16*)alloc((size_t)EDIM * EDIM * 2);
  float* bq  = (float*)alloc(EDIM * 4);
  size_t base_needed = off;

  size_t qkv16_b = (size_t)3 * MROWS * EDIM * 2;
  size_t part_b  = (size_t)2 * 4 * 2048 * 1024 * 4;
  bool bigX  = ws_size >= base_needed + qkv16_b;
  bool midX  = ws_size >= base_needed + part_b;
  char* X = (char*)alloc(bigX ? qkv16_b : (midX ? part_b : 0));
  u16* qkv16 = (u16*)X;
  float* part = (float*)X;
  float* awp  = (float*)X;

  float* out_f = (float*)d_out;                        // (L, N, E)
  float* aw_f  = (float*)d_out + (size_t)MROWS * EDIM; // (N, L, Kp)

  // weight prep (merged) + conv-weight transpose
  prep1<<<dim3(3072), 256, 0, stream>>>(ipw, ow, ipb, w_in, w_out, bq);
  wtrans<<<dim3(16384, 2), 64, 0, stream>>>(ew, fw, w_eT, w_fT);

  // q/k/v projections
  if (bigX) {
    castqkv<<<dim3(8192, 3), 256, 0, stream>>>(query, key, value, qkv16);
    gemm256<0, 0><<<dim3(64, 4, 3), 512, 0, stream>>>(
        qkv16, qkv16 + (size_t)MROWS * EDIM, qkv16 + (size_t)2 * MROWS * EDIM,
        w_in, w_in + 1048576, w_in + 2097152,
        bq, ipb + 1024, ipb + 2048,
        qp, kp, vp, MROWS, 1024, 1);
  } else {
    gemm_bt<2, 0><<<dim3(128, 8, 3), 256, 0, stream>>>(
        query, key, value,
        w_in, w_in + 1048576, w_in + 2097152,
        bq, ipb + 1024, ipb + 2048,
        qp, kp, vp, MROWS, 1024, 1);
  }

  // conv compression of k and v -> kc (head-major) / vcT (transposed swz)
  if (bigX || midX) {
    gemm256<1, 2><<<dim3(8, 4, 8), 512, 0, stream>>>(
        kp, vp, vp,
        w_eT, w_fT, w_fT,
        eb, fb, fb,
        part, part + (size_t)4 * 2048 * 1024, part,
        NB * KPDIM, 8192, 4);
    redc<<<dim3(2048, 2), 256, 0, stream>>>(part, eb, fb, kc, vcT);
  } else {
    gemm_bt<1, 3><<<dim3(16, 8, 1), 256, 0, stream>>>(
        kp, kp, kp, w_eT, w_eT, w_eT, eb, eb, eb,
        kc, kc, kc, NB * KPDIM, 8192, 1);
    gemm_bt<1, 4><<<dim3(16, 8, 1), 256, 0, stream>>>(
        vp, vp, vp, w_fT, w_fT, w_fT, fb, fb, fb,
        vcT, vcT, vcT, NB * KPDIM, 8192, 1);
  }

  // fused attention + head-mean weights
  if (bigX) {
    attn_fused5<<<dim3(32, 8, 4), 256, 0, stream>>>(qp, kc, vcT, ao, awp, 4);
    awred<<<dim3(4096), 256, 0, stream>>>(awp, aw_f);
  } else {
    attn_fused<<<dim3(32, 8, 1), 256, 0, stream>>>(qp, kc, vcT, ao, aw_f, 16);
  }

  // output projection -> f32 d_out
  gemm256<0, 1><<<dim3(64, 4, 1), 512, 0, stream>>>(
      ao, ao, ao,
      w_out, w_out, w_out,
      ob, ob, ob,
      out_f, out_f, out_f, MROWS, 1024, 1);
}

// Round 13
// 414.865 us; speedup vs baseline: 1.2007x; 1.0321x over previous
//
#include <hip/hip_runtime.h>

typedef unsigned short u16;
typedef u16  u16x4 __attribute__((ext_vector_type(4)));
typedef u16  u16x8 __attribute__((ext_vector_type(8)));
typedef float f32x4 __attribute__((ext_vector_type(4)));
typedef int   i32x4 __attribute__((ext_vector_type(4)));
typedef __bf16 bf16x8 __attribute__((ext_vector_type(8)));

#define LSEQ 2048
#define NB 8
#define EDIM 1024
#define HNUM 16
#define DDIM 64
#define KPDIM 256
#define NE (NB*EDIM)       /* 8192 */
#define MROWS (LSEQ*NB)    /* 16384 */
#define AWSZ ((size_t)NB*LSEQ*KPDIM)  /* 4194304 */

__device__ __forceinline__ u16 f2b(float f) {
  unsigned u = __builtin_bit_cast(unsigned, f);
  u += 0x7fffu + ((u >> 16) & 1u);
  return (u16)(u >> 16);
}

__device__ __forceinline__ unsigned pk2(float a, float b) {
  return (unsigned)f2b(a) | ((unsigned)f2b(b) << 16);
}

__device__ __forceinline__ void gl_lds16(const void* g, void* l) {
  __builtin_amdgcn_global_load_lds(
      (const __attribute__((address_space(1))) void*)g,
      (__attribute__((address_space(3))) void*)l, 16, 0, 0);
}

__device__ __forceinline__ f32x4 mfma16(bf16x8 a, bf16x8 b, f32x4 c) {
  return __builtin_amdgcn_mfma_f32_16x16x32_bf16(a, b, c, 0, 0, 0);
}

#define BAR()   __builtin_amdgcn_s_barrier()
#define LGKM0() asm volatile("s_waitcnt lgkmcnt(0)" ::: "memory")
#define WVM6()  asm volatile("s_waitcnt vmcnt(6)" ::: "memory")
#define WVM0()  asm volatile("s_waitcnt vmcnt(0)" ::: "memory")

// ---------------------------------------------------------------------------
// Weight prep: in_proj cast (+q scale), out_w cast, q-bias scale — one launch
// ---------------------------------------------------------------------------
__global__ void prep1(const float* __restrict__ ipw, const float* __restrict__ ow,
                      const float* __restrict__ ipb, u16* __restrict__ w_in,
                      u16* __restrict__ w_out, float* __restrict__ bq) {
  int i = blockIdx.x * blockDim.x + threadIdx.x;
  if (i < 786432) {
    f32x4 v = ((const f32x4*)ipw)[i];
    float s = (i < 262144) ? 0.125f : 1.0f;
    u16x4 o;
    o[0] = f2b(v[0] * s); o[1] = f2b(v[1] * s);
    o[2] = f2b(v[2] * s); o[3] = f2b(v[3] * s);
    ((u16x4*)w_in)[i] = o;
  }
  if (i < 262144) {
    f32x4 v = ((const f32x4*)ow)[i];
    u16x4 o;
    o[0] = f2b(v[0]); o[1] = f2b(v[1]); o[2] = f2b(v[2]); o[3] = f2b(v[3]);
    ((u16x4*)w_out)[i] = o;
  }
  if (i < 256) {
    f32x4 b = ((const f32x4*)ipb)[i];
    ((f32x4*)bq)[i] = b * 0.125f;
  }
}

// (O, I, 8) f32  ->  (O, t*E + i) bf16   (per-wave LDS transpose)
__global__ void wtrans(const float* __restrict__ ew, const float* __restrict__ fw,
                       u16* __restrict__ eT, u16* __restrict__ fT) {
  const float* src = blockIdx.y ? fw : ew;
  u16* dst = blockIdx.y ? fT : eT;
  int eo = blockIdx.x >> 4;
  int ei0 = (blockIdx.x & 15) * 64;
  int l = threadIdx.x;
  __shared__ u16 lds[8][64];
  const float* s = src + (size_t)eo * 8192 + (size_t)ei0 * 8 + l * 8;
  f32x4 a = *(const f32x4*)s;
  f32x4 b = *(const f32x4*)(s + 4);
  float v[8] = {a[0], a[1], a[2], a[3], b[0], b[1], b[2], b[3]};
#pragma unroll
  for (int t = 0; t < 8; ++t) lds[t][l] = f2b(v[t]);
  __syncthreads();
  int t = l >> 3, c = l & 7;
  i32x4 out = *(const i32x4*)&lds[t][c * 8];
  *(i32x4*)(dst + (size_t)eo * 8192 + t * 1024 + ei0 + c * 8) = out;
}

// q/k/v f32 -> bf16, contiguous [3][MROWS][E]
__global__ void castqkv(const float* __restrict__ q, const float* __restrict__ k,
                        const float* __restrict__ v, u16* __restrict__ out) {
  const float* src = blockIdx.y == 0 ? q : (blockIdx.y == 1 ? k : v);
  size_t base = (size_t)blockIdx.y * ((size_t)MROWS * EDIM);
  size_t i = ((size_t)blockIdx.x * 256 + threadIdx.x) * 8;
  f32x4 v0 = *(const f32x4*)(src + i);
  f32x4 v1 = *(const f32x4*)(src + i + 4);
  u16x8 o;
  o[0] = f2b(v0[0]); o[1] = f2b(v0[1]); o[2] = f2b(v0[2]); o[3] = f2b(v0[3]);
  o[4] = f2b(v1[0]); o[5] = f2b(v1[1]); o[6] = f2b(v1[2]); o[7] = f2b(v1[3]);
  *(u16x8*)(out + base + i) = o;
}

// sum 4 split-K partials + bias -> bf16.
// K -> head-major (N,H,Kp,D). V -> transposed (N,H,D,Kp) chunk-swizzled.
__global__ void redc(const float* __restrict__ part, const float* __restrict__ eb,
                     const float* __restrict__ fb, u16* __restrict__ kc,
                     u16* __restrict__ vcT) {
  int zc = blockIdx.y;
  const float* p = part + (size_t)zc * 4 * 2048 * 1024;
  const float* bias = zc ? fb : eb;
  size_t i = ((size_t)blockIdx.x * 256 + threadIdx.x) * 4;
  f32x4 s = *(const f32x4*)(p + i);
  s += *(const f32x4*)(p + 2097152 + i);
  s += *(const f32x4*)(p + 2 * 2097152 + i);
  s += *(const f32x4*)(p + 3 * 2097152 + i);
  int e = (int)(i & 1023);
  int row = (int)(i >> 10);           // n*256 + p
  int n = row >> 8, pp = row & 255;
  int h = e >> 6, d = e & 63;
  f32x4 b = *(const f32x4*)(bias + e);
  if (zc == 0) {
    u16x4 o;
    o[0] = f2b(s[0] + b[0]); o[1] = f2b(s[1] + b[1]);
    o[2] = f2b(s[2] + b[2]); o[3] = f2b(s[3] + b[3]);
    *(u16x4*)(kc + (((size_t)(n * HNUM + h) * KPDIM + pp) * DDIM + d)) = o;
  } else {
    size_t base = (size_t)(n * HNUM + h) * (DDIM * KPDIM);
#pragma unroll
    for (int q = 0; q < 4; ++q) {
      int dq = d + q;
      vcT[base + dq * 256 + (((pp >> 3) ^ (dq & 7)) * 8) + (pp & 7)] =
          f2b(s[q] + b[q]);
    }
  }
}

// sum the 2 head-group AW partials
__global__ void awred(const float* __restrict__ awp, float* __restrict__ aw) {
  size_t i = ((size_t)blockIdx.x * 256 + threadIdx.x) * 4;
  f32x4 s = *(const f32x4*)(awp + i);
  s += *(const f32x4*)(awp + AWSZ + i);
  *(f32x4*)(aw + i) = s;
}

// ---------------------------------------------------------------------------
// 256x256 GEMM — 8-phase ring schedule (r8, verified) + coalesced bf16
// epilogue (r9). Reader/stage ring and vmcnt ledger: see r8 comments.
//   AMODE 0: A bf16 rows contiguous (ld=K); AMODE 1: conv-gather
//   OUTMODE 0: bf16 C+bias (LDS-bounced); 1: f32 C+bias; 2: f32 split-K partial
// grid = (M/256, N/256, nz*kspl); block = 512 (8 waves, 2M x 4N); nt even
// ---------------------------------------------------------------------------
template<int AMODE, int OUTMODE>
__global__ __launch_bounds__(512, 2)
void gemm256(const void* A0p, const void* A1p, const void* A2p,
             const u16* B0p, const u16* B1p, const u16* B2p,
             const float* b0p, const float* b1p, const float* b2p,
             void* C0p, void* C1p, void* C2p,
             int M, int K, int kspl) {
  const int zc = blockIdx.z / kspl, sp = blockIdx.z % kspl;
  const void* Ap = zc == 0 ? A0p : (zc == 1 ? A1p : A2p);
  const u16* Bp = zc == 0 ? B0p : (zc == 1 ? B1p : B2p);
  const float* biasp = zc == 0 ? b0p : (zc == 1 ? b1p : b2p);
  void* Cp = zc == 0 ? C0p : (zc == 1 ? C1p : C2p);

  __shared__ u16 lds[2][2][2][128 * 64];  // [buf][A=0/B=1][half][r*64+swzchunk*8]

  const int tid = threadIdx.x;
  const int w = tid >> 6, lane = tid & 63;
  const int lr = lane & 15, lg = lane >> 4;
  const int wr = w >> 2, wc = w & 3;            // 2M x 4N waves
  const int m0 = blockIdx.x * 256, n0 = blockIdx.y * 256;
  const int kper = K / kspl, kbase = sp * kper, nt = kper >> 6;

  f32x4 acc[8][4];
#pragma unroll
  for (int mi = 0; mi < 8; ++mi)
#pragma unroll
    for (int ni = 0; ni < 4; ++ni) {
      f32x4 zv = {0.f, 0.f, 0.f, 0.f};
      acc[mi][ni] = zv;
    }

  // stage one 16KB half: op (0=A,1=B), half (0/1 = rows 0-127/128-255), tile kt
  auto stage_half = [&](int buf, int op, int half, int kt) {
    const int k0 = kbase + (kt << 6);
#pragma unroll
    for (int i = 0; i < 2; ++i) {
      int c = i * 512 + tid;               // 0..1023
      int r = c >> 3, j = c & 7, js = j ^ (r & 7);
      int row = half * 128 + r;
      u16* dst = &lds[buf][op][half][c * 8];
      if (op == 1) {
        gl_lds16(Bp + (size_t)(n0 + row) * K + k0 + js * 8, dst);
      } else if (AMODE == 0) {
        gl_lds16((const u16*)Ap + (size_t)(m0 + row) * K + k0 + js * 8, dst);
      } else {  // conv gather: m=(nn,p), k=(t,ei); k0 mult of 64, no 1024-cross
        int m = m0 + row;
        int nn = m >> 8, p = m & 255;
        int k = k0 + js * 8;
        gl_lds16((const u16*)Ap + (size_t)(p * 8 + (k >> 10)) * NE +
                 nn * EDIM + (k & 1023), dst);
      }
    }
  };

  auto LDA = [&](int buf, int row, int ks) -> bf16x8 {
    return *(const bf16x8*)&lds[buf][0][row >> 7]
        [(row & 127) * 64 + (((ks * 4 + lg) ^ (row & 7)) << 3)];
  };
  auto LDB = [&](int buf, int row, int ks) -> bf16x8 {
    return *(const bf16x8*)&lds[buf][1][row >> 7]
        [(row & 127) * 64 + (((ks * 4 + lg) ^ (row & 7)) << 3)];
  };

  // ---- prologue: T0 all 4 halves -> buf0; T1 B0,B1,A0 -> buf1 ----
  stage_half(0, 0, 0, 0); stage_half(0, 1, 0, 0);
  stage_half(0, 1, 1, 0); stage_half(0, 0, 1, 0);
  if (nt > 1) {
    stage_half(1, 1, 0, 1); stage_half(1, 1, 1, 1); stage_half(1, 0, 0, 1);
    WVM6();
  } else {
    WVM0();
  }
  BAR();

  for (int t = 0; t < nt; t += 2) {
    bf16x8 a0[4][2], a1[4][2], b0f[2][2], b1f[2][2];
    // ================= tile t (buf0) =================
    // ---- ph1: reads a0, b0 ----
#pragma unroll
    for (int mi = 0; mi < 4; ++mi)
#pragma unroll
      for (int ks = 0; ks < 2; ++ks)
        a0[mi][ks] = LDA(0, wr * 128 + mi * 16 + lr, ks);
#pragma unroll
    for (int ni = 0; ni < 2; ++ni)
#pragma unroll
      for (int ks = 0; ks < 2; ++ks)
        b0f[ni][ks] = LDB(0, wc * 64 + ni * 16 + lr, ks);
    stage_half(1, 0, 1, t + 1);            // (t+1).A1 (free since prev ph7)
    BAR(); LGKM0();
    __builtin_amdgcn_s_setprio(1);
#pragma unroll
    for (int mi = 0; mi < 4; ++mi)
#pragma unroll
      for (int ni = 0; ni < 2; ++ni)
#pragma unroll
        for (int ks = 0; ks < 2; ++ks)
          acc[mi][ni] = mfma16(a0[mi][ks], b0f[ni][ks], acc[mi][ni]);
    __builtin_amdgcn_s_setprio(0);
    BAR();
    // ---- ph2: reads b1; no stage ----
#pragma unroll
    for (int ni = 0; ni < 2; ++ni)
#pragma unroll
      for (int ks = 0; ks < 2; ++ks)
        b1f[ni][ks] = LDB(0, wc * 64 + (ni + 2) * 16 + lr, ks);
    BAR(); LGKM0();
    __builtin_amdgcn_s_setprio(1);
#pragma unroll
    for (int mi = 0; mi < 4; ++mi)
#pragma unroll
      for (int ni = 0; ni < 2; ++ni)
#pragma unroll
        for (int ks = 0; ks < 2; ++ks)
          acc[mi][ni + 2] = mfma16(a0[mi][ks], b1f[ni][ks], acc[mi][ni + 2]);
    __builtin_amdgcn_s_setprio(0);
    BAR();
    // ---- ph3: reads a1 ----
#pragma unroll
    for (int mi = 0; mi < 4; ++mi)
#pragma unroll
      for (int ks = 0; ks < 2; ++ks)
        a1[mi][ks] = LDA(0, wr * 128 + 64 + mi * 16 + lr, ks);
    if (t + 2 < nt) stage_half(0, 1, 0, t + 2);   // (t+2).B0 (free after ph2)
    BAR(); LGKM0();
    __builtin_amdgcn_s_setprio(1);
#pragma unroll
    for (int mi = 0; mi < 4; ++mi)
#pragma unroll
      for (int ni = 0; ni < 2; ++ni)
#pragma unroll
        for (int ks = 0; ks < 2; ++ks)
          acc[mi + 4][ni + 2] = mfma16(a1[mi][ks], b1f[ni][ks], acc[mi + 4][ni + 2]);
    __builtin_amdgcn_s_setprio(0);
    BAR();
    // ---- ph4: regs only; stage B1+A0 ----
    if (t + 2 < nt) { stage_half(0, 1, 1, t + 2); stage_half(0, 0, 0, t + 2); }
    BAR();
    __builtin_amdgcn_s_setprio(1);
#pragma unroll
    for (int mi = 0; mi < 4; ++mi)
#pragma unroll
      for (int ni = 0; ni < 2; ++ni)
#pragma unroll
        for (int ks = 0; ks < 2; ++ks)
          acc[mi + 4][ni] = mfma16(a1[mi][ks], b0f[ni][ks], acc[mi + 4][ni]);
    __builtin_amdgcn_s_setprio(0);
    if (t + 2 < nt) { WVM6(); } else { WVM0(); }
    BAR();
    // ================= tile t+1 (buf1) =================
    // ---- ph5 ----
#pragma unroll
    for (int mi = 0; mi < 4; ++mi)
#pragma unroll
      for (int ks = 0; ks < 2; ++ks)
        a0[mi][ks] = LDA(1, wr * 128 + mi * 16 + lr, ks);
#pragma unroll
    for (int ni = 0; ni < 2; ++ni)
#pragma unroll
      for (int ks = 0; ks < 2; ++ks)
        b0f[ni][ks] = LDB(1, wc * 64 + ni * 16 + lr, ks);
    if (t + 2 < nt) stage_half(0, 0, 1, t + 2);   // (t+2).A1 (free after ph3)
    BAR(); LGKM0();
    __builtin_amdgcn_s_setprio(1);
#pragma unroll
    for (int mi = 0; mi < 4; ++mi)
#pragma unroll
      for (int ni = 0; ni < 2; ++ni)
#pragma unroll
        for (int ks = 0; ks < 2; ++ks)
          acc[mi][ni] = mfma16(a0[mi][ks], b0f[ni][ks], acc[mi][ni]);
    __builtin_amdgcn_s_setprio(0);
    BAR();
    // ---- ph6: no stage ----
#pragma unroll
    for (int ni = 0; ni < 2; ++ni)
#pragma unroll
      for (int ks = 0; ks < 2; ++ks)
        b1f[ni][ks] = LDB(1, wc * 64 + (ni + 2) * 16 + lr, ks);
    BAR(); LGKM0();
    __builtin_amdgcn_s_setprio(1);
#pragma unroll
    for (int mi = 0; mi < 4; ++mi)
#pragma unroll
      for (int ni = 0; ni < 2; ++ni)
#pragma unroll
        for (int ks = 0; ks < 2; ++ks)
          acc[mi][ni + 2] = mfma16(a0[mi][ks], b1f[ni][ks], acc[mi][ni + 2]);
    __builtin_amdgcn_s_setprio(0);
    BAR();
    // ---- ph7 ----
#pragma unroll
    for (int mi = 0; mi < 4; ++mi)
#pragma unroll
      for (int ks = 0; ks < 2; ++ks)
        a1[mi][ks] = LDA(1, wr * 128 + 64 + mi * 16 + lr, ks);
    if (t + 3 < nt) stage_half(1, 1, 0, t + 3);   // (t+3).B0 (free after ph6)
    BAR(); LGKM0();
    __builtin_amdgcn_s_setprio(1);
#pragma unroll
    for (int mi = 0; mi < 4; ++mi)
#pragma unroll
      for (int ni = 0; ni < 2; ++ni)
#pragma unroll
        for (int ks = 0; ks < 2; ++ks)
          acc[mi + 4][ni + 2] = mfma16(a1[mi][ks], b1f[ni][ks], acc[mi + 4][ni + 2]);
    __builtin_amdgcn_s_setprio(0);
    BAR();
    // ---- ph8: regs only; stage B1'+A0' ----
    if (t + 3 < nt) { stage_half(1, 1, 1, t + 3); stage_half(1, 0, 0, t + 3); }
    BAR();
    __builtin_amdgcn_s_setprio(1);
#pragma unroll
    for (int mi = 0; mi < 4; ++mi)
#pragma unroll
      for (int ni = 0; ni < 2; ++ni)
#pragma unroll
        for (int ks = 0; ks < 2; ++ks)
          acc[mi + 4][ni] = mfma16(a1[mi][ks], b0f[ni][ks], acc[mi + 4][ni]);
    __builtin_amdgcn_s_setprio(0);
    if (t + 3 < nt) { WVM6(); } else { WVM0(); }
    BAR();
  }

  // ---- epilogue ----
  if (OUTMODE == 0) {
    // LDS-bounce: tile -> LDS (128 KB), then fully-coalesced 16B/lane stores.
    __syncthreads();
    u16* cw = (u16*)&lds[0][0][0][0];       // [256][256] u16
#pragma unroll
    for (int ni = 0; ni < 4; ++ni) {
      const int col = wc * 64 + ni * 16 + lr;
      const float bv = biasp[n0 + col];
#pragma unroll
      for (int mi = 0; mi < 8; ++mi)
#pragma unroll
        for (int j = 0; j < 4; ++j) {
          const int row = wr * 128 + mi * 16 + lg * 4 + j;
          cw[row * 256 + col] = f2b(acc[mi][ni][j] + bv);
        }
    }
    __syncthreads();
#pragma unroll
    for (int it = 0; it < 16; ++it) {
      int c = it * 512 + tid;
      int row = c >> 5, ch = c & 31;
      i32x4 v = *(const i32x4*)&cw[row * 256 + ch * 8];
      *(i32x4*)((u16*)Cp + (size_t)(m0 + row) * 1024 + n0 + ch * 8) = v;
    }
  } else {
#pragma unroll
    for (int ni = 0; ni < 4; ++ni) {
      const int col = n0 + wc * 64 + ni * 16 + lr;
      const float bv = (OUTMODE == 2) ? 0.f : biasp[col];
#pragma unroll
      for (int mi = 0; mi < 8; ++mi)
#pragma unroll
        for (int j = 0; j < 4; ++j) {
          const int row = m0 + wr * 128 + mi * 16 + lg * 4 + j;
          const float v = acc[mi][ni][j] + bv;
          if (OUTMODE == 2)
            ((float*)Cp)[(size_t)sp * M * 1024 + (size_t)row * 1024 + col] = v;
          else
            ((float*)Cp)[(size_t)row * 1024 + col] = v;
        }
    }
  }
}

// ---------------------------------------------------------------------------
// Legacy 128x128 GEMM — fallback paths only (small workspace)
// ---------------------------------------------------------------------------
template<int AMODE, int OUTMODE>
__global__ __launch_bounds__(256)
void gemm_bt(const void* A0p, const void* A1p, const void* A2p,
             const u16* B0p, const u16* B1p, const u16* B2p,
             const float* b0p, const float* b1p, const float* b2p,
             void* C0p, void* C1p, void* C2p,
             int M, int K, int kspl) {
  const int zc = blockIdx.z / kspl;
  const int sp = blockIdx.z % kspl;
  const void* Ap = zc == 0 ? A0p : (zc == 1 ? A1p : A2p);
  const u16* Bp = zc == 0 ? B0p : (zc == 1 ? B1p : B2p);
  const float* biasp = zc == 0 ? b0p : (zc == 1 ? b1p : b2p);
  void* Cp = zc == 0 ? C0p : (zc == 1 ? C1p : C2p);

  __shared__ u16 Alds[128 * 64];
  __shared__ u16 Blds[128 * 64];

  const int tid = threadIdx.x;
  const int w = tid >> 6, lane = tid & 63;
  const int lr = lane & 15, lg = lane >> 4;
  const int m0 = blockIdx.x * 128, n0 = blockIdx.y * 128;
  const int wr = (w >> 1) * 64, wc = (w & 1) * 64;
  const int brow = lane >> 3;
  const int bcol = (lane & 7) * 8;

  f32x4 acc[4][4];
#pragma unroll
  for (int mi = 0; mi < 4; ++mi)
#pragma unroll
    for (int ni = 0; ni < 4; ++ni) {
      f32x4 zv = {0.f, 0.f, 0.f, 0.f};
      acc[mi][ni] = zv;
    }

  const int kper = K / kspl;
  const int ktn = kper >> 6;
  const int kb = sp * kper;
  for (int kt = 0; kt < ktn; ++kt) {
    const int k0 = kb + (kt << 6);
    __syncthreads();
#pragma unroll
    for (int i = 0; i < 4; ++i) {
      const int c = w * 4 + i;
      const int row = c * 8 + brow;
      gl_lds16(Bp + (size_t)(n0 + row) * K + k0 + bcol, &Blds[c * 512]);
    }
    if (AMODE == 2) {
      const float* Af = (const float*)Ap;
#pragma unroll
      for (int i = 0; i < 4; ++i) {
        const int c = i * 256 + tid;
        const int row = c >> 3, k8 = (c & 7) * 8;
        const float* s = Af + (size_t)(m0 + row) * K + k0 + k8;
        f32x4 v0 = *(const f32x4*)s;
        f32x4 v1 = *(const f32x4*)(s + 4);
        u16x8 pk;
        pk[0] = f2b(v0[0]); pk[1] = f2b(v0[1]); pk[2] = f2b(v0[2]); pk[3] = f2b(v0[3]);
        pk[4] = f2b(v1[0]); pk[5] = f2b(v1[1]); pk[6] = f2b(v1[2]); pk[7] = f2b(v1[3]);
        *(u16x8*)&Alds[row * 64 + k8] = pk;
      }
    } else if (AMODE == 0) {
      const u16* Ab = (const u16*)Ap;
#pragma unroll
      for (int i = 0; i < 4; ++i) {
        const int c = w * 4 + i;
        const int row = c * 8 + brow;
        gl_lds16(Ab + (size_t)(m0 + row) * K + k0 + bcol, &Alds[c * 512]);
      }
    } else {
      const u16* Ab = (const u16*)Ap;
#pragma unroll
      for (int i = 0; i < 4; ++i) {
        const int c = w * 4 + i;
        const int m = m0 + c * 8 + brow;
        const int nn = m >> 8, p = m & 255;
        const int k = k0 + bcol;
        gl_lds16(Ab + (size_t)(p * 8 + (k >> 10)) * NE + nn * EDIM + (k & 1023),
                 &Alds[c * 512]);
      }
    }
    __syncthreads();
#pragma unroll
    for (int ks = 0; ks < 2; ++ks) {
      bf16x8 af[4], bf[4];
#pragma unroll
      for (int mi = 0; mi < 4; ++mi)
        af[mi] = *(const bf16x8*)&Alds[(wr + mi * 16 + lr) * 64 + ks * 32 + lg * 8];
#pragma unroll
      for (int ni = 0; ni < 4; ++ni)
        bf[ni] = *(const bf16x8*)&Blds[(wc + ni * 16 + lr) * 64 + ks * 32 + lg * 8];
#pragma unroll
      for (int mi = 0; mi < 4; ++mi)
#pragma unroll
        for (int ni = 0; ni < 4; ++ni)
          acc[mi][ni] = mfma16(af[mi], bf[ni], acc[mi][ni]);
    }
  }
#pragma unroll
  for (int ni = 0; ni < 4; ++ni) {
    const int col = n0 + wc + ni * 16 + lr;
    const float bv = (OUTMODE == 2) ? 0.f : biasp[col];
#pragma unroll
    for (int mi = 0; mi < 4; ++mi)
#pragma unroll
      for (int j = 0; j < 4; ++j) {
        const int row = m0 + wr + mi * 16 + lg * 4 + j;
        const float v = acc[mi][ni][j] + bv;
        if (OUTMODE == 4) {
          const int nn = row >> 8, pp = row & 255, h = col >> 6, d = col & 63;
          ((u16*)Cp)[(size_t)(nn * HNUM + h) * (DDIM * KPDIM) + d * 256 +
                     (((pp >> 3) ^ (d & 7)) * 8) + (pp & 7)] = f2b(v);
        } else if (OUTMODE == 3) {
          const int nn = row >> 8, pp = row & 255, h = col >> 6, d = col & 63;
          ((u16*)Cp)[((size_t)(nn * HNUM + h) * KPDIM + pp) * DDIM + d] = f2b(v);
        } else if (OUTMODE == 2)
          ((float*)Cp)[(size_t)sp * M * 1024 + (size_t)row * 1024 + col] = v;
        else if (OUTMODE == 1)
          ((float*)Cp)[(size_t)row * 1024 + col] = v;
        else
          ((u16*)Cp)[(size_t)row * 1024 + col] = f2b(v);
      }
  }
}

// ---------------------------------------------------------------------------
// Fused attention v5 (r12-verified): swapped-operand QK^T, P in registers.
// block = (64 q-rows, n, head-group of hpg). LDS 64 KB, 2 blocks/CU.
// See r12 comments for the layout derivation.
// ---------------------------------------------------------------------------
__global__ __launch_bounds__(256)
void attn_fused5(const u16* __restrict__ Q, const u16* __restrict__ Kc,
                 const u16* __restrict__ VcT, u16* __restrict__ Aout,
                 float* __restrict__ AWp, int hpg) {
  __shared__ u16 Kl[256 * 64];   // K [p][d] chunk-swizzled
  __shared__ u16 Vl[64 * 256];   // V^T [d][p] chunk-swizzled
  const int tid = threadIdx.x;
  const int w = tid >> 6, lane = tid & 63;
  const int lr = lane & 15, lg = lane >> 4;
  const int n = blockIdx.y;
  const int l0 = blockIdx.x * 64;
  const int lrow = l0 + w * 16 + lr;     // this lane's q-row (for S^T / AW)
  char* kbase = (char*)Kl;
  char* vbase = (char*)Vl;
  const int sA = lr + ((lg & 1) << 5);   // lr + 32*(lg&1)
  const int sB = sA + 16;
  const int part = lg >> 1;

  auto stageK = [&](int h) {
    const u16* kh = Kc + (size_t)(n * HNUM + h) * (KPDIM * DDIM);
#pragma unroll
    for (int it = 0; it < 8; ++it) {
      int c = it * 256 + tid, p = c >> 3, j = c & 7;
      gl_lds16(kh + p * 64 + ((j ^ (p & 7)) << 3), kbase + c * 16);
    }
  };
  auto stageV = [&](int h) {
    const u16* vh = VcT + (size_t)(n * HNUM + h) * (DDIM * KPDIM);
#pragma unroll
    for (int it = 0; it < 8; ++it) {
      int c = it * 256 + tid;
      gl_lds16(vh + c * 8, vbase + c * 16);
    }
  };

  f32x4 macc[16];
#pragma unroll
  for (int ni = 0; ni < 16; ++ni) { f32x4 zv = {0.f,0.f,0.f,0.f}; macc[ni] = zv; }

  const int hbase = blockIdx.z * hpg;
  stageK(hbase); stageV(hbase);

  for (int hh = 0; hh < hpg; ++hh) {
    const int h = hbase + hh;
    __syncthreads();   // staged K,V landed (drains vmcnt + rendezvous)
    const u16* qp = Q + (size_t)lrow * NE + n * EDIM + h * DDIM + lg * 8;
    bf16x8 aq0 = *(const bf16x8*)qp;
    bf16x8 aq1 = *(const bf16x8*)(qp + 32);
    // ---- S^T = K @ Q^T : swapped operands ----
    f32x4 s[16];
#pragma unroll
    for (int ni = 0; ni < 16; ++ni) { f32x4 zv = {0.f,0.f,0.f,0.f}; s[ni] = zv; }
#pragma unroll
    for (int ni = 0; ni < 16; ++ni) {
      int row = ni * 16 + lr;             // K row p (A-operand, lane lr)
      const char* kr = kbase + row * 128;
      bf16x8 k0 = *(const bf16x8*)(kr + ((lg ^ (row & 7)) << 4));
      bf16x8 k1 = *(const bf16x8*)(kr + (((4 + lg) ^ (row & 7)) << 4));
      s[ni] = mfma16(k0, aq0, s[ni]);
      s[ni] = mfma16(k1, aq1, s[ni]);
    }
    LGKM0();
    BAR();            // all waves' K reads done -> K region free
    if (hh + 1 < hpg) stageK(h + 1);      // overlaps softmax+pack+PV
    // ---- softmax: per-lane scalar (q = lr) ----
    float mx = -1e30f;
#pragma unroll
    for (int ni = 0; ni < 16; ++ni)
#pragma unroll
      for (int j = 0; j < 4; ++j) mx = fmaxf(mx, s[ni][j]);
    mx = fmaxf(mx, __shfl_xor(mx, 16, 64));
    mx = fmaxf(mx, __shfl_xor(mx, 32, 64));
    float sm = 0.f;
#pragma unroll
    for (int ni = 0; ni < 16; ++ni)
#pragma unroll
      for (int j = 0; j < 4; ++j) {
        float e = __expf(s[ni][j] - mx);
        s[ni][j] = e; sm += e;
      }
    sm += __shfl_xor(sm, 16, 64);
    sm += __shfl_xor(sm, 32, 64);
    const float inv = 1.0f / sm;
#pragma unroll
    for (int ni = 0; ni < 16; ++ni) {
#pragma unroll
      for (int j = 0; j < 4; ++j) s[ni][j] *= inv;   // normalized P
      macc[ni] += s[ni] * 0.0625f;                   // head-mean accum
    }
    // ---- pack P into A-frags (cross-lane quad exchange) + PV ----
    f32x4 o[4];
#pragma unroll
    for (int ni2 = 0; ni2 < 4; ++ni2) { f32x4 zv = {0.f,0.f,0.f,0.f}; o[ni2] = zv; }
#pragma unroll
    for (int ks = 0; ks < 8; ++ks) {
      unsigned lo0 = pk2(s[2 * ks][0], s[2 * ks][1]);
      unsigned lo1 = pk2(s[2 * ks][2], s[2 * ks][3]);
      unsigned hi0 = pk2(s[2 * ks + 1][0], s[2 * ks + 1][1]);
      unsigned hi1 = pk2(s[2 * ks + 1][2], s[2 * ks + 1][3]);
      unsigned aL0 = (unsigned)__shfl((int)lo0, sA, 64);
      unsigned aL1 = (unsigned)__shfl((int)lo1, sA, 64);
      unsigned aH0 = (unsigned)__shfl((int)hi0, sA, 64);
      unsigned aH1 = (unsigned)__shfl((int)hi1, sA, 64);
      unsigned bL0 = (unsigned)__shfl((int)lo0, sB, 64);
      unsigned bL1 = (unsigned)__shfl((int)lo1, sB, 64);
      unsigned bH0 = (unsigned)__shfl((int)hi0, sB, 64);
      unsigned bH1 = (unsigned)__shfl((int)hi1, sB, 64);
      i32x4 pu;
      pu[0] = (int)(part ? aH0 : aL0);
      pu[1] = (int)(part ? aH1 : aL1);
      pu[2] = (int)(part ? bH0 : bL0);
      pu[3] = (int)(part ? bH1 : bL1);
      bf16x8 pa = __builtin_bit_cast(bf16x8, pu);
#pragma unroll
      for (int ni2 = 0; ni2 < 4; ++ni2) {
        int d = ni2 * 16 + lr;
        bf16x8 vf = *(const bf16x8*)(vbase + d * 512 + (((ks * 4 + lg) ^ (d & 7)) << 4));
        o[ni2] = mfma16(pa, vf, o[ni2]);
      }
    }
    // ---- write O tile (rows q = lg*4+j; already normalized) ----
#pragma unroll
    for (int ni2 = 0; ni2 < 4; ++ni2)
#pragma unroll
      for (int j = 0; j < 4; ++j) {
        int gl = l0 + w * 16 + lg * 4 + j;
        Aout[(size_t)gl * NE + n * EDIM + h * DDIM + ni2 * 16 + lr] = f2b(o[ni2][j]);
      }
    LGKM0();
    BAR();            // all waves' V reads done -> V region free
    if (hh + 1 < hpg) stageV(h + 1);
  }
  // ---- write head-mean attention weight partial: lane owns q-row lrow ----
  float* awo = AWp + (size_t)blockIdx.z * AWSZ + (size_t)n * (LSEQ * KPDIM)
             + (size_t)lrow * KPDIM;
#pragma unroll
  for (int ni = 0; ni < 16; ++ni)
    *(f32x4*)(awo + ni * 16 + lg * 4) = macc[ni];
}

// ---------------------------------------------------------------------------
// Fused attention v3 (r9/r11, stable) — fallback path only (small workspace).
// ---------------------------------------------------------------------------
__global__ __launch_bounds__(256)
void attn_fused(const u16* __restrict__ Q, const u16* __restrict__ Kc,
                const u16* __restrict__ VcT, u16* __restrict__ Aout,
                float* __restrict__ AWp, int hpg) {
  __shared__ u16 Ares[256 * 64];
  __shared__ u16 Bres[64 * 256];
  const int tid = threadIdx.x;
  const int w = tid >> 6, lane = tid & 63;
  const int lr = lane & 15, lg = lane >> 4;
  const int n = blockIdx.y;
  const int l0 = blockIdx.x * 64;
  const int lrow = l0 + w * 16 + lr;
  char* kbase = (char*)Ares;
  char* vbase = (char*)Bres;
  char* pbase = (char*)Ares + w * 8192;

  f32x4 macc[16];
#pragma unroll
  for (int ni = 0; ni < 16; ++ni) { f32x4 zv = {0.f,0.f,0.f,0.f}; macc[ni] = zv; }

  for (int hh = 0; hh < hpg; ++hh) {
    const int h = blockIdx.z * hpg + hh;
    const u16* kh = Kc + (size_t)(n * HNUM + h) * (KPDIM * DDIM);
    const u16* vh = VcT + (size_t)(n * HNUM + h) * (DDIM * KPDIM);
    __syncthreads();
#pragma unroll
    for (int it = 0; it < 8; ++it) {
      int c = it * 256 + tid;
      int p = c >> 3, j = c & 7;
      gl_lds16(kh + p * 64 + ((j ^ (p & 7)) << 3), kbase + c * 16);
    }
#pragma unroll
    for (int it = 0; it < 8; ++it) {
      int c = it * 256 + tid;
      gl_lds16(vh + c * 8, vbase + c * 16);
    }
    const u16* qp = Q + (size_t)lrow * NE + n * EDIM + h * DDIM + lg * 8;
    bf16x8 aq0 = *(const bf16x8*)qp;
    bf16x8 aq1 = *(const bf16x8*)(qp + 32);
    __syncthreads();
    f32x4 s[16];
#pragma unroll
    for (int ni = 0; ni < 16; ++ni) { f32x4 zv = {0.f,0.f,0.f,0.f}; s[ni] = zv; }
#pragma unroll
    for (int ni = 0; ni < 16; ++ni) {
      int row = ni * 16 + lr;
      const char* kr = kbase + row * 128;
      bf16x8 b0 = *(const bf16x8*)(kr + ((lg ^ (row & 7)) << 4));
      bf16x8 b1 = *(const bf16x8*)(kr + (((4 + lg) ^ (row & 7)) << 4));
      s[ni] = mfma16(aq0, b0, s[ni]);
      s[ni] = mfma16(aq1, b1, s[ni]);
    }
    float mx[4], sm[4], inv[4], invs[4];
#pragma unroll
    for (int j = 0; j < 4; ++j) mx[j] = -1e30f;
#pragma unroll
    for (int ni = 0; ni < 16; ++ni)
#pragma unroll
      for (int j = 0; j < 4; ++j) mx[j] = fmaxf(mx[j], s[ni][j]);
#pragma unroll
    for (int msk = 1; msk <= 8; msk <<= 1)
#pragma unroll
      for (int j = 0; j < 4; ++j) mx[j] = fmaxf(mx[j], __shfl_xor(mx[j], msk, 64));
#pragma unroll
    for (int j = 0; j < 4; ++j) sm[j] = 0.f;
#pragma unroll
    for (int ni = 0; ni < 16; ++ni)
#pragma unroll
      for (int j = 0; j < 4; ++j) {
        float e = __expf(s[ni][j] - mx[j]);
        s[ni][j] = e; sm[j] += e;
      }
#pragma unroll
    for (int msk = 1; msk <= 8; msk <<= 1)
#pragma unroll
      for (int j = 0; j < 4; ++j) sm[j] += __shfl_xor(sm[j], msk, 64);
#pragma unroll
    for (int j = 0; j < 4; ++j) { inv[j] = 1.0f / sm[j]; invs[j] = inv[j] * 0.0625f; }
    __syncthreads();
#pragma unroll
    for (int ni = 0; ni < 16; ++ni)
#pragma unroll
      for (int j = 0; j < 4; ++j) {
        macc[ni][j] += s[ni][j] * invs[j];
        int r = lg * 4 + j;
        *(u16*)(pbase + r * 512 + ((ni * 32 + lr * 2) ^ ((r & 7) << 4))) =
            f2b(s[ni][j]);
      }
    f32x4 o[4];
#pragma unroll
    for (int ni2 = 0; ni2 < 4; ++ni2) { f32x4 zv = {0.f,0.f,0.f,0.f}; o[ni2] = zv; }
#pragma unroll
    for (int ks = 0; ks < 8; ++ks) {
      bf16x8 a = *(const bf16x8*)(pbase + lr * 512 + ((ks * 64 + 16 * lg) ^ ((lr & 7) << 4)));
#pragma unroll
      for (int ni2 = 0; ni2 < 4; ++ni2) {
        int d = ni2 * 16 + lr;
        bf16x8 b = *(const bf16x8*)(vbase + d * 512 + (((ks * 4 + lg) ^ (d & 7)) << 4));
        o[ni2] = mfma16(a, b, o[ni2]);
      }
    }
#pragma unroll
    for (int ni2 = 0; ni2 < 4; ++ni2)
#pragma unroll
      for (int j = 0; j < 4; ++j) {
        int gl = l0 + w * 16 + lg * 4 + j;
        Aout[(size_t)gl * NE + n * EDIM + h * DDIM + ni2 * 16 + lr] =
            f2b(o[ni2][j] * inv[j]);
      }
  }
  float* awo = AWp + (size_t)blockIdx.z * AWSZ + (size_t)n * (LSEQ * KPDIM);
#pragma unroll
  for (int ni = 0; ni < 16; ++ni)
#pragma unroll
    for (int j = 0; j < 4; ++j) {
      int r = lg * 4 + j;
      awo[(size_t)(l0 + w * 16 + r) * KPDIM + ni * 16 + lr] = macc[ni][j];
    }
}

// ---------------------------------------------------------------------------
extern "C" void kernel_launch(void* const* d_in, const int* in_sizes, int n_in,
                              void* d_out, int out_size, void* d_ws, size_t ws_size,
                              hipStream_t stream) {
  const float* query = (const float*)d_in[0];
  const float* key   = (const float*)d_in[1];
  const float* value = (const float*)d_in[2];
  const float* ipw   = (const float*)d_in[3];
  const float* ipb   = (const float*)d_in[4];
  const float* ew    = (const float*)d_in[5];
  const float* eb    = (const float*)d_in[6];
  const float* fw    = (const float*)d_in[7];
  const float* fb    = (const float*)d_in[8];
  const float* ow    = (const float*)d_in[9];
  const float* ob    = (const float*)d_in[10];

  char* ws = (char*)d_ws;
  size_t off = 0;
  auto alloc = [&](size_t bytes) {
    void* p = ws + off;
    off += (bytes + 255) & ~(size_t)255;
    return p;
  };
  u16* qp    = (u16*)alloc((size_t)MROWS * EDIM * 2);
  u16* kp    = (u16*)alloc((size_t)MROWS * EDIM * 2);
  u16* vp    = (u16*)alloc((size_t)MROWS * EDIM * 2);
  u16* ao    = (u16*)alloc((size_t)MROWS * EDIM * 2);
  u16* kc    = (u16*)alloc((size_t)NB * KPDIM * EDIM * 2);   // (N,H,Kp,D)
  u16* vcT   = (u16*)alloc((size_t)NB * KPDIM * EDIM * 2);   // (N,H,D,Kp) swz
  u16* w_in  = (u16*)alloc((size_t)3 * EDIM * EDIM * 2);
  u16* w_eT  = (u16*)alloc((size_t)EDIM * 8 * EDIM * 2);
  u16* w_fT  = (u16*)alloc((size_t)EDIM * 8 * EDIM * 2);
  u16* w_out = (u16*)alloc((size_t)EDIM * EDIM * 2);
  float* bq  = (float*)alloc(EDIM * 4);
  size_t base_needed = off;

  size_t qkv16_b = (size_t)3 * MROWS * EDIM * 2;
  size_t part_b  = (size_t)2 * 4 * 2048 * 1024 * 4;
  bool bigX  = ws_size >= base_needed + qkv16_b;
  bool midX  = ws_size >= base_needed + part_b;
  char* X = (char*)alloc(bigX ? qkv16_b : (midX ? part_b : 0));
  u16* qkv16 = (u16*)X;
  float* part = (float*)X;
  float* awp  = (float*)X;

  float* out_f = (float*)d_out;                        // (L, N, E)
  float* aw_f  = (float*)d_out + (size_t)MROWS * EDIM; // (N, L, Kp)

  // weight prep (merged) + conv-weight transpose
  prep1<<<dim3(3072), 256, 0, stream>>>(ipw, ow, ipb, w_in, w_out, bq);
  wtrans<<<dim3(16384, 2), 64, 0, stream>>>(ew, fw, w_eT, w_fT);

  // q/k/v projections
  if (bigX) {
    castqkv<<<dim3(8192, 3), 256, 0, stream>>>(query, key, value, qkv16);
    gemm256<0, 0><<<dim3(64, 4, 3), 512, 0, stream>>>(
        qkv16, qkv16 + (size_t)MROWS * EDIM, qkv16 + (size_t)2 * MROWS * EDIM,
        w_in, w_in + 1048576, w_in + 2097152,
        bq, ipb + 1024, ipb + 2048,
        qp, kp, vp, MROWS, 1024, 1);
  } else {
    gemm_bt<2, 0><<<dim3(128, 8, 3), 256, 0, stream>>>(
        query, key, value,
        w_in, w_in + 1048576, w_in + 2097152,
        bq, ipb + 1024, ipb + 2048,
        qp, kp, vp, MROWS, 1024, 1);
  }

  // conv compression of k and v -> kc (head-major) / vcT (transposed swz)
  if (bigX || midX) {
    gemm256<1, 2><<<dim3(8, 4, 8), 512, 0, stream>>>(
        kp, vp, vp,
        w_eT, w_fT, w_fT,
        eb, fb, fb,
        part, part + (size_t)4 * 2048 * 1024, part,
        NB * KPDIM, 8192, 4);
    redc<<<dim3(2048, 2), 256, 0, stream>>>(part, eb, fb, kc, vcT);
  } else {
    gemm_bt<1, 3><<<dim3(16, 8, 1), 256, 0, stream>>>(
        kp, kp, kp, w_eT, w_eT, w_eT, eb, eb, eb,
        kc, kc, kc, NB * KPDIM, 8192, 1);
    gemm_bt<1, 4><<<dim3(16, 8, 1), 256, 0, stream>>>(
        vp, vp, vp, w_fT, w_fT, w_fT, fb, fb, fb,
        vcT, vcT, vcT, NB * KPDIM, 8192, 1);
  }

  // fused attention + head-mean weights (z=2: 512 blocks = exactly 2/CU)
  if (bigX) {
    attn_fused5<<<dim3(32, 8, 2), 256, 0, stream>>>(qp, kc, vcT, ao, awp, 8);
    awred<<<dim3(4096), 256, 0, stream>>>(awp, aw_f);
  } else {
    attn_fused<<<dim3(32, 8, 1), 256, 0, stream>>>(qp, kc, vcT, ao, aw_f, 16);
  }

  // output projection -> f32 d_out
  gemm256<0, 1><<<dim3(64, 4, 1), 512, 0, stream>>>(
      ao, ao, ao,
      w_out, w_out, w_out,
      ob, ob, ob,
      out_f, out_f, out_f, MROWS, 1024, 1);
}

// Round 14
// 408.790 us; speedup vs baseline: 1.2186x; 1.0149x over previous
//
#include <hip/hip_runtime.h>

typedef unsigned short u16;
typedef u16  u16x4 __attribute__((ext_vector_type(4)));
typedef u16  u16x8 __attribute__((ext_vector_type(8)));
typedef float f32x4 __attribute__((ext_vector_type(4)));
typedef int   i32x4 __attribute__((ext_vector_type(4)));
typedef __bf16 bf16x8 __attribute__((ext_vector_type(8)));

#define LSEQ 2048
#define NB 8
#define EDIM 1024
#define HNUM 16
#define DDIM 64
#define KPDIM 256
#define NE (NB*EDIM)       /* 8192 */
#define MROWS (LSEQ*NB)    /* 16384 */
#define AWSZ ((size_t)NB*LSEQ*KPDIM)  /* 4194304 */

__device__ __forceinline__ u16 f2b(float f) {
  unsigned u = __builtin_bit_cast(unsigned, f);
  u += 0x7fffu + ((u >> 16) & 1u);
  return (u16)(u >> 16);
}

__device__ __forceinline__ unsigned pk2(float a, float b) {
  return (unsigned)f2b(a) | ((unsigned)f2b(b) << 16);
}

__device__ __forceinline__ void gl_lds16(const void* g, void* l) {
  __builtin_amdgcn_global_load_lds(
      (const __attribute__((address_space(1))) void*)g,
      (__attribute__((address_space(3))) void*)l, 16, 0, 0);
}

__device__ __forceinline__ f32x4 mfma16(bf16x8 a, bf16x8 b, f32x4 c) {
  return __builtin_amdgcn_mfma_f32_16x16x32_bf16(a, b, c, 0, 0, 0);
}

#define BAR()   __builtin_amdgcn_s_barrier()
#define LGKM0() asm volatile("s_waitcnt lgkmcnt(0)" ::: "memory")
#define WVM6()  asm volatile("s_waitcnt vmcnt(6)" ::: "memory")
#define WVM0()  asm volatile("s_waitcnt vmcnt(0)" ::: "memory")

// ---------------------------------------------------------------------------
// Weight prep: in_proj cast (+q scale), out_w cast, q-bias scale — one launch
// ---------------------------------------------------------------------------
__global__ void prep1(const float* __restrict__ ipw, const float* __restrict__ ow,
                      const float* __restrict__ ipb, u16* __restrict__ w_in,
                      u16* __restrict__ w_out, float* __restrict__ bq) {
  int i = blockIdx.x * blockDim.x + threadIdx.x;
  if (i < 786432) {
    f32x4 v = ((const f32x4*)ipw)[i];
    float s = (i < 262144) ? 0.125f : 1.0f;
    u16x4 o;
    o[0] = f2b(v[0] * s); o[1] = f2b(v[1] * s);
    o[2] = f2b(v[2] * s); o[3] = f2b(v[3] * s);
    ((u16x4*)w_in)[i] = o;
  }
  if (i < 262144) {
    f32x4 v = ((const f32x4*)ow)[i];
    u16x4 o;
    o[0] = f2b(v[0]); o[1] = f2b(v[1]); o[2] = f2b(v[2]); o[3] = f2b(v[3]);
    ((u16x4*)w_out)[i] = o;
  }
  if (i < 256) {
    f32x4 b = ((const f32x4*)ipb)[i];
    ((f32x4*)bq)[i] = b * 0.125f;
  }
}

// (O, I, 8) f32  ->  (O, t*E + i) bf16   (per-wave LDS transpose)
__global__ void wtrans(const float* __restrict__ ew, const float* __restrict__ fw,
                       u16* __restrict__ eT, u16* __restrict__ fT) {
  const float* src = blockIdx.y ? fw : ew;
  u16* dst = blockIdx.y ? fT : eT;
  int eo = blockIdx.x >> 4;
  int ei0 = (blockIdx.x & 15) * 64;
  int l = threadIdx.x;
  __shared__ u16 lds[8][64];
  const float* s = src + (size_t)eo * 8192 + (size_t)ei0 * 8 + l * 8;
  f32x4 a = *(const f32x4*)s;
  f32x4 b = *(const f32x4*)(s + 4);
  float v[8] = {a[0], a[1], a[2], a[3], b[0], b[1], b[2], b[3]};
#pragma unroll
  for (int t = 0; t < 8; ++t) lds[t][l] = f2b(v[t]);
  __syncthreads();
  int t = l >> 3, c = l & 7;
  i32x4 out = *(const i32x4*)&lds[t][c * 8];
  *(i32x4*)(dst + (size_t)eo * 8192 + t * 1024 + ei0 + c * 8) = out;
}

// q/k/v f32 -> bf16, contiguous [3][MROWS][E]
__global__ void castqkv(const float* __restrict__ q, const float* __restrict__ k,
                        const float* __restrict__ v, u16* __restrict__ out) {
  const float* src = blockIdx.y == 0 ? q : (blockIdx.y == 1 ? k : v);
  size_t base = (size_t)blockIdx.y * ((size_t)MROWS * EDIM);
  size_t i = ((size_t)blockIdx.x * 256 + threadIdx.x) * 8;
  f32x4 v0 = *(const f32x4*)(src + i);
  f32x4 v1 = *(const f32x4*)(src + i + 4);
  u16x8 o;
  o[0] = f2b(v0[0]); o[1] = f2b(v0[1]); o[2] = f2b(v0[2]); o[3] = f2b(v0[3]);
  o[4] = f2b(v1[0]); o[5] = f2b(v1[1]); o[6] = f2b(v1[2]); o[7] = f2b(v1[3]);
  *(u16x8*)(out + base + i) = o;
}

// sum 4 split-K partials + bias -> bf16.
// K -> head-major (N,H,Kp,D). V -> transposed (N,H,D,Kp) chunk-swizzled.
__global__ void redc(const float* __restrict__ part, const float* __restrict__ eb,
                     const float* __restrict__ fb, u16* __restrict__ kc,
                     u16* __restrict__ vcT) {
  int zc = blockIdx.y;
  const float* p = part + (size_t)zc * 4 * 2048 * 1024;
  const float* bias = zc ? fb : eb;
  size_t i = ((size_t)blockIdx.x * 256 + threadIdx.x) * 4;
  f32x4 s = *(const f32x4*)(p + i);
  s += *(const f32x4*)(p + 2097152 + i);
  s += *(const f32x4*)(p + 2 * 2097152 + i);
  s += *(const f32x4*)(p + 3 * 2097152 + i);
  int e = (int)(i & 1023);
  int row = (int)(i >> 10);           // n*256 + p
  int n = row >> 8, pp = row & 255;
  int h = e >> 6, d = e & 63;
  f32x4 b = *(const f32x4*)(bias + e);
  if (zc == 0) {
    u16x4 o;
    o[0] = f2b(s[0] + b[0]); o[1] = f2b(s[1] + b[1]);
    o[2] = f2b(s[2] + b[2]); o[3] = f2b(s[3] + b[3]);
    *(u16x4*)(kc + (((size_t)(n * HNUM + h) * KPDIM + pp) * DDIM + d)) = o;
  } else {
    size_t base = (size_t)(n * HNUM + h) * (DDIM * KPDIM);
#pragma unroll
    for (int q = 0; q < 4; ++q) {
      int dq = d + q;
      vcT[base + dq * 256 + (((pp >> 3) ^ (dq & 7)) * 8) + (pp & 7)] =
          f2b(s[q] + b[q]);
    }
  }
}

// sum the 2 head-group AW partials
__global__ void awred(const float* __restrict__ awp, float* __restrict__ aw) {
  size_t i = ((size_t)blockIdx.x * 256 + threadIdx.x) * 4;
  f32x4 s = *(const f32x4*)(awp + i);
  s += *(const f32x4*)(awp + AWSZ + i);
  *(f32x4*)(aw + i) = s;
}

// ---------------------------------------------------------------------------
// 256x256 GEMM — 8-phase ring schedule (r8, verified) + coalesced bf16
// epilogue (r9). Reader/stage ring and vmcnt ledger: see r8 comments.
//   AMODE 0: A bf16 rows contiguous (ld=K); AMODE 1: conv-gather
//   OUTMODE 0: bf16 C+bias (LDS-bounced); 1: f32 C+bias; 2: f32 split-K partial
// grid = (M/256, N/256, nz*kspl); block = 512 (8 waves, 2M x 4N); nt even
// ---------------------------------------------------------------------------
template<int AMODE, int OUTMODE>
__global__ __launch_bounds__(512, 2)
void gemm256(const void* A0p, const void* A1p, const void* A2p,
             const u16* B0p, const u16* B1p, const u16* B2p,
             const float* b0p, const float* b1p, const float* b2p,
             void* C0p, void* C1p, void* C2p,
             int M, int K, int kspl) {
  const int zc = blockIdx.z / kspl, sp = blockIdx.z % kspl;
  const void* Ap = zc == 0 ? A0p : (zc == 1 ? A1p : A2p);
  const u16* Bp = zc == 0 ? B0p : (zc == 1 ? B1p : B2p);
  const float* biasp = zc == 0 ? b0p : (zc == 1 ? b1p : b2p);
  void* Cp = zc == 0 ? C0p : (zc == 1 ? C1p : C2p);

  __shared__ u16 lds[2][2][2][128 * 64];  // [buf][A=0/B=1][half][r*64+swzchunk*8]

  const int tid = threadIdx.x;
  const int w = tid >> 6, lane = tid & 63;
  const int lr = lane & 15, lg = lane >> 4;
  const int wr = w >> 2, wc = w & 3;            // 2M x 4N waves
  const int m0 = blockIdx.x * 256, n0 = blockIdx.y * 256;
  const int kper = K / kspl, kbase = sp * kper, nt = kper >> 6;

  f32x4 acc[8][4];
#pragma unroll
  for (int mi = 0; mi < 8; ++mi)
#pragma unroll
    for (int ni = 0; ni < 4; ++ni) {
      f32x4 zv = {0.f, 0.f, 0.f, 0.f};
      acc[mi][ni] = zv;
    }

  // stage one 16KB half: op (0=A,1=B), half (0/1 = rows 0-127/128-255), tile kt
  auto stage_half = [&](int buf, int op, int half, int kt) {
    const int k0 = kbase + (kt << 6);
#pragma unroll
    for (int i = 0; i < 2; ++i) {
      int c = i * 512 + tid;               // 0..1023
      int r = c >> 3, j = c & 7, js = j ^ (r & 7);
      int row = half * 128 + r;
      u16* dst = &lds[buf][op][half][c * 8];
      if (op == 1) {
        gl_lds16(Bp + (size_t)(n0 + row) * K + k0 + js * 8, dst);
      } else if (AMODE == 0) {
        gl_lds16((const u16*)Ap + (size_t)(m0 + row) * K + k0 + js * 8, dst);
      } else {  // conv gather: m=(nn,p), k=(t,ei); k0 mult of 64, no 1024-cross
        int m = m0 + row;
        int nn = m >> 8, p = m & 255;
        int k = k0 + js * 8;
        gl_lds16((const u16*)Ap + (size_t)(p * 8 + (k >> 10)) * NE +
                 nn * EDIM + (k & 1023), dst);
      }
    }
  };

  auto LDA = [&](int buf, int row, int ks) -> bf16x8 {
    return *(const bf16x8*)&lds[buf][0][row >> 7]
        [(row & 127) * 64 + (((ks * 4 + lg) ^ (row & 7)) << 3)];
  };
  auto LDB = [&](int buf, int row, int ks) -> bf16x8 {
    return *(const bf16x8*)&lds[buf][1][row >> 7]
        [(row & 127) * 64 + (((ks * 4 + lg) ^ (row & 7)) << 3)];
  };

  // ---- prologue: T0 all 4 halves -> buf0; T1 B0,B1,A0 -> buf1 ----
  stage_half(0, 0, 0, 0); stage_half(0, 1, 0, 0);
  stage_half(0, 1, 1, 0); stage_half(0, 0, 1, 0);
  if (nt > 1) {
    stage_half(1, 1, 0, 1); stage_half(1, 1, 1, 1); stage_half(1, 0, 0, 1);
    WVM6();
  } else {
    WVM0();
  }
  BAR();

  for (int t = 0; t < nt; t += 2) {
    bf16x8 a0[4][2], a1[4][2], b0f[2][2], b1f[2][2];
    // ================= tile t (buf0) =================
    // ---- ph1: reads a0, b0 ----
#pragma unroll
    for (int mi = 0; mi < 4; ++mi)
#pragma unroll
      for (int ks = 0; ks < 2; ++ks)
        a0[mi][ks] = LDA(0, wr * 128 + mi * 16 + lr, ks);
#pragma unroll
    for (int ni = 0; ni < 2; ++ni)
#pragma unroll
      for (int ks = 0; ks < 2; ++ks)
        b0f[ni][ks] = LDB(0, wc * 64 + ni * 16 + lr, ks);
    stage_half(1, 0, 1, t + 1);            // (t+1).A1 (free since prev ph7)
    BAR(); LGKM0();
    __builtin_amdgcn_s_setprio(1);
#pragma unroll
    for (int mi = 0; mi < 4; ++mi)
#pragma unroll
      for (int ni = 0; ni < 2; ++ni)
#pragma unroll
        for (int ks = 0; ks < 2; ++ks)
          acc[mi][ni] = mfma16(a0[mi][ks], b0f[ni][ks], acc[mi][ni]);
    __builtin_amdgcn_s_setprio(0);
    BAR();
    // ---- ph2: reads b1; no stage ----
#pragma unroll
    for (int ni = 0; ni < 2; ++ni)
#pragma unroll
      for (int ks = 0; ks < 2; ++ks)
        b1f[ni][ks] = LDB(0, wc * 64 + (ni + 2) * 16 + lr, ks);
    BAR(); LGKM0();
    __builtin_amdgcn_s_setprio(1);
#pragma unroll
    for (int mi = 0; mi < 4; ++mi)
#pragma unroll
      for (int ni = 0; ni < 2; ++ni)
#pragma unroll
        for (int ks = 0; ks < 2; ++ks)
          acc[mi][ni + 2] = mfma16(a0[mi][ks], b1f[ni][ks], acc[mi][ni + 2]);
    __builtin_amdgcn_s_setprio(0);
    BAR();
    // ---- ph3: reads a1 ----
#pragma unroll
    for (int mi = 0; mi < 4; ++mi)
#pragma unroll
      for (int ks = 0; ks < 2; ++ks)
        a1[mi][ks] = LDA(0, wr * 128 + 64 + mi * 16 + lr, ks);
    if (t + 2 < nt) stage_half(0, 1, 0, t + 2);   // (t+2).B0 (free after ph2)
    BAR(); LGKM0();
    __builtin_amdgcn_s_setprio(1);
#pragma unroll
    for (int mi = 0; mi < 4; ++mi)
#pragma unroll
      for (int ni = 0; ni < 2; ++ni)
#pragma unroll
        for (int ks = 0; ks < 2; ++ks)
          acc[mi + 4][ni + 2] = mfma16(a1[mi][ks], b1f[ni][ks], acc[mi + 4][ni + 2]);
    __builtin_amdgcn_s_setprio(0);
    BAR();
    // ---- ph4: regs only; stage B1+A0 ----
    if (t + 2 < nt) { stage_half(0, 1, 1, t + 2); stage_half(0, 0, 0, t + 2); }
    BAR();
    __builtin_amdgcn_s_setprio(1);
#pragma unroll
    for (int mi = 0; mi < 4; ++mi)
#pragma unroll
      for (int ni = 0; ni < 2; ++ni)
#pragma unroll
        for (int ks = 0; ks < 2; ++ks)
          acc[mi + 4][ni] = mfma16(a1[mi][ks], b0f[ni][ks], acc[mi + 4][ni]);
    __builtin_amdgcn_s_setprio(0);
    if (t + 2 < nt) { WVM6(); } else { WVM0(); }
    BAR();
    // ================= tile t+1 (buf1) =================
    // ---- ph5 ----
#pragma unroll
    for (int mi = 0; mi < 4; ++mi)
#pragma unroll
      for (int ks = 0; ks < 2; ++ks)
        a0[mi][ks] = LDA(1, wr * 128 + mi * 16 + lr, ks);
#pragma unroll
    for (int ni = 0; ni < 2; ++ni)
#pragma unroll
      for (int ks = 0; ks < 2; ++ks)
        b0f[ni][ks] = LDB(1, wc * 64 + ni * 16 + lr, ks);
    if (t + 2 < nt) stage_half(0, 0, 1, t + 2);   // (t+2).A1 (free after ph3)
    BAR(); LGKM0();
    __builtin_amdgcn_s_setprio(1);
#pragma unroll
    for (int mi = 0; mi < 4; ++mi)
#pragma unroll
      for (int ni = 0; ni < 2; ++ni)
#pragma unroll
        for (int ks = 0; ks < 2; ++ks)
          acc[mi][ni] = mfma16(a0[mi][ks], b0f[ni][ks], acc[mi][ni]);
    __builtin_amdgcn_s_setprio(0);
    BAR();
    // ---- ph6: no stage ----
#pragma unroll
    for (int ni = 0; ni < 2; ++ni)
#pragma unroll
      for (int ks = 0; ks < 2; ++ks)
        b1f[ni][ks] = LDB(1, wc * 64 + (ni + 2) * 16 + lr, ks);
    BAR(); LGKM0();
    __builtin_amdgcn_s_setprio(1);
#pragma unroll
    for (int mi = 0; mi < 4; ++mi)
#pragma unroll
      for (int ni = 0; ni < 2; ++ni)
#pragma unroll
        for (int ks = 0; ks < 2; ++ks)
          acc[mi][ni + 2] = mfma16(a0[mi][ks], b1f[ni][ks], acc[mi][ni + 2]);
    __builtin_amdgcn_s_setprio(0);
    BAR();
    // ---- ph7 ----
#pragma unroll
    for (int mi = 0; mi < 4; ++mi)
#pragma unroll
      for (int ks = 0; ks < 2; ++ks)
        a1[mi][ks] = LDA(1, wr * 128 + 64 + mi * 16 + lr, ks);
    if (t + 3 < nt) stage_half(1, 1, 0, t + 3);   // (t+3).B0 (free after ph6)
    BAR(); LGKM0();
    __builtin_amdgcn_s_setprio(1);
#pragma unroll
    for (int mi = 0; mi < 4; ++mi)
#pragma unroll
      for (int ni = 0; ni < 2; ++ni)
#pragma unroll
        for (int ks = 0; ks < 2; ++ks)
          acc[mi + 4][ni + 2] = mfma16(a1[mi][ks], b1f[ni][ks], acc[mi + 4][ni + 2]);
    __builtin_amdgcn_s_setprio(0);
    BAR();
    // ---- ph8: regs only; stage B1'+A0' ----
    if (t + 3 < nt) { stage_half(1, 1, 1, t + 3); stage_half(1, 0, 0, t + 3); }
    BAR();
    __builtin_amdgcn_s_setprio(1);
#pragma unroll
    for (int mi = 0; mi < 4; ++mi)
#pragma unroll
      for (int ni = 0; ni < 2; ++ni)
#pragma unroll
        for (int ks = 0; ks < 2; ++ks)
          acc[mi + 4][ni] = mfma16(a1[mi][ks], b0f[ni][ks], acc[mi + 4][ni]);
    __builtin_amdgcn_s_setprio(0);
    if (t + 3 < nt) { WVM6(); } else { WVM0(); }
    BAR();
  }

  // ---- epilogue ----
  if (OUTMODE == 0) {
    // LDS-bounce: tile -> LDS (128 KB), then fully-coalesced 16B/lane stores.
    __syncthreads();
    u16* cw = (u16*)&lds[0][0][0][0];       // [256][256] u16
#pragma unroll
    for (int ni = 0; ni < 4; ++ni) {
      const int col = wc * 64 + ni * 16 + lr;
      const float bv = biasp[n0 + col];
#pragma unroll
      for (int mi = 0; mi < 8; ++mi)
#pragma unroll
        for (int j = 0; j < 4; ++j) {
          const int row = wr * 128 + mi * 16 + lg * 4 + j;
          cw[row * 256 + col] = f2b(acc[mi][ni][j] + bv);
        }
    }
    __syncthreads();
#pragma unroll
    for (int it = 0; it < 16; ++it) {
      int c = it * 512 + tid;
      int row = c >> 5, ch = c & 31;
      i32x4 v = *(const i32x4*)&cw[row * 256 + ch * 8];
      *(i32x4*)((u16*)Cp + (size_t)(m0 + row) * 1024 + n0 + ch * 8) = v;
    }
  } else {
#pragma unroll
    for (int ni = 0; ni < 4; ++ni) {
      const int col = n0 + wc * 64 + ni * 16 + lr;
      const float bv = (OUTMODE == 2) ? 0.f : biasp[col];
#pragma unroll
      for (int mi = 0; mi < 8; ++mi)
#pragma unroll
        for (int j = 0; j < 4; ++j) {
          const int row = m0 + wr * 128 + mi * 16 + lg * 4 + j;
          const float v = acc[mi][ni][j] + bv;
          if (OUTMODE == 2)
            ((float*)Cp)[(size_t)sp * M * 1024 + (size_t)row * 1024 + col] = v;
          else
            ((float*)Cp)[(size_t)row * 1024 + col] = v;
        }
    }
  }
}

// ---------------------------------------------------------------------------
// Legacy 128x128 GEMM — fallback paths only (small workspace)
// ---------------------------------------------------------------------------
template<int AMODE, int OUTMODE>
__global__ __launch_bounds__(256)
void gemm_bt(const void* A0p, const void* A1p, const void* A2p,
             const u16* B0p, const u16* B1p, const u16* B2p,
             const float* b0p, const float* b1p, const float* b2p,
             void* C0p, void* C1p, void* C2p,
             int M, int K, int kspl) {
  const int zc = blockIdx.z / kspl;
  const int sp = blockIdx.z % kspl;
  const void* Ap = zc == 0 ? A0p : (zc == 1 ? A1p : A2p);
  const u16* Bp = zc == 0 ? B0p : (zc == 1 ? B1p : B2p);
  const float* biasp = zc == 0 ? b0p : (zc == 1 ? b1p : b2p);
  void* Cp = zc == 0 ? C0p : (zc == 1 ? C1p : C2p);

  __shared__ u16 Alds[128 * 64];
  __shared__ u16 Blds[128 * 64];

  const int tid = threadIdx.x;
  const int w = tid >> 6, lane = tid & 63;
  const int lr = lane & 15, lg = lane >> 4;
  const int m0 = blockIdx.x * 128, n0 = blockIdx.y * 128;
  const int wr = (w >> 1) * 64, wc = (w & 1) * 64;
  const int brow = lane >> 3;
  const int bcol = (lane & 7) * 8;

  f32x4 acc[4][4];
#pragma unroll
  for (int mi = 0; mi < 4; ++mi)
#pragma unroll
    for (int ni = 0; ni < 4; ++ni) {
      f32x4 zv = {0.f, 0.f, 0.f, 0.f};
      acc[mi][ni] = zv;
    }

  const int kper = K / kspl;
  const int ktn = kper >> 6;
  const int kb = sp * kper;
  for (int kt = 0; kt < ktn; ++kt) {
    const int k0 = kb + (kt << 6);
    __syncthreads();
#pragma unroll
    for (int i = 0; i < 4; ++i) {
      const int c = w * 4 + i;
      const int row = c * 8 + brow;
      gl_lds16(Bp + (size_t)(n0 + row) * K + k0 + bcol, &Blds[c * 512]);
    }
    if (AMODE == 2) {
      const float* Af = (const float*)Ap;
#pragma unroll
      for (int i = 0; i < 4; ++i) {
        const int c = i * 256 + tid;
        const int row = c >> 3, k8 = (c & 7) * 8;
        const float* s = Af + (size_t)(m0 + row) * K + k0 + k8;
        f32x4 v0 = *(const f32x4*)s;
        f32x4 v1 = *(const f32x4*)(s + 4);
        u16x8 pk;
        pk[0] = f2b(v0[0]); pk[1] = f2b(v0[1]); pk[2] = f2b(v0[2]); pk[3] = f2b(v0[3]);
        pk[4] = f2b(v1[0]); pk[5] = f2b(v1[1]); pk[6] = f2b(v1[2]); pk[7] = f2b(v1[3]);
        *(u16x8*)&Alds[row * 64 + k8] = pk;
      }
    } else if (AMODE == 0) {
      const u16* Ab = (const u16*)Ap;
#pragma unroll
      for (int i = 0; i < 4; ++i) {
        const int c = w * 4 + i;
        const int row = c * 8 + brow;
        gl_lds16(Ab + (size_t)(m0 + row) * K + k0 + bcol, &Alds[c * 512]);
      }
    } else {
      const u16* Ab = (const u16*)Ap;
#pragma unroll
      for (int i = 0; i < 4; ++i) {
        const int c = w * 4 + i;
        const int m = m0 + c * 8 + brow;
        const int nn = m >> 8, p = m & 255;
        const int k = k0 + bcol;
        gl_lds16(Ab + (size_t)(p * 8 + (k >> 10)) * NE + nn * EDIM + (k & 1023),
                 &Alds[c * 512]);
      }
    }
    __syncthreads();
#pragma unroll
    for (int ks = 0; ks < 2; ++ks) {
      bf16x8 af[4], bf[4];
#pragma unroll
      for (int mi = 0; mi < 4; ++mi)
        af[mi] = *(const bf16x8*)&Alds[(wr + mi * 16 + lr) * 64 + ks * 32 + lg * 8];
#pragma unroll
      for (int ni = 0; ni < 4; ++ni)
        bf[ni] = *(const bf16x8*)&Blds[(wc + ni * 16 + lr) * 64 + ks * 32 + lg * 8];
#pragma unroll
      for (int mi = 0; mi < 4; ++mi)
#pragma unroll
        for (int ni = 0; ni < 4; ++ni)
          acc[mi][ni] = mfma16(af[mi], bf[ni], acc[mi][ni]);
    }
  }
#pragma unroll
  for (int ni = 0; ni < 4; ++ni) {
    const int col = n0 + wc + ni * 16 + lr;
    const float bv = (OUTMODE == 2) ? 0.f : biasp[col];
#pragma unroll
    for (int mi = 0; mi < 4; ++mi)
#pragma unroll
      for (int j = 0; j < 4; ++j) {
        const int row = m0 + wr + mi * 16 + lg * 4 + j;
        const float v = acc[mi][ni][j] + bv;
        if (OUTMODE == 4) {
          const int nn = row >> 8, pp = row & 255, h = col >> 6, d = col & 63;
          ((u16*)Cp)[(size_t)(nn * HNUM + h) * (DDIM * KPDIM) + d * 256 +
                     (((pp >> 3) ^ (d & 7)) * 8) + (pp & 7)] = f2b(v);
        } else if (OUTMODE == 3) {
          const int nn = row >> 8, pp = row & 255, h = col >> 6, d = col & 63;
          ((u16*)Cp)[((size_t)(nn * HNUM + h) * KPDIM + pp) * DDIM + d] = f2b(v);
        } else if (OUTMODE == 2)
          ((float*)Cp)[(size_t)sp * M * 1024 + (size_t)row * 1024 + col] = v;
        else if (OUTMODE == 1)
          ((float*)Cp)[(size_t)row * 1024 + col] = v;
        else
          ((u16*)Cp)[(size_t)row * 1024 + col] = f2b(v);
      }
  }
}

// ---------------------------------------------------------------------------
// Fused attention v5.1 (r12-verified + Q(h+1) register prefetch):
// swapped-operand QK^T, P in registers. block = (64 q-rows, n, head-group).
// LDS 64 KB, 2 blocks/CU. See r12 comments for the layout derivation.
// Q prefetch is wave-local (registers only — no sync semantics touched):
// aqn loaded right after stageK(h+1) issue, consumed next iteration.
// ---------------------------------------------------------------------------
__global__ __launch_bounds__(256)
void attn_fused5(const u16* __restrict__ Q, const u16* __restrict__ Kc,
                 const u16* __restrict__ VcT, u16* __restrict__ Aout,
                 float* __restrict__ AWp, int hpg) {
  __shared__ u16 Kl[256 * 64];   // K [p][d] chunk-swizzled
  __shared__ u16 Vl[64 * 256];   // V^T [d][p] chunk-swizzled
  const int tid = threadIdx.x;
  const int w = tid >> 6, lane = tid & 63;
  const int lr = lane & 15, lg = lane >> 4;
  const int n = blockIdx.y;
  const int l0 = blockIdx.x * 64;
  const int lrow = l0 + w * 16 + lr;     // this lane's q-row (for S^T / AW)
  char* kbase = (char*)Kl;
  char* vbase = (char*)Vl;
  const int sA = lr + ((lg & 1) << 5);   // lr + 32*(lg&1)
  const int sB = sA + 16;
  const int part = lg >> 1;

  auto stageK = [&](int h) {
    const u16* kh = Kc + (size_t)(n * HNUM + h) * (KPDIM * DDIM);
#pragma unroll
    for (int it = 0; it < 8; ++it) {
      int c = it * 256 + tid, p = c >> 3, j = c & 7;
      gl_lds16(kh + p * 64 + ((j ^ (p & 7)) << 3), kbase + c * 16);
    }
  };
  auto stageV = [&](int h) {
    const u16* vh = VcT + (size_t)(n * HNUM + h) * (DDIM * KPDIM);
#pragma unroll
    for (int it = 0; it < 8; ++it) {
      int c = it * 256 + tid;
      gl_lds16(vh + c * 8, vbase + c * 16);
    }
  };
  const u16* qrow = Q + (size_t)lrow * NE + n * EDIM + lg * 8;

  f32x4 macc[16];
#pragma unroll
  for (int ni = 0; ni < 16; ++ni) { f32x4 zv = {0.f,0.f,0.f,0.f}; macc[ni] = zv; }

  const int hbase = blockIdx.z * hpg;
  stageK(hbase); stageV(hbase);
  // preload Q for first head (wave-local)
  bf16x8 aq0 = *(const bf16x8*)(qrow + hbase * DDIM);
  bf16x8 aq1 = *(const bf16x8*)(qrow + hbase * DDIM + 32);

  for (int hh = 0; hh < hpg; ++hh) {
    const int h = hbase + hh;
    __syncthreads();   // staged K,V landed (drains vmcnt + rendezvous)
    // ---- S^T = K @ Q^T : swapped operands ----
    f32x4 s[16];
#pragma unroll
    for (int ni = 0; ni < 16; ++ni) { f32x4 zv = {0.f,0.f,0.f,0.f}; s[ni] = zv; }
#pragma unroll
    for (int ni = 0; ni < 16; ++ni) {
      int row = ni * 16 + lr;             // K row p (A-operand, lane lr)
      const char* kr = kbase + row * 128;
      bf16x8 k0 = *(const bf16x8*)(kr + ((lg ^ (row & 7)) << 4));
      bf16x8 k1 = *(const bf16x8*)(kr + (((4 + lg) ^ (row & 7)) << 4));
      s[ni] = mfma16(k0, aq0, s[ni]);
      s[ni] = mfma16(k1, aq1, s[ni]);
    }
    LGKM0();
    BAR();            // all waves' K reads done -> K region free
    if (hh + 1 < hpg) stageK(h + 1);      // overlaps softmax+pack+PV
    // ---- prefetch Q(h+1) into registers (wave-local, hides load latency) ----
    bf16x8 aqn0, aqn1;
    if (hh + 1 < hpg) {
      aqn0 = *(const bf16x8*)(qrow + (h + 1) * DDIM);
      aqn1 = *(const bf16x8*)(qrow + (h + 1) * DDIM + 32);
    }
    // ---- softmax: per-lane scalar (q = lr) ----
    float mx = -1e30f;
#pragma unroll
    for (int ni = 0; ni < 16; ++ni)
#pragma unroll
      for (int j = 0; j < 4; ++j) mx = fmaxf(mx, s[ni][j]);
    mx = fmaxf(mx, __shfl_xor(mx, 16, 64));
    mx = fmaxf(mx, __shfl_xor(mx, 32, 64));
    float sm = 0.f;
#pragma unroll
    for (int ni = 0; ni < 16; ++ni)
#pragma unroll
      for (int j = 0; j < 4; ++j) {
        float e = __expf(s[ni][j] - mx);
        s[ni][j] = e; sm += e;
      }
    sm += __shfl_xor(sm, 16, 64);
    sm += __shfl_xor(sm, 32, 64);
    const float inv = 1.0f / sm;
#pragma unroll
    for (int ni = 0; ni < 16; ++ni) {
#pragma unroll
      for (int j = 0; j < 4; ++j) s[ni][j] *= inv;   // normalized P
      macc[ni] += s[ni] * 0.0625f;                   // head-mean accum
    }
    // ---- pack P into A-frags (cross-lane quad exchange) + PV ----
    f32x4 o[4];
#pragma unroll
    for (int ni2 = 0; ni2 < 4; ++ni2) { f32x4 zv = {0.f,0.f,0.f,0.f}; o[ni2] = zv; }
#pragma unroll
    for (int ks = 0; ks < 8; ++ks) {
      unsigned lo0 = pk2(s[2 * ks][0], s[2 * ks][1]);
      unsigned lo1 = pk2(s[2 * ks][2], s[2 * ks][3]);
      unsigned hi0 = pk2(s[2 * ks + 1][0], s[2 * ks + 1][1]);
      unsigned hi1 = pk2(s[2 * ks + 1][2], s[2 * ks + 1][3]);
      unsigned aL0 = (unsigned)__shfl((int)lo0, sA, 64);
      unsigned aL1 = (unsigned)__shfl((int)lo1, sA, 64);
      unsigned aH0 = (unsigned)__shfl((int)hi0, sA, 64);
      unsigned aH1 = (unsigned)__shfl((int)hi1, sA, 64);
      unsigned bL0 = (unsigned)__shfl((int)lo0, sB, 64);
      unsigned bL1 = (unsigned)__shfl((int)lo1, sB, 64);
      unsigned bH0 = (unsigned)__shfl((int)hi0, sB, 64);
      unsigned bH1 = (unsigned)__shfl((int)hi1, sB, 64);
      i32x4 pu;
      pu[0] = (int)(part ? aH0 : aL0);
      pu[1] = (int)(part ? aH1 : aL1);
      pu[2] = (int)(part ? bH0 : bL0);
      pu[3] = (int)(part ? bH1 : bL1);
      bf16x8 pa = __builtin_bit_cast(bf16x8, pu);
#pragma unroll
      for (int ni2 = 0; ni2 < 4; ++ni2) {
        int d = ni2 * 16 + lr;
        bf16x8 vf = *(const bf16x8*)(vbase + d * 512 + (((ks * 4 + lg) ^ (d & 7)) << 4));
        o[ni2] = mfma16(pa, vf, o[ni2]);
      }
    }
    // ---- write O tile (rows q = lg*4+j; already normalized) ----
#pragma unroll
    for (int ni2 = 0; ni2 < 4; ++ni2)
#pragma unroll
      for (int j = 0; j < 4; ++j) {
        int gl = l0 + w * 16 + lg * 4 + j;
        Aout[(size_t)gl * NE + n * EDIM + h * DDIM + ni2 * 16 + lr] = f2b(o[ni2][j]);
      }
    LGKM0();
    BAR();            // all waves' V reads done -> V region free
    if (hh + 1 < hpg) stageV(h + 1);
    aq0 = aqn0; aq1 = aqn1;
  }
  // ---- write head-mean attention weight partial: lane owns q-row lrow ----
  float* awo = AWp + (size_t)blockIdx.z * AWSZ + (size_t)n * (LSEQ * KPDIM)
             + (size_t)lrow * KPDIM;
#pragma unroll
  for (int ni = 0; ni < 16; ++ni)
    *(f32x4*)(awo + ni * 16 + lg * 4) = macc[ni];
}

// ---------------------------------------------------------------------------
// Fused attention v3 (r9/r11, stable) — fallback path only (small workspace).
// ---------------------------------------------------------------------------
__global__ __launch_bounds__(256)
void attn_fused(const u16* __restrict__ Q, const u16* __restrict__ Kc,
                const u16* __restrict__ VcT, u16* __restrict__ Aout,
                float* __restrict__ AWp, int hpg) {
  __shared__ u16 Ares[256 * 64];
  __shared__ u16 Bres[64 * 256];
  const int tid = threadIdx.x;
  const int w = tid >> 6, lane = tid & 63;
  const int lr = lane & 15, lg = lane >> 4;
  const int n = blockIdx.y;
  const int l0 = blockIdx.x * 64;
  const int lrow = l0 + w * 16 + lr;
  char* kbase = (char*)Ares;
  char* vbase = (char*)Bres;
  char* pbase = (char*)Ares + w * 8192;

  f32x4 macc[16];
#pragma unroll
  for (int ni = 0; ni < 16; ++ni) { f32x4 zv = {0.f,0.f,0.f,0.f}; macc[ni] = zv; }

  for (int hh = 0; hh < hpg; ++hh) {
    const int h = blockIdx.z * hpg + hh;
    const u16* kh = Kc + (size_t)(n * HNUM + h) * (KPDIM * DDIM);
    const u16* vh = VcT + (size_t)(n * HNUM + h) * (DDIM * KPDIM);
    __syncthreads();
#pragma unroll
    for (int it = 0; it < 8; ++it) {
      int c = it * 256 + tid;
      int p = c >> 3, j = c & 7;
      gl_lds16(kh + p * 64 + ((j ^ (p & 7)) << 3), kbase + c * 16);
    }
#pragma unroll
    for (int it = 0; it < 8; ++it) {
      int c = it * 256 + tid;
      gl_lds16(vh + c * 8, vbase + c * 16);
    }
    const u16* qp = Q + (size_t)lrow * NE + n * EDIM + h * DDIM + lg * 8;
    bf16x8 aq0 = *(const bf16x8*)qp;
    bf16x8 aq1 = *(const bf16x8*)(qp + 32);
    __syncthreads();
    f32x4 s[16];
#pragma unroll
    for (int ni = 0; ni < 16; ++ni) { f32x4 zv = {0.f,0.f,0.f,0.f}; s[ni] = zv; }
#pragma unroll
    for (int ni = 0; ni < 16; ++ni) {
      int row = ni * 16 + lr;
      const char* kr = kbase + row * 128;
      bf16x8 b0 = *(const bf16x8*)(kr + ((lg ^ (row & 7)) << 4));
      bf16x8 b1 = *(const bf16x8*)(kr + (((4 + lg) ^ (row & 7)) << 4));
      s[ni] = mfma16(aq0, b0, s[ni]);
      s[ni] = mfma16(aq1, b1, s[ni]);
    }
    float mx[4], sm[4], inv[4], invs[4];
#pragma unroll
    for (int j = 0; j < 4; ++j) mx[j] = -1e30f;
#pragma unroll
    for (int ni = 0; ni < 16; ++ni)
#pragma unroll
      for (int j = 0; j < 4; ++j) mx[j] = fmaxf(mx[j], s[ni][j]);
#pragma unroll
    for (int msk = 1; msk <= 8; msk <<= 1)
#pragma unroll
      for (int j = 0; j < 4; ++j) mx[j] = fmaxf(mx[j], __shfl_xor(mx[j], msk, 64));
#pragma unroll
    for (int j = 0; j < 4; ++j) sm[j] = 0.f;
#pragma unroll
    for (int ni = 0; ni < 16; ++ni)
#pragma unroll
      for (int j = 0; j < 4; ++j) {
        float e = __expf(s[ni][j] - mx[j]);
        s[ni][j] = e; sm[j] += e;
      }
#pragma unroll
    for (int msk = 1; msk <= 8; msk <<= 1)
#pragma unroll
      for (int j = 0; j < 4; ++j) sm[j] += __shfl_xor(sm[j], msk, 64);
#pragma unroll
    for (int j = 0; j < 4; ++j) { inv[j] = 1.0f / sm[j]; invs[j] = inv[j] * 0.0625f; }
    __syncthreads();
#pragma unroll
    for (int ni = 0; ni < 16; ++ni)
#pragma unroll
      for (int j = 0; j < 4; ++j) {
        macc[ni][j] += s[ni][j] * invs[j];
        int r = lg * 4 + j;
        *(u16*)(pbase + r * 512 + ((ni * 32 + lr * 2) ^ ((r & 7) << 4))) =
            f2b(s[ni][j]);
      }
    f32x4 o[4];
#pragma unroll
    for (int ni2 = 0; ni2 < 4; ++ni2) { f32x4 zv = {0.f,0.f,0.f,0.f}; o[ni2] = zv; }
#pragma unroll
    for (int ks = 0; ks < 8; ++ks) {
      bf16x8 a = *(const bf16x8*)(pbase + lr * 512 + ((ks * 64 + 16 * lg) ^ ((lr & 7) << 4)));
#pragma unroll
      for (int ni2 = 0; ni2 < 4; ++ni2) {
        int d = ni2 * 16 + lr;
        bf16x8 b = *(const bf16x8*)(vbase + d * 512 + (((ks * 4 + lg) ^ (d & 7)) << 4));
        o[ni2] = mfma16(a, b, o[ni2]);
      }
    }
#pragma unroll
    for (int ni2 = 0; ni2 < 4; ++ni2)
#pragma unroll
      for (int j = 0; j < 4; ++j) {
        int gl = l0 + w * 16 + lg * 4 + j;
        Aout[(size_t)gl * NE + n * EDIM + h * DDIM + ni2 * 16 + lr] =
            f2b(o[ni2][j] * inv[j]);
      }
  }
  float* awo = AWp + (size_t)blockIdx.z * AWSZ + (size_t)n * (LSEQ * KPDIM);
#pragma unroll
  for (int ni = 0; ni < 16; ++ni)
#pragma unroll
    for (int j = 0; j < 4; ++j) {
      int r = lg * 4 + j;
      awo[(size_t)(l0 + w * 16 + r) * KPDIM + ni * 16 + lr] = macc[ni][j];
    }
}

// ---------------------------------------------------------------------------
extern "C" void kernel_launch(void* const* d_in, const int* in_sizes, int n_in,
                              void* d_out, int out_size, void* d_ws, size_t ws_size,
                              hipStream_t stream) {
  const float* query = (const float*)d_in[0];
  const float* key   = (const float*)d_in[1];
  const float* value = (const float*)d_in[2];
  const float* ipw   = (const float*)d_in[3];
  const float* ipb   = (const float*)d_in[4];
  const float* ew    = (const float*)d_in[5];
  const float* eb    = (const float*)d_in[6];
  const float* fw    = (const float*)d_in[7];
  const float* fb    = (const float*)d_in[8];
  const float* ow    = (const float*)d_in[9];
  const float* ob    = (const float*)d_in[10];

  char* ws = (char*)d_ws;
  size_t off = 0;
  auto alloc = [&](size_t bytes) {
    void* p = ws + off;
    off += (bytes + 255) & ~(size_t)255;
    return p;
  };
  u16* qp    = (u16*)alloc((size_t)MROWS * EDIM * 2);
  u16* kp    = (u16*)alloc((size_t)MROWS * EDIM * 2);
  u16* vp    = (u16*)alloc((size_t)MROWS * EDIM * 2);
  u16* ao    = (u16*)alloc((size_t)MROWS * EDIM * 2);
  u16* kc    = (u16*)alloc((size_t)NB * KPDIM * EDIM * 2);   // (N,H,Kp,D)
  u16* vcT   = (u16*)alloc((size_t)NB * KPDIM * EDIM * 2);   // (N,H,D,Kp) swz
  u16* w_in  = (u16*)alloc((size_t)3 * EDIM * EDIM * 2);
  u16* w_eT  = (u16*)alloc((size_t)EDIM * 8 * EDIM * 2);
  u16* w_fT  = (u16*)alloc((size_t)EDIM * 8 * EDIM * 2);
  u16* w_out = (u16*)alloc((size_t)EDIM * EDIM * 2);
  float* bq  = (float*)alloc(EDIM * 4);
  size_t base_needed = off;

  size_t qkv16_b = (size_t)3 * MROWS * EDIM * 2;
  size_t part_b  = (size_t)2 * 4 * 2048 * 1024 * 4;
  bool bigX  = ws_size >= base_needed + qkv16_b;
  bool midX  = ws_size >= base_needed + part_b;
  char* X = (char*)alloc(bigX ? qkv16_b : (midX ? part_b : 0));
  u16* qkv16 = (u16*)X;
  float* part = (float*)X;
  float* awp  = (float*)X;

  float* out_f = (float*)d_out;                        // (L, N, E)
  float* aw_f  = (float*)d_out + (size_t)MROWS * EDIM; // (N, L, Kp)

  // weight prep (merged) + conv-weight transpose
  prep1<<<dim3(3072), 256, 0, stream>>>(ipw, ow, ipb, w_in, w_out, bq);
  wtrans<<<dim3(16384, 2), 64, 0, stream>>>(ew, fw, w_eT, w_fT);

  // q/k/v projections
  if (bigX) {
    castqkv<<<dim3(8192, 3), 256, 0, stream>>>(query, key, value, qkv16);
    gemm256<0, 0><<<dim3(64, 4, 3), 512, 0, stream>>>(
        qkv16, qkv16 + (size_t)MROWS * EDIM, qkv16 + (size_t)2 * MROWS * EDIM,
        w_in, w_in + 1048576, w_in + 2097152,
        bq, ipb + 1024, ipb + 2048,
        qp, kp, vp, MROWS, 1024, 1);
  } else {
    gemm_bt<2, 0><<<dim3(128, 8, 3), 256, 0, stream>>>(
        query, key, value,
        w_in, w_in + 1048576, w_in + 2097152,
        bq, ipb + 1024, ipb + 2048,
        qp, kp, vp, MROWS, 1024, 1);
  }

  // conv compression of k and v -> kc (head-major) / vcT (transposed swz)
  if (bigX || midX) {
    gemm256<1, 2><<<dim3(8, 4, 8), 512, 0, stream>>>(
        kp, vp, vp,
        w_eT, w_fT, w_fT,
        eb, fb, fb,
        part, part + (size_t)4 * 2048 * 1024, part,
        NB * KPDIM, 8192, 4);
    redc<<<dim3(2048, 2), 256, 0, stream>>>(part, eb, fb, kc, vcT);
  } else {
    gemm_bt<1, 3><<<dim3(16, 8, 1), 256, 0, stream>>>(
        kp, kp, kp, w_eT, w_eT, w_eT, eb, eb, eb,
        kc, kc, kc, NB * KPDIM, 8192, 1);
    gemm_bt<1, 4><<<dim3(16, 8, 1), 256, 0, stream>>>(
        vp, vp, vp, w_fT, w_fT, w_fT, fb, fb, fb,
        vcT, vcT, vcT, NB * KPDIM, 8192, 1);
  }

  // fused attention + head-mean weights (z=2: 512 blocks = exactly 2/CU)
  if (bigX) {
    attn_fused5<<<dim3(32, 8, 2), 256, 0, stream>>>(qp, kc, vcT, ao, awp, 8);
    awred<<<dim3(4096), 256, 0, stream>>>(awp, aw_f);
  } else {
    attn_fused<<<dim3(32, 8, 1), 256, 0, stream>>>(qp, kc, vcT, ao, aw_f, 16);
  }

  // output projection -> f32 d_out
  gemm256<0, 1><<<dim3(64, 4, 1), 512, 0, stream>>>(
      ao, ao, ao,
      w_out, w_out, w_out,
      ob, ob, ob,
      out_f, out_f, out_f, MROWS, 1024, 1);
}